// Round 2
// baseline (10949.962 us; speedup 1.0000x reference)
//
#include <hip/hip_runtime.h>
#include <hip/hip_bf16.h>

#define MSAMP 4096
#define D0    512
#define EXPN  8192
#define NCLS  1000

#define BM 128
#define BN 128
#define BK 16
#define TM 8
#define TN 8
#define PAD 132   // LDS row stride in floats: 528B, 16B-aligned for b128

// ---------------------------------------------------------------------------
// MODE 0: C = A @ B (NN).  MODE 1: C = (A@B^T)*inv_i*inv_j, diag=-3e38.
// ---------------------------------------------------------------------------
template<int MODE>
__global__ __launch_bounds__(256) void gemm_t(
    const float* __restrict__ A, const float* __restrict__ B,
    float* __restrict__ C, int M, int K, int N,
    const float* __restrict__ invn)
{
    __shared__ float As[BK][PAD];
    __shared__ float Bs[BK][PAD];

    const int tid = threadIdx.x;
    const int tx = tid & 15, ty = tid >> 4;
    const int row0 = blockIdx.y * BM, col0 = blockIdx.x * BN;
    const int ar = tid >> 2;            // 0..63
    const int ac = (tid & 3) << 2;      // 0,4,8,12
    const int br = tid >> 5;            // 0..7
    const int bc = (tid & 31) << 2;     // 0..124

    float acc[TM][TN];
#pragma unroll
    for (int i = 0; i < TM; ++i)
#pragma unroll
        for (int j = 0; j < TN; ++j) acc[i][j] = 0.f;

    for (int k0 = 0; k0 < K; k0 += BK) {
        float4 a0 = *(const float4*)(A + (size_t)(row0 + ar) * K + k0 + ac);
        float4 a1 = *(const float4*)(A + (size_t)(row0 + ar + 64) * K + k0 + ac);
        As[ac + 0][ar] = a0.x; As[ac + 1][ar] = a0.y;
        As[ac + 2][ar] = a0.z; As[ac + 3][ar] = a0.w;
        As[ac + 0][ar + 64] = a1.x; As[ac + 1][ar + 64] = a1.y;
        As[ac + 2][ar + 64] = a1.z; As[ac + 3][ar + 64] = a1.w;

        if (MODE == 1) {
            // NT: Bs[k][n] = B[(col0+n)*K + k0+k]
            float4 b0 = *(const float4*)(B + (size_t)(col0 + ar) * K + k0 + ac);
            float4 b1 = *(const float4*)(B + (size_t)(col0 + ar + 64) * K + k0 + ac);
            Bs[ac + 0][ar] = b0.x; Bs[ac + 1][ar] = b0.y;
            Bs[ac + 2][ar] = b0.z; Bs[ac + 3][ar] = b0.w;
            Bs[ac + 0][ar + 64] = b1.x; Bs[ac + 1][ar + 64] = b1.y;
            Bs[ac + 2][ar + 64] = b1.z; Bs[ac + 3][ar + 64] = b1.w;
        } else {
            float4 b0 = *(const float4*)(B + (size_t)(k0 + br) * N + col0 + bc);
            float4 b1 = *(const float4*)(B + (size_t)(k0 + br + 8) * N + col0 + bc);
            *(float4*)&Bs[br][bc]     = b0;
            *(float4*)&Bs[br + 8][bc] = b1;
        }
        __syncthreads();

#pragma unroll
        for (int kk = 0; kk < BK; ++kk) {
            float a[TM], b[TN];
#pragma unroll
            for (int i = 0; i < TM; ++i) a[i] = As[kk][ty * TM + i];
#pragma unroll
            for (int j = 0; j < TN; ++j) b[j] = Bs[kk][tx * TN + j];
#pragma unroll
            for (int i = 0; i < TM; ++i)
#pragma unroll
                for (int j = 0; j < TN; ++j)
                    acc[i][j] = fmaf(a[i], b[j], acc[i][j]);
        }
        __syncthreads();
    }

#pragma unroll
    for (int i = 0; i < TM; ++i) {
        const int gi = row0 + ty * TM + i;
        float inv_i = (MODE == 1) ? invn[gi] : 0.f;
#pragma unroll
        for (int j = 0; j < TN; ++j) {
            const int gj = col0 + tx * TN + j;
            float v = acc[i][j];
            if (MODE == 1) {
                v *= inv_i * invn[gj];
                if (gi == gj) v = -3.0e38f;
            }
            C[(size_t)gi * N + gj] = v;
        }
    }
}

// ---------------------------------------------------------------------------
// Tk(bf16) = tanh( (1/k) * Adj @ Xe ), Adj from 1-bit rows (4096 bits/row).
// M=K=4096, N=8192.
// ---------------------------------------------------------------------------
__global__ __launch_bounds__(256) void gemm_adj(
    const unsigned* __restrict__ Abits, const float* __restrict__ Xe,
    __hip_bfloat16* __restrict__ Tk, const int* __restrict__ kp)
{
    __shared__ float Bs[BK][PAD];
    __shared__ unsigned aw[BM];

    const int tid = threadIdx.x;
    const int tx = tid & 15, ty = tid >> 4;
    const int row0 = blockIdx.y * BM, col0 = blockIdx.x * BN;
    const int br = tid >> 5;
    const int bc = (tid & 31) << 2;

    float acc[TM][TN];
#pragma unroll
    for (int i = 0; i < TM; ++i)
#pragma unroll
        for (int j = 0; j < TN; ++j) acc[i][j] = 0.f;

    for (int k0 = 0; k0 < MSAMP; k0 += BK) {
        if ((k0 & 31) == 0 && tid < BM)
            aw[tid] = Abits[(size_t)(row0 + tid) * (MSAMP / 32) + (k0 >> 5)];

        float4 b0 = *(const float4*)(Xe + (size_t)(k0 + br) * EXPN + col0 + bc);
        float4 b1 = *(const float4*)(Xe + (size_t)(k0 + br + 8) * EXPN + col0 + bc);
        *(float4*)&Bs[br][bc]     = b0;
        *(float4*)&Bs[br + 8][bc] = b1;
        __syncthreads();

        unsigned w[TM];
#pragma unroll
        for (int i = 0; i < TM; ++i) w[i] = aw[ty * TM + i];
        const int sh0 = k0 & 16;

#pragma unroll
        for (int kk = 0; kk < BK; ++kk) {
            float b[TN];
#pragma unroll
            for (int j = 0; j < TN; ++j) b[j] = Bs[kk][tx * TN + j];
#pragma unroll
            for (int i = 0; i < TM; ++i) {
                const float a = ((w[i] >> (sh0 + kk)) & 1u) ? 1.0f : 0.0f;
#pragma unroll
                for (int j = 0; j < TN; ++j)
                    acc[i][j] = fmaf(a, b[j], acc[i][j]);
            }
        }
        __syncthreads();
    }

    const float kv = 1.0f / (float)(*kp);
#pragma unroll
    for (int i = 0; i < TM; ++i) {
        const int gi = row0 + ty * TM + i;
#pragma unroll
        for (int j = 0; j < TN; ++j) {
            const int gj = col0 + tx * TN + j;
            Tk[(size_t)gi * EXPN + gj] = __float2bfloat16(tanhf(acc[i][j] * kv));
        }
    }
}

// ---------------------------------------------------------------------------
// out = relu(Xe) @ Wm + bf16(Tk) @ Wc   (M=4096, K=8192, N=1000)
// ---------------------------------------------------------------------------
__device__ __forceinline__ float bf2f(unsigned short u) {
    return __uint_as_float(((unsigned)u) << 16);
}

__global__ __launch_bounds__(256) void gemm_out(
    const float* __restrict__ Xe, const __hip_bfloat16* __restrict__ Tk,
    const float* __restrict__ Wm, const float* __restrict__ Wc,
    float* __restrict__ Cout, int M, int K, int N)
{
    __shared__ float As1[BK][PAD], As2[BK][PAD];
    __shared__ float Bs1[BK][PAD], Bs2[BK][PAD];

    const int tid = threadIdx.x;
    const int tx = tid & 15, ty = tid >> 4;
    const int row0 = blockIdx.y * BM, col0 = blockIdx.x * BN;
    const int ar = tid >> 2;
    const int ac = (tid & 3) << 2;
    const int br = tid >> 5;
    const int bc = (tid & 31) << 2;

    float acc[TM][TN];
#pragma unroll
    for (int i = 0; i < TM; ++i)
#pragma unroll
        for (int j = 0; j < TN; ++j) acc[i][j] = 0.f;

    const float4 zero4 = make_float4(0.f, 0.f, 0.f, 0.f);
    const int colb = col0 + bc;
    const bool bvalid = (colb < N);   // N % 4 == 0 so float4 never straddles
    const unsigned short* Tku = (const unsigned short*)Tk;

    for (int k0 = 0; k0 < K; k0 += BK) {
        float4 a0 = *(const float4*)(Xe + (size_t)(row0 + ar) * K + k0 + ac);
        float4 a1 = *(const float4*)(Xe + (size_t)(row0 + ar + 64) * K + k0 + ac);
        As1[ac + 0][ar] = fmaxf(a0.x, 0.f); As1[ac + 1][ar] = fmaxf(a0.y, 0.f);
        As1[ac + 2][ar] = fmaxf(a0.z, 0.f); As1[ac + 3][ar] = fmaxf(a0.w, 0.f);
        As1[ac + 0][ar + 64] = fmaxf(a1.x, 0.f); As1[ac + 1][ar + 64] = fmaxf(a1.y, 0.f);
        As1[ac + 2][ar + 64] = fmaxf(a1.z, 0.f); As1[ac + 3][ar + 64] = fmaxf(a1.w, 0.f);

        ushort4 c0 = *(const ushort4*)(Tku + (size_t)(row0 + ar) * K + k0 + ac);
        ushort4 c1 = *(const ushort4*)(Tku + (size_t)(row0 + ar + 64) * K + k0 + ac);
        As2[ac + 0][ar] = bf2f(c0.x); As2[ac + 1][ar] = bf2f(c0.y);
        As2[ac + 2][ar] = bf2f(c0.z); As2[ac + 3][ar] = bf2f(c0.w);
        As2[ac + 0][ar + 64] = bf2f(c1.x); As2[ac + 1][ar + 64] = bf2f(c1.y);
        As2[ac + 2][ar + 64] = bf2f(c1.z); As2[ac + 3][ar + 64] = bf2f(c1.w);

        float4 b0 = bvalid ? *(const float4*)(Wm + (size_t)(k0 + br) * N + colb) : zero4;
        float4 b1 = bvalid ? *(const float4*)(Wm + (size_t)(k0 + br + 8) * N + colb) : zero4;
        *(float4*)&Bs1[br][bc]     = b0;
        *(float4*)&Bs1[br + 8][bc] = b1;

        float4 d0 = bvalid ? *(const float4*)(Wc + (size_t)(k0 + br) * N + colb) : zero4;
        float4 d1 = bvalid ? *(const float4*)(Wc + (size_t)(k0 + br + 8) * N + colb) : zero4;
        *(float4*)&Bs2[br][bc]     = d0;
        *(float4*)&Bs2[br + 8][bc] = d1;

        __syncthreads();

#pragma unroll
        for (int kk = 0; kk < BK; ++kk) {
            float a1r[TM], b1r[TN], a2r[TM], b2r[TN];
#pragma unroll
            for (int i = 0; i < TM; ++i) { a1r[i] = As1[kk][ty * TM + i]; a2r[i] = As2[kk][ty * TM + i]; }
#pragma unroll
            for (int j = 0; j < TN; ++j) { b1r[j] = Bs1[kk][tx * TN + j]; b2r[j] = Bs2[kk][tx * TN + j]; }
#pragma unroll
            for (int i = 0; i < TM; ++i)
#pragma unroll
                for (int j = 0; j < TN; ++j) {
                    acc[i][j] = fmaf(a1r[i], b1r[j], acc[i][j]);
                    acc[i][j] = fmaf(a2r[i], b2r[j], acc[i][j]);
                }
        }
        __syncthreads();
    }

#pragma unroll
    for (int i = 0; i < TM; ++i) {
        const int gi = row0 + ty * TM + i;
#pragma unroll
        for (int j = 0; j < TN; ++j) {
            const int gj = col0 + tx * TN + j;
            if (gj < N) Cout[(size_t)gi * N + gj] = acc[i][j];
        }
    }
}

// ---------------------------------------------------------------------------
// Per-row 1/||Xe_row||
// ---------------------------------------------------------------------------
__global__ __launch_bounds__(256) void row_invnorm(const float* __restrict__ Xe,
                                                   float* __restrict__ invn)
{
    const int row = blockIdx.x;
    const float4* p = (const float4*)(Xe + (size_t)row * EXPN);
    float s = 0.f;
    for (int j = threadIdx.x; j < EXPN / 4; j += 256) {
        float4 v = p[j];
        s += v.x * v.x + v.y * v.y + v.z * v.z + v.w * v.w;
    }
#pragma unroll
    for (int off = 32; off > 0; off >>= 1) s += __shfl_down(s, off);
    __shared__ float wsum[4];
    if ((threadIdx.x & 63) == 0) wsum[threadIdx.x >> 6] = s;
    __syncthreads();
    if (threadIdx.x == 0)
        invn[row] = rsqrtf(wsum[0] + wsum[1] + wsum[2] + wsum[3]);
}

// ---------------------------------------------------------------------------
// Per-row k-th largest via 4-pass radix select on sign-flipped uint keys.
// ---------------------------------------------------------------------------
__global__ __launch_bounds__(256) void topk_thresh(const float* __restrict__ sim,
                                                   float* __restrict__ thr,
                                                   int N, const int* __restrict__ kp)
{
    const int row = blockIdx.x;
    const float* srow = sim + (size_t)row * N;
    __shared__ int hist[256];
    __shared__ unsigned s_prefix;
    __shared__ int s_rem;
    if (threadIdx.x == 0) { s_prefix = 0u; s_rem = *kp; }
    __syncthreads();

    for (int pass = 0; pass < 4; ++pass) {
        const int shift = 24 - 8 * pass;
        hist[threadIdx.x] = 0;
        __syncthreads();
        const unsigned prefix = s_prefix;
        const unsigned pmask = (pass == 0) ? 0u : (0xFFFFFFFFu << (shift + 8));
        for (int j = threadIdx.x; j < N; j += 256) {
            unsigned u = __float_as_uint(srow[j]);
            u = ((int)u < 0) ? ~u : (u | 0x80000000u);
            if ((u & pmask) == (prefix & pmask))
                atomicAdd(&hist[(u >> shift) & 255], 1);
        }
        __syncthreads();
        if (threadIdx.x == 0) {
            int rem = s_rem, accum = 0, b;
            for (b = 255; b > 0; --b) {
                if (accum + hist[b] >= rem) break;
                accum += hist[b];
            }
            s_rem = rem - accum;
            s_prefix = prefix | ((unsigned)b << shift);
        }
        __syncthreads();
    }

    if (threadIdx.x == 0) {
        const unsigned u = s_prefix;
        const unsigned orig = (u & 0x80000000u) ? (u & 0x7FFFFFFFu) : ~u;
        thr[row] = __uint_as_float(orig);
    }
}

// ---------------------------------------------------------------------------
// Pack Adj[i][j] = (Sm[i][j] >= thr[i]) into 1 bit each. 128 words/row.
// ---------------------------------------------------------------------------
__global__ __launch_bounds__(128) void bitpack(const float* __restrict__ Sm,
                                               const float* __restrict__ thr,
                                               unsigned* __restrict__ Abits)
{
    const int row = blockIdx.x;
    const int w = threadIdx.x;          // 0..127
    const float t = thr[row];
    const float* p = Sm + (size_t)row * MSAMP + w * 32;
    unsigned m = 0;
#pragma unroll
    for (int b = 0; b < 32; b += 4) {
        float4 v = *(const float4*)(p + b);
        m |= (v.x >= t ? 1u : 0u) << (b + 0);
        m |= (v.y >= t ? 1u : 0u) << (b + 1);
        m |= (v.z >= t ? 1u : 0u) << (b + 2);
        m |= (v.w >= t ? 1u : 0u) << (b + 3);
    }
    Abits[(size_t)row * (MSAMP / 32) + w] = m;
}

// ---------------------------------------------------------------------------
extern "C" void kernel_launch(void* const* d_in, const int* in_sizes, int n_in,
                              void* d_out, int out_size, void* d_ws, size_t ws_size,
                              hipStream_t stream)
{
    const float* X  = (const float*)d_in[0];
    const float* Wb = (const float*)d_in[1];
    const float* Wm = (const float*)d_in[2];
    const float* Wc = (const float*)d_in[3];
    const int*   kp = (const int*)d_in[4];
    float* out = (float*)d_out;

    // Workspace layout (peak ~194 MiB):
    //   [0, 128 MiB)          Xe   f32 [4096 x 8192]          (live whole run)
    //   [128 MiB, 192 MiB)    Sm   f32 [4096 x 4096]          (phase A)
    //                         Tk   bf16 [4096 x 8192] overlay (phase B; Sm dead)
    //   [192 MiB, +32 KiB)    invn f32[4096], thr f32[4096]
    //   [+32 KiB, +2 MiB)     Abits u32 [4096 x 128]
    char* base = (char*)d_ws;
    const size_t XE_B  = (size_t)MSAMP * EXPN * 4;          // 134217728
    const size_t SM_B  = (size_t)MSAMP * MSAMP * 4;         // 67108864
    const size_t need  = XE_B + SM_B + 32768 + (size_t)MSAMP * (MSAMP / 32) * 4;
    if (ws_size < need) return;  // diagnostic: leaves d_out poisoned instead of faulting

    float*          Xe    = (float*)base;
    float*          Sm    = (float*)(base + XE_B);
    __hip_bfloat16* Tk    = (__hip_bfloat16*)(base + XE_B);   // overlays Sm
    float*          invn  = (float*)(base + XE_B + SM_B);
    float*          thr   = invn + MSAMP;
    unsigned*       Abits = (unsigned*)(base + XE_B + SM_B + 32768);

    const dim3 blk(256);

    // 1) Xe = X @ W_buffer
    gemm_t<0><<<dim3(EXPN / BN, MSAMP / BM), blk, 0, stream>>>(
        X, Wb, Xe, MSAMP, D0, EXPN, nullptr);

    // 2) row inverse norms
    row_invnorm<<<dim3(MSAMP), blk, 0, stream>>>(Xe, invn);

    // 3) Sm = (Xe @ Xe^T) * inv_i * inv_j, diag = -3e38
    gemm_t<1><<<dim3(MSAMP / BN, MSAMP / BM), blk, 0, stream>>>(
        Xe, Xe, Sm, MSAMP, EXPN, MSAMP, invn);

    // 4) per-row k-th largest threshold (exact, f32)
    topk_thresh<<<dim3(MSAMP), blk, 0, stream>>>(Sm, thr, MSAMP, kp);

    // 5) pack adjacency bits (Sm dead afterwards)
    bitpack<<<dim3(MSAMP), dim3(128), 0, stream>>>(Sm, thr, Abits);

    // 6) Tk(bf16) = tanh( (1/k) * Adj @ Xe )   — writes over Sm region
    gemm_adj<<<dim3(EXPN / BN, MSAMP / BM), blk, 0, stream>>>(
        Abits, Xe, Tk, kp);

    // 7) out = relu(Xe) @ W_main + Tk @ W_comp
    gemm_out<<<dim3((NCLS + BN - 1) / BN, MSAMP / BM), blk, 0, stream>>>(
        Xe, Tk, Wm, Wc, out, MSAMP, EXPN, NCLS);
}

// Round 3
// 5001.872 us; speedup vs baseline: 2.1892x; 2.1892x over previous
//
#include <hip/hip_runtime.h>
#include <hip/hip_bf16.h>

#define MSAMP 4096
#define D0    512
#define EXPN  8192
#define NCLS  1000

#define BM 128
#define BN 128
#define BK 16
#define TM 8
#define TN 8
#define PAD 132

typedef __attribute__((ext_vector_type(8))) short          short8;
typedef __attribute__((ext_vector_type(8))) unsigned short ushort8v;
typedef __attribute__((ext_vector_type(4))) float          f32x4;

__device__ __forceinline__ float bf2f(unsigned short u) {
    return __uint_as_float(((unsigned)u) << 16);
}
__device__ __forceinline__ unsigned short f2bf(float f) {   // RNE
    unsigned u = __float_as_uint(f);
    return (unsigned short)((u + 0x7FFFu + ((u >> 16) & 1u)) >> 16);
}

// ---------------------------------------------------------------------------
// Xe GEMM (f32 VALU, proven round-2 structure): epilogue writes hi/lo bf16.
// A = X [4096][512], B = Wb [512][8192].
// ---------------------------------------------------------------------------
__global__ __launch_bounds__(256) void gemm_xe(
    const float* __restrict__ A, const float* __restrict__ B,
    unsigned short* __restrict__ XeHi, unsigned short* __restrict__ XeLo)
{
    __shared__ float As[BK][PAD];
    __shared__ float Bs[BK][PAD];

    const int tid = threadIdx.x;
    const int tx = tid & 15, ty = tid >> 4;
    const int row0 = blockIdx.y * BM, col0 = blockIdx.x * BN;
    const int ar = tid >> 2, ac = (tid & 3) << 2;
    const int br = tid >> 5, bc = (tid & 31) << 2;

    float acc[TM][TN];
#pragma unroll
    for (int i = 0; i < TM; ++i)
#pragma unroll
        for (int j = 0; j < TN; ++j) acc[i][j] = 0.f;

    for (int k0 = 0; k0 < D0; k0 += BK) {
        float4 a0 = *(const float4*)(A + (size_t)(row0 + ar) * D0 + k0 + ac);
        float4 a1 = *(const float4*)(A + (size_t)(row0 + ar + 64) * D0 + k0 + ac);
        As[ac + 0][ar] = a0.x; As[ac + 1][ar] = a0.y;
        As[ac + 2][ar] = a0.z; As[ac + 3][ar] = a0.w;
        As[ac + 0][ar + 64] = a1.x; As[ac + 1][ar + 64] = a1.y;
        As[ac + 2][ar + 64] = a1.z; As[ac + 3][ar + 64] = a1.w;

        float4 b0 = *(const float4*)(B + (size_t)(k0 + br) * EXPN + col0 + bc);
        float4 b1 = *(const float4*)(B + (size_t)(k0 + br + 8) * EXPN + col0 + bc);
        *(float4*)&Bs[br][bc]     = b0;
        *(float4*)&Bs[br + 8][bc] = b1;
        __syncthreads();

#pragma unroll
        for (int kk = 0; kk < BK; ++kk) {
            float a[TM], b[TN];
#pragma unroll
            for (int i = 0; i < TM; ++i) a[i] = As[kk][ty * TM + i];
#pragma unroll
            for (int j = 0; j < TN; ++j) b[j] = Bs[kk][tx * TN + j];
#pragma unroll
            for (int i = 0; i < TM; ++i)
#pragma unroll
                for (int j = 0; j < TN; ++j)
                    acc[i][j] = fmaf(a[i], b[j], acc[i][j]);
        }
        __syncthreads();
    }

    union { unsigned short u[8]; ushort8v v; } h8, l8;
#pragma unroll
    for (int i = 0; i < TM; ++i) {
        const int gi = row0 + ty * TM + i;
#pragma unroll
        for (int j = 0; j < TN; ++j) {
            float v = acc[i][j];
            unsigned short hu = f2bf(v);
            float lv = v - bf2f(hu);
            h8.u[j] = hu;
            l8.u[j] = f2bf(lv);
        }
        *(ushort8v*)&XeHi[(size_t)gi * EXPN + col0 + tx * TN] = h8.v;
        *(ushort8v*)&XeLo[(size_t)gi * EXPN + col0 + tx * TN] = l8.v;
    }
}

// ---------------------------------------------------------------------------
// sim = (Xe @ Xe^T)*inv_i*inv_j via split-bf16 MFMA (hh + hl + lh), diag=-3e38
// Tiles 128x128, BK=32, 4 waves (2x2, each 64x64 = 4x4 MFMA tiles).
// LDS tile layout: [row][chunk^ (row&3)] chunks of 8 ushorts (16B), swizzled.
// ---------------------------------------------------------------------------
__global__ __launch_bounds__(256) void gemm_sim(
    const unsigned short* __restrict__ XeHi, const unsigned short* __restrict__ XeLo,
    const float* __restrict__ invn, float* __restrict__ Sm)
{
    __shared__ unsigned short Ah[128][32], Al[128][32], Bh[128][32], Bl[128][32];

    const int tid = threadIdx.x;
    const int wid = tid >> 6, lane = tid & 63;
    const int l15 = lane & 15, q = lane >> 4;
    const int wm = (wid >> 1) * 64, wn = (wid & 1) * 64;
    const int row0 = blockIdx.y * 128, col0 = blockIdx.x * 128;

    const int sr = tid >> 1;               // 0..127
    const int scp = (tid & 1) * 2;         // chunk pair: 0 or 2

    f32x4 acc[4][4];
#pragma unroll
    for (int m = 0; m < 4; ++m)
#pragma unroll
        for (int n = 0; n < 4; ++n) acc[m][n] = (f32x4){0.f, 0.f, 0.f, 0.f};

    const int c0 = (scp ^ (sr & 3)) * 8;
    const int c1 = ((scp + 1) ^ (sr & 3)) * 8;

    for (int k0 = 0; k0 < EXPN; k0 += 32) {
        const unsigned short* pah = XeHi + (size_t)(row0 + sr) * EXPN + k0 + scp * 8;
        const unsigned short* pal = XeLo + (size_t)(row0 + sr) * EXPN + k0 + scp * 8;
        const unsigned short* pbh = XeHi + (size_t)(col0 + sr) * EXPN + k0 + scp * 8;
        const unsigned short* pbl = XeLo + (size_t)(col0 + sr) * EXPN + k0 + scp * 8;
        ushort8v ah0 = *(const ushort8v*)pah, ah1 = *(const ushort8v*)(pah + 8);
        ushort8v al0 = *(const ushort8v*)pal, al1 = *(const ushort8v*)(pal + 8);
        ushort8v bh0 = *(const ushort8v*)pbh, bh1 = *(const ushort8v*)(pbh + 8);
        ushort8v bl0 = *(const ushort8v*)pbl, bl1 = *(const ushort8v*)(pbl + 8);

        __syncthreads();   // previous iteration's frag reads complete
        *(ushort8v*)&Ah[sr][c0] = ah0;  *(ushort8v*)&Ah[sr][c1] = ah1;
        *(ushort8v*)&Al[sr][c0] = al0;  *(ushort8v*)&Al[sr][c1] = al1;
        *(ushort8v*)&Bh[sr][c0] = bh0;  *(ushort8v*)&Bh[sr][c1] = bh1;
        *(ushort8v*)&Bl[sr][c0] = bl0;  *(ushort8v*)&Bl[sr][c1] = bl1;
        __syncthreads();

        short8 fah[4], fal[4], fbh[4], fbl[4];
#pragma unroll
        for (int m = 0; m < 4; ++m) {
            const int ra = wm + m * 16 + l15;
            const int rb = wn + m * 16 + l15;
            const int ca = (q ^ (ra & 3)) * 8;
            const int cb = (q ^ (rb & 3)) * 8;
            fah[m] = *(const short8*)&Ah[ra][ca];
            fal[m] = *(const short8*)&Al[ra][ca];
            fbh[m] = *(const short8*)&Bh[rb][cb];
            fbl[m] = *(const short8*)&Bl[rb][cb];
        }
#pragma unroll
        for (int m = 0; m < 4; ++m)
#pragma unroll
            for (int n = 0; n < 4; ++n) {
                acc[m][n] = __builtin_amdgcn_mfma_f32_16x16x32_bf16(fah[m], fbh[n], acc[m][n], 0, 0, 0);
                acc[m][n] = __builtin_amdgcn_mfma_f32_16x16x32_bf16(fah[m], fbl[n], acc[m][n], 0, 0, 0);
                acc[m][n] = __builtin_amdgcn_mfma_f32_16x16x32_bf16(fal[m], fbh[n], acc[m][n], 0, 0, 0);
            }
    }

#pragma unroll
    for (int m = 0; m < 4; ++m)
#pragma unroll
        for (int n = 0; n < 4; ++n) {
            const int gj = col0 + wn + n * 16 + l15;
            const float invj = invn[gj];
#pragma unroll
            for (int r = 0; r < 4; ++r) {
                const int gi = row0 + wm + m * 16 + q * 4 + r;
                float v = acc[m][n][r] * invn[gi] * invj;
                if (gi == gj) v = -3.0e38f;
                Sm[(size_t)gi * MSAMP + gj] = v;
            }
        }
}

// ---------------------------------------------------------------------------
// Tk(bf16) = tanh((1/k) * Adj @ Xe): A-frags built from bitmask, B from XeT.
// ---------------------------------------------------------------------------
__global__ __launch_bounds__(256) void gemm_adj(
    const unsigned* __restrict__ Abits, const unsigned short* __restrict__ XeT,
    unsigned short* __restrict__ Tk, const int* __restrict__ kp)
{
    __shared__ unsigned short Bh[128][32];
    __shared__ unsigned aw[128];

    const int tid = threadIdx.x;
    const int wid = tid >> 6, lane = tid & 63;
    const int l15 = lane & 15, q = lane >> 4;
    const int wm = (wid >> 1) * 64, wn = (wid & 1) * 64;
    const int row0 = blockIdx.y * 128;   // m over 4096
    const int col0 = blockIdx.x * 128;   // n over 8192

    const int sr = tid >> 1;
    const int scp = (tid & 1) * 2;
    const int c0 = (scp ^ (sr & 3)) * 8;
    const int c1 = ((scp + 1) ^ (sr & 3)) * 8;

    f32x4 acc[4][4];
#pragma unroll
    for (int m = 0; m < 4; ++m)
#pragma unroll
        for (int n = 0; n < 4; ++n) acc[m][n] = (f32x4){0.f, 0.f, 0.f, 0.f};

    for (int k0 = 0; k0 < MSAMP; k0 += 32) {
        const unsigned short* pb = XeT + (size_t)(col0 + sr) * MSAMP + k0 + scp * 8;
        ushort8v b0 = *(const ushort8v*)pb, b1 = *(const ushort8v*)(pb + 8);
        unsigned w = 0;
        if (tid < 128) w = Abits[(size_t)(row0 + tid) * (MSAMP / 32) + (k0 >> 5)];

        __syncthreads();
        *(ushort8v*)&Bh[sr][c0] = b0;  *(ushort8v*)&Bh[sr][c1] = b1;
        if (tid < 128) aw[tid] = w;
        __syncthreads();

        short8 fb[4];
#pragma unroll
        for (int n = 0; n < 4; ++n) {
            const int rb = wn + n * 16 + l15;
            fb[n] = *(const short8*)&Bh[rb][(q ^ (rb & 3)) * 8];
        }
#pragma unroll
        for (int m = 0; m < 4; ++m) {
            const unsigned wrd = aw[wm + m * 16 + l15];
            const unsigned bits = (wrd >> (q * 8)) & 0xFFu;
            union { unsigned u[4]; short8 s; } fa;
#pragma unroll
            for (int p = 0; p < 4; ++p) {
                fa.u[p] = (((bits >> (2 * p)) & 1u) ? 0x3F80u : 0u) |
                          (((bits >> (2 * p + 1)) & 1u) ? 0x3F800000u : 0u);
            }
#pragma unroll
            for (int n = 0; n < 4; ++n)
                acc[m][n] = __builtin_amdgcn_mfma_f32_16x16x32_bf16(fa.s, fb[n], acc[m][n], 0, 0, 0);
        }
    }

    const float kv = 1.0f / (float)(*kp);
#pragma unroll
    for (int m = 0; m < 4; ++m)
#pragma unroll
        for (int n = 0; n < 4; ++n) {
            const int gj = col0 + wn + n * 16 + l15;
#pragma unroll
            for (int r = 0; r < 4; ++r) {
                const int gi = row0 + wm + m * 16 + q * 4 + r;
                Tk[(size_t)gi * EXPN + gj] = f2bf(tanhf(acc[m][n][r] * kv));
            }
        }
}

// ---------------------------------------------------------------------------
// out = relu(XeHi) @ Wm + Tk @ Wc  (A-sides bf16, B f32; f32 VALU GEMM)
// ---------------------------------------------------------------------------
__global__ __launch_bounds__(256) void gemm_out(
    const unsigned short* __restrict__ XeHi, const unsigned short* __restrict__ Tk,
    const float* __restrict__ Wm, const float* __restrict__ Wc,
    float* __restrict__ Cout)
{
    __shared__ float As1[BK][PAD], As2[BK][PAD];
    __shared__ float Bs1[BK][PAD], Bs2[BK][PAD];

    const int tid = threadIdx.x;
    const int tx = tid & 15, ty = tid >> 4;
    const int row0 = blockIdx.y * BM, col0 = blockIdx.x * BN;
    const int ar = tid >> 2, ac = (tid & 3) << 2;
    const int br = tid >> 5, bc = (tid & 31) << 2;

    float acc[TM][TN];
#pragma unroll
    for (int i = 0; i < TM; ++i)
#pragma unroll
        for (int j = 0; j < TN; ++j) acc[i][j] = 0.f;

    const float4 zero4 = make_float4(0.f, 0.f, 0.f, 0.f);
    const int colb = col0 + bc;
    const bool bvalid = (colb < NCLS);

    for (int k0 = 0; k0 < EXPN; k0 += BK) {
        ushort4 a0 = *(const ushort4*)(XeHi + (size_t)(row0 + ar) * EXPN + k0 + ac);
        ushort4 a1 = *(const ushort4*)(XeHi + (size_t)(row0 + ar + 64) * EXPN + k0 + ac);
        As1[ac + 0][ar] = fmaxf(bf2f(a0.x), 0.f); As1[ac + 1][ar] = fmaxf(bf2f(a0.y), 0.f);
        As1[ac + 2][ar] = fmaxf(bf2f(a0.z), 0.f); As1[ac + 3][ar] = fmaxf(bf2f(a0.w), 0.f);
        As1[ac + 0][ar + 64] = fmaxf(bf2f(a1.x), 0.f); As1[ac + 1][ar + 64] = fmaxf(bf2f(a1.y), 0.f);
        As1[ac + 2][ar + 64] = fmaxf(bf2f(a1.z), 0.f); As1[ac + 3][ar + 64] = fmaxf(bf2f(a1.w), 0.f);

        ushort4 c0 = *(const ushort4*)(Tk + (size_t)(row0 + ar) * EXPN + k0 + ac);
        ushort4 c1 = *(const ushort4*)(Tk + (size_t)(row0 + ar + 64) * EXPN + k0 + ac);
        As2[ac + 0][ar] = bf2f(c0.x); As2[ac + 1][ar] = bf2f(c0.y);
        As2[ac + 2][ar] = bf2f(c0.z); As2[ac + 3][ar] = bf2f(c0.w);
        As2[ac + 0][ar + 64] = bf2f(c1.x); As2[ac + 1][ar + 64] = bf2f(c1.y);
        As2[ac + 2][ar + 64] = bf2f(c1.z); As2[ac + 3][ar + 64] = bf2f(c1.w);

        float4 b0 = bvalid ? *(const float4*)(Wm + (size_t)(k0 + br) * NCLS + colb) : zero4;
        float4 b1 = bvalid ? *(const float4*)(Wm + (size_t)(k0 + br + 8) * NCLS + colb) : zero4;
        *(float4*)&Bs1[br][bc]     = b0;
        *(float4*)&Bs1[br + 8][bc] = b1;

        float4 d0 = bvalid ? *(const float4*)(Wc + (size_t)(k0 + br) * NCLS + colb) : zero4;
        float4 d1 = bvalid ? *(const float4*)(Wc + (size_t)(k0 + br + 8) * NCLS + colb) : zero4;
        *(float4*)&Bs2[br][bc]     = d0;
        *(float4*)&Bs2[br + 8][bc] = d1;

        __syncthreads();

#pragma unroll
        for (int kk = 0; kk < BK; ++kk) {
            float a1r[TM], b1r[TN], a2r[TM], b2r[TN];
#pragma unroll
            for (int i = 0; i < TM; ++i) { a1r[i] = As1[kk][ty * TM + i]; a2r[i] = As2[kk][ty * TM + i]; }
#pragma unroll
            for (int j = 0; j < TN; ++j) { b1r[j] = Bs1[kk][tx * TN + j]; b2r[j] = Bs2[kk][tx * TN + j]; }
#pragma unroll
            for (int i = 0; i < TM; ++i)
#pragma unroll
                for (int j = 0; j < TN; ++j) {
                    acc[i][j] = fmaf(a1r[i], b1r[j], acc[i][j]);
                    acc[i][j] = fmaf(a2r[i], b2r[j], acc[i][j]);
                }
        }
        __syncthreads();
    }

#pragma unroll
    for (int i = 0; i < TM; ++i) {
        const int gi = row0 + ty * TM + i;
#pragma unroll
        for (int j = 0; j < TN; ++j) {
            const int gj = col0 + tx * TN + j;
            if (gj < NCLS) Cout[(size_t)gi * NCLS + gj] = acc[i][j];
        }
    }
}

// ---------------------------------------------------------------------------
__global__ __launch_bounds__(256) void row_invnorm(
    const unsigned short* __restrict__ hi, const unsigned short* __restrict__ lo,
    float* __restrict__ invn)
{
    const int row = blockIdx.x;
    float s = 0.f;
    for (int j = threadIdx.x * 4; j < EXPN; j += 1024) {
        ushort4 h = *(const ushort4*)(hi + (size_t)row * EXPN + j);
        ushort4 l = *(const ushort4*)(lo + (size_t)row * EXPN + j);
        float x0 = bf2f(h.x) + bf2f(l.x), x1 = bf2f(h.y) + bf2f(l.y);
        float x2 = bf2f(h.z) + bf2f(l.z), x3 = bf2f(h.w) + bf2f(l.w);
        s += x0 * x0 + x1 * x1 + x2 * x2 + x3 * x3;
    }
#pragma unroll
    for (int off = 32; off > 0; off >>= 1) s += __shfl_down(s, off);
    __shared__ float wsum[4];
    if ((threadIdx.x & 63) == 0) wsum[threadIdx.x >> 6] = s;
    __syncthreads();
    if (threadIdx.x == 0)
        invn[row] = rsqrtf(wsum[0] + wsum[1] + wsum[2] + wsum[3]);
}

// ---------------------------------------------------------------------------
__global__ __launch_bounds__(256) void topk_thresh(const float* __restrict__ sim,
                                                   float* __restrict__ thr,
                                                   int N, const int* __restrict__ kp)
{
    const int row = blockIdx.x;
    const float* srow = sim + (size_t)row * N;
    __shared__ int hist[256];
    __shared__ unsigned s_prefix;
    __shared__ int s_rem;
    if (threadIdx.x == 0) { s_prefix = 0u; s_rem = *kp; }
    __syncthreads();

    for (int pass = 0; pass < 4; ++pass) {
        const int shift = 24 - 8 * pass;
        hist[threadIdx.x] = 0;
        __syncthreads();
        const unsigned prefix = s_prefix;
        const unsigned pmask = (pass == 0) ? 0u : (0xFFFFFFFFu << (shift + 8));
        for (int j = threadIdx.x; j < N; j += 256) {
            unsigned u = __float_as_uint(srow[j]);
            u = ((int)u < 0) ? ~u : (u | 0x80000000u);
            if ((u & pmask) == (prefix & pmask))
                atomicAdd(&hist[(u >> shift) & 255], 1);
        }
        __syncthreads();
        if (threadIdx.x == 0) {
            int rem = s_rem, accum = 0, b;
            for (b = 255; b > 0; --b) {
                if (accum + hist[b] >= rem) break;
                accum += hist[b];
            }
            s_rem = rem - accum;
            s_prefix = prefix | ((unsigned)b << shift);
        }
        __syncthreads();
    }

    if (threadIdx.x == 0) {
        const unsigned u = s_prefix;
        const unsigned orig = (u & 0x80000000u) ? (u & 0x7FFFFFFFu) : ~u;
        thr[row] = __uint_as_float(orig);
    }
}

// ---------------------------------------------------------------------------
__global__ __launch_bounds__(128) void bitpack(const float* __restrict__ Sm,
                                               const float* __restrict__ thr,
                                               unsigned* __restrict__ Abits)
{
    const int row = blockIdx.x;
    const int w = threadIdx.x;
    const float t = thr[row];
    const float* p = Sm + (size_t)row * MSAMP + w * 32;
    unsigned m = 0;
#pragma unroll
    for (int b = 0; b < 32; b += 4) {
        float4 v = *(const float4*)(p + b);
        m |= (v.x >= t ? 1u : 0u) << (b + 0);
        m |= (v.y >= t ? 1u : 0u) << (b + 1);
        m |= (v.z >= t ? 1u : 0u) << (b + 2);
        m |= (v.w >= t ? 1u : 0u) << (b + 3);
    }
    Abits[(size_t)row * (MSAMP / 32) + w] = m;
}

// ---------------------------------------------------------------------------
// XeT[n][m] = XeHi[m][n]   (bf16 transpose, 32x32 LDS tiles)
// ---------------------------------------------------------------------------
__global__ void transpose_bf16(const unsigned short* __restrict__ src,
                               unsigned short* __restrict__ dst)
{
    __shared__ unsigned short t[32][33];
    const int bx = blockIdx.x;   // 8192/32 tiles along n
    const int by = blockIdx.y;   // 4096/32 tiles along m
    const int tx = threadIdx.x, ty = threadIdx.y;
#pragma unroll
    for (int i = 0; i < 4; ++i)
        t[ty + 8 * i][tx] = src[(size_t)(by * 32 + ty + 8 * i) * EXPN + bx * 32 + tx];
    __syncthreads();
#pragma unroll
    for (int i = 0; i < 4; ++i)
        dst[(size_t)(bx * 32 + ty + 8 * i) * MSAMP + by * 32 + tx] = t[tx][ty + 8 * i];
}

// ---------------------------------------------------------------------------
extern "C" void kernel_launch(void* const* d_in, const int* in_sizes, int n_in,
                              void* d_out, int out_size, void* d_ws, size_t ws_size,
                              hipStream_t stream)
{
    const float* X  = (const float*)d_in[0];
    const float* Wb = (const float*)d_in[1];
    const float* Wm = (const float*)d_in[2];
    const float* Wc = (const float*)d_in[3];
    const int*   kp = (const int*)d_in[4];
    float* out = (float*)d_out;

    // Workspace (peak ~194 MiB, same as known-good round 2):
    //  [0,64M)    XeHi bf16 [4096][8192]                (live all phases)
    //  [64,128M)  XeLo bf16  -> XeT bf16 [8192][4096]   (lo dead after sim)
    //  [128,192M) Sm f32 [4096][4096] -> Tk bf16 [4096][8192]  (Sm dead after bitpack)
    //  [192M..)   Abits u32 [4096][128] (2 MiB), invn, thr
    char* base = (char*)d_ws;
    const size_t SEG = (size_t)64 << 20;
    const size_t need = 3 * SEG + ((size_t)2 << 20) + 65536;
    if (ws_size < need) return;

    unsigned short* XeHi = (unsigned short*)base;
    unsigned short* XeLo = (unsigned short*)(base + SEG);
    unsigned short* XeT  = (unsigned short*)(base + SEG);        // overlay (after sim)
    float*          Sm   = (float*)(base + 2 * SEG);
    unsigned short* Tk   = (unsigned short*)(base + 2 * SEG);    // overlay (after bitpack)
    unsigned*       Abits= (unsigned*)(base + 3 * SEG);
    float*          invn = (float*)(base + 3 * SEG + ((size_t)2 << 20));
    float*          thr  = invn + MSAMP;

    const dim3 blk(256);

    // 1) Xe = X @ Wb  (f32 compute, bf16 hi/lo output)
    gemm_xe<<<dim3(EXPN / BN, MSAMP / BM), blk, 0, stream>>>(X, Wb, XeHi, XeLo);

    // 2) row inverse norms from hi+lo
    row_invnorm<<<dim3(MSAMP), blk, 0, stream>>>(XeHi, XeLo, invn);

    // 3) sim via split-bf16 MFMA (hh+hl+lh)
    gemm_sim<<<dim3(MSAMP / 128, MSAMP / 128), blk, 0, stream>>>(XeHi, XeLo, invn, Sm);

    // 4) per-row k-th largest threshold (exact f32 radix select)
    topk_thresh<<<dim3(MSAMP), blk, 0, stream>>>(Sm, thr, MSAMP, kp);

    // 5) adjacency bitmask
    bitpack<<<dim3(MSAMP), dim3(128), 0, stream>>>(Sm, thr, Abits);

    // 6) XeT = XeHi^T  (into dead XeLo region)
    transpose_bf16<<<dim3(EXPN / 32, MSAMP / 32), dim3(32, 8), 0, stream>>>(XeHi, XeT);

    // 7) Tk = tanh((1/k) Adj @ Xe) via MFMA (bit A-frags, XeT B)  — over dead Sm
    gemm_adj<<<dim3(EXPN / 128, MSAMP / 128), blk, 0, stream>>>(Abits, XeT, Tk, kp);

    // 8) out = relu(Xe) @ Wm + Tk @ Wc
    gemm_out<<<dim3((NCLS + BN - 1) / BN, MSAMP / BM), blk, 0, stream>>>(
        XeHi, Tk, Wm, Wc, out);
}

// Round 4
// 2184.907 us; speedup vs baseline: 5.0116x; 2.2893x over previous
//
#include <hip/hip_runtime.h>
#include <hip/hip_bf16.h>

#define MSAMP 4096
#define D0    512
#define EXPN  8192
#define NCLS  1000
#define NPAD  1024

#define BM 128
#define BN 128
#define BK 16
#define TM 8
#define TN 8
#define PAD 132

typedef __attribute__((ext_vector_type(8))) short          short8;
typedef __attribute__((ext_vector_type(8))) unsigned short ushort8v;
typedef __attribute__((ext_vector_type(4))) float          f32x4;

__device__ __forceinline__ float bf2f(unsigned short u) {
    return __uint_as_float(((unsigned)u) << 16);
}
__device__ __forceinline__ unsigned short f2bf(float f) {   // RNE
    unsigned u = __float_as_uint(f);
    return (unsigned short)((u + 0x7FFFu + ((u >> 16) & 1u)) >> 16);
}
__device__ __forceinline__ ushort8v relu8(ushort8v v) {
#pragma unroll
    for (int j = 0; j < 8; ++j) v[j] = (v[j] & 0x8000u) ? (unsigned short)0 : v[j];
    return v;
}

// ---------------------------------------------------------------------------
// Xe GEMM (f32 VALU): epilogue writes hi/lo bf16.
// ---------------------------------------------------------------------------
__global__ __launch_bounds__(256) void gemm_xe(
    const float* __restrict__ A, const float* __restrict__ B,
    unsigned short* __restrict__ XeHi, unsigned short* __restrict__ XeLo)
{
    __shared__ float As[BK][PAD];
    __shared__ float Bs[BK][PAD];

    const int tid = threadIdx.x;
    const int tx = tid & 15, ty = tid >> 4;
    const int row0 = blockIdx.y * BM, col0 = blockIdx.x * BN;
    const int ar = tid >> 2, ac = (tid & 3) << 2;
    const int br = tid >> 5, bc = (tid & 31) << 2;

    float acc[TM][TN];
#pragma unroll
    for (int i = 0; i < TM; ++i)
#pragma unroll
        for (int j = 0; j < TN; ++j) acc[i][j] = 0.f;

    for (int k0 = 0; k0 < D0; k0 += BK) {
        float4 a0 = *(const float4*)(A + (size_t)(row0 + ar) * D0 + k0 + ac);
        float4 a1 = *(const float4*)(A + (size_t)(row0 + ar + 64) * D0 + k0 + ac);
        As[ac + 0][ar] = a0.x; As[ac + 1][ar] = a0.y;
        As[ac + 2][ar] = a0.z; As[ac + 3][ar] = a0.w;
        As[ac + 0][ar + 64] = a1.x; As[ac + 1][ar + 64] = a1.y;
        As[ac + 2][ar + 64] = a1.z; As[ac + 3][ar + 64] = a1.w;

        float4 b0 = *(const float4*)(B + (size_t)(k0 + br) * EXPN + col0 + bc);
        float4 b1 = *(const float4*)(B + (size_t)(k0 + br + 8) * EXPN + col0 + bc);
        *(float4*)&Bs[br][bc]     = b0;
        *(float4*)&Bs[br + 8][bc] = b1;
        __syncthreads();

#pragma unroll
        for (int kk = 0; kk < BK; ++kk) {
            float a[TM], b[TN];
#pragma unroll
            for (int i = 0; i < TM; ++i) a[i] = As[kk][ty * TM + i];
#pragma unroll
            for (int j = 0; j < TN; ++j) b[j] = Bs[kk][tx * TN + j];
#pragma unroll
            for (int i = 0; i < TM; ++i)
#pragma unroll
                for (int j = 0; j < TN; ++j)
                    acc[i][j] = fmaf(a[i], b[j], acc[i][j]);
        }
        __syncthreads();
    }

    union { unsigned short u[8]; ushort8v v; } h8, l8;
#pragma unroll
    for (int i = 0; i < TM; ++i) {
        const int gi = row0 + ty * TM + i;
#pragma unroll
        for (int j = 0; j < TN; ++j) {
            float v = acc[i][j];
            unsigned short hu = f2bf(v);
            float lv = v - bf2f(hu);
            h8.u[j] = hu;
            l8.u[j] = f2bf(lv);
        }
        *(ushort8v*)&XeHi[(size_t)gi * EXPN + col0 + tx * TN] = h8.v;
        *(ushort8v*)&XeLo[(size_t)gi * EXPN + col0 + tx * TN] = l8.v;
    }
}

// ---------------------------------------------------------------------------
// sim = (Xe @ Xe^T)*inv_i*inv_j via split-bf16 MFMA (hh + hl + lh), diag=-3e38
// ---------------------------------------------------------------------------
__global__ __launch_bounds__(256) void gemm_sim(
    const unsigned short* __restrict__ XeHi, const unsigned short* __restrict__ XeLo,
    const float* __restrict__ invn, float* __restrict__ Sm)
{
    __shared__ unsigned short Ah[128][32], Al[128][32], Bh[128][32], Bl[128][32];

    const int tid = threadIdx.x;
    const int wid = tid >> 6, lane = tid & 63;
    const int l15 = lane & 15, q = lane >> 4;
    const int wm = (wid >> 1) * 64, wn = (wid & 1) * 64;
    const int row0 = blockIdx.y * 128, col0 = blockIdx.x * 128;

    const int sr = tid >> 1;
    const int scp = (tid & 1) * 2;

    f32x4 acc[4][4];
#pragma unroll
    for (int m = 0; m < 4; ++m)
#pragma unroll
        for (int n = 0; n < 4; ++n) acc[m][n] = (f32x4){0.f, 0.f, 0.f, 0.f};

    const int c0 = (scp ^ (sr & 3)) * 8;
    const int c1 = ((scp + 1) ^ (sr & 3)) * 8;

    for (int k0 = 0; k0 < EXPN; k0 += 32) {
        const unsigned short* pah = XeHi + (size_t)(row0 + sr) * EXPN + k0 + scp * 8;
        const unsigned short* pal = XeLo + (size_t)(row0 + sr) * EXPN + k0 + scp * 8;
        const unsigned short* pbh = XeHi + (size_t)(col0 + sr) * EXPN + k0 + scp * 8;
        const unsigned short* pbl = XeLo + (size_t)(col0 + sr) * EXPN + k0 + scp * 8;
        ushort8v ah0 = *(const ushort8v*)pah, ah1 = *(const ushort8v*)(pah + 8);
        ushort8v al0 = *(const ushort8v*)pal, al1 = *(const ushort8v*)(pal + 8);
        ushort8v bh0 = *(const ushort8v*)pbh, bh1 = *(const ushort8v*)(pbh + 8);
        ushort8v bl0 = *(const ushort8v*)pbl, bl1 = *(const ushort8v*)(pbl + 8);

        __syncthreads();
        *(ushort8v*)&Ah[sr][c0] = ah0;  *(ushort8v*)&Ah[sr][c1] = ah1;
        *(ushort8v*)&Al[sr][c0] = al0;  *(ushort8v*)&Al[sr][c1] = al1;
        *(ushort8v*)&Bh[sr][c0] = bh0;  *(ushort8v*)&Bh[sr][c1] = bh1;
        *(ushort8v*)&Bl[sr][c0] = bl0;  *(ushort8v*)&Bl[sr][c1] = bl1;
        __syncthreads();

        short8 fah[4], fal[4], fbh[4], fbl[4];
#pragma unroll
        for (int m = 0; m < 4; ++m) {
            const int ra = wm + m * 16 + l15;
            const int rb = wn + m * 16 + l15;
            const int ca = (q ^ (ra & 3)) * 8;
            const int cb = (q ^ (rb & 3)) * 8;
            fah[m] = *(const short8*)&Ah[ra][ca];
            fal[m] = *(const short8*)&Al[ra][ca];
            fbh[m] = *(const short8*)&Bh[rb][cb];
            fbl[m] = *(const short8*)&Bl[rb][cb];
        }
#pragma unroll
        for (int m = 0; m < 4; ++m)
#pragma unroll
            for (int n = 0; n < 4; ++n) {
                acc[m][n] = __builtin_amdgcn_mfma_f32_16x16x32_bf16(fah[m], fbh[n], acc[m][n], 0, 0, 0);
                acc[m][n] = __builtin_amdgcn_mfma_f32_16x16x32_bf16(fah[m], fbl[n], acc[m][n], 0, 0, 0);
                acc[m][n] = __builtin_amdgcn_mfma_f32_16x16x32_bf16(fal[m], fbh[n], acc[m][n], 0, 0, 0);
            }
    }

#pragma unroll
    for (int m = 0; m < 4; ++m)
#pragma unroll
        for (int n = 0; n < 4; ++n) {
            const int gj = col0 + wn + n * 16 + l15;
            const float invj = invn[gj];
#pragma unroll
            for (int r = 0; r < 4; ++r) {
                const int gi = row0 + wm + m * 16 + q * 4 + r;
                float v = acc[m][n][r] * invn[gi] * invj;
                if (gi == gj) v = -3.0e38f;
                Sm[(size_t)gi * MSAMP + gj] = v;
            }
        }
}

// ---------------------------------------------------------------------------
// Tk(bf16) = tanh((1/k) * Adj @ Xe): A-frags built from bitmask, B from XeT.
// ---------------------------------------------------------------------------
__global__ __launch_bounds__(256) void gemm_adj(
    const unsigned* __restrict__ Abits, const unsigned short* __restrict__ XeT,
    unsigned short* __restrict__ Tk, const int* __restrict__ kp)
{
    __shared__ unsigned short Bh[128][32];
    __shared__ unsigned aw[128];

    const int tid = threadIdx.x;
    const int wid = tid >> 6, lane = tid & 63;
    const int l15 = lane & 15, q = lane >> 4;
    const int wm = (wid >> 1) * 64, wn = (wid & 1) * 64;
    const int row0 = blockIdx.y * 128;
    const int col0 = blockIdx.x * 128;

    const int sr = tid >> 1;
    const int scp = (tid & 1) * 2;
    const int c0 = (scp ^ (sr & 3)) * 8;
    const int c1 = ((scp + 1) ^ (sr & 3)) * 8;

    f32x4 acc[4][4];
#pragma unroll
    for (int m = 0; m < 4; ++m)
#pragma unroll
        for (int n = 0; n < 4; ++n) acc[m][n] = (f32x4){0.f, 0.f, 0.f, 0.f};

    for (int k0 = 0; k0 < MSAMP; k0 += 32) {
        const unsigned short* pb = XeT + (size_t)(col0 + sr) * MSAMP + k0 + scp * 8;
        ushort8v b0 = *(const ushort8v*)pb, b1 = *(const ushort8v*)(pb + 8);
        unsigned w = 0;
        if (tid < 128) w = Abits[(size_t)(row0 + tid) * (MSAMP / 32) + (k0 >> 5)];

        __syncthreads();
        *(ushort8v*)&Bh[sr][c0] = b0;  *(ushort8v*)&Bh[sr][c1] = b1;
        if (tid < 128) aw[tid] = w;
        __syncthreads();

        short8 fb[4];
#pragma unroll
        for (int n = 0; n < 4; ++n) {
            const int rb = wn + n * 16 + l15;
            fb[n] = *(const short8*)&Bh[rb][(q ^ (rb & 3)) * 8];
        }
#pragma unroll
        for (int m = 0; m < 4; ++m) {
            const unsigned wrd = aw[wm + m * 16 + l15];
            const unsigned bits = (wrd >> (q * 8)) & 0xFFu;
            union { unsigned u[4]; short8 s; } fa;
#pragma unroll
            for (int p = 0; p < 4; ++p) {
                fa.u[p] = (((bits >> (2 * p)) & 1u) ? 0x3F80u : 0u) |
                          (((bits >> (2 * p + 1)) & 1u) ? 0x3F800000u : 0u);
            }
#pragma unroll
            for (int n = 0; n < 4; ++n)
                acc[m][n] = __builtin_amdgcn_mfma_f32_16x16x32_bf16(fa.s, fb[n], acc[m][n], 0, 0, 0);
        }
    }

    const float kv = 1.0f / (float)(*kp);
#pragma unroll
    for (int m = 0; m < 4; ++m)
#pragma unroll
        for (int n = 0; n < 4; ++n) {
            const int gj = col0 + wn + n * 16 + l15;
#pragma unroll
            for (int r = 0; r < 4; ++r) {
                const int gi = row0 + wm + m * 16 + q * 4 + r;
                Tk[(size_t)gi * EXPN + gj] = f2bf(tanhf(acc[m][n][r] * kv));
            }
        }
}

// ---------------------------------------------------------------------------
// Transpose+convert W: dst[n][k] = bf16(src[k][n]); n in [0,NPAD), zero-pad.
// src [8192][1000] f32 row-major.  32x32 tiles, block 32x8.
// ---------------------------------------------------------------------------
__global__ void transpose_w(const float* __restrict__ src,
                            unsigned short* __restrict__ dst)
{
    __shared__ float t[32][33];
    const int k0 = blockIdx.x * 32, n0 = blockIdx.y * 32;
    const int tx = threadIdx.x, ty = threadIdx.y;
#pragma unroll
    for (int i = 0; i < 4; ++i) {
        const int n = n0 + tx;
        t[ty + 8 * i][tx] = (n < NCLS) ? src[(size_t)(k0 + ty + 8 * i) * NCLS + n] : 0.f;
    }
    __syncthreads();
#pragma unroll
    for (int i = 0; i < 4; ++i)
        dst[(size_t)(n0 + ty + 8 * i) * EXPN + k0 + tx] = f2bf(t[tx][ty + 8 * i]);
}

// ---------------------------------------------------------------------------
// out = relu(XeHi) @ WmT^T + Tk @ WcT^T via MFMA, fused K=16384 loop.
// WmT/WcT: bf16 [NPAD][8192] (NT layout). Grid (NPAD/128, 4096/128).
// ---------------------------------------------------------------------------
__global__ __launch_bounds__(256) void gemm_out_mfma(
    const unsigned short* __restrict__ XeHi, const unsigned short* __restrict__ Tk,
    const unsigned short* __restrict__ WmT, const unsigned short* __restrict__ WcT,
    float* __restrict__ Cout)
{
    __shared__ unsigned short As[128][32], Bs[128][32];

    const int tid = threadIdx.x;
    const int wid = tid >> 6, lane = tid & 63;
    const int l15 = lane & 15, q = lane >> 4;
    const int wm = (wid >> 1) * 64, wn = (wid & 1) * 64;
    const int row0 = blockIdx.y * 128;
    const int col0 = blockIdx.x * 128;

    const int sr = tid >> 1;
    const int scp = (tid & 1) * 2;
    const int c0 = (scp ^ (sr & 3)) * 8;
    const int c1 = ((scp + 1) ^ (sr & 3)) * 8;

    f32x4 acc[4][4];
#pragma unroll
    for (int m = 0; m < 4; ++m)
#pragma unroll
        for (int n = 0; n < 4; ++n) acc[m][n] = (f32x4){0.f, 0.f, 0.f, 0.f};

    for (int kt = 0; kt < 2 * EXPN; kt += 32) {
        const bool first = (kt < EXPN);
        const int k0 = first ? kt : kt - EXPN;
        const unsigned short* pa = (first ? XeHi : Tk) + (size_t)(row0 + sr) * EXPN + k0 + scp * 8;
        const unsigned short* pb = (first ? WmT : WcT) + (size_t)(col0 + sr) * EXPN + k0 + scp * 8;
        ushort8v a0 = *(const ushort8v*)pa, a1 = *(const ushort8v*)(pa + 8);
        ushort8v b0 = *(const ushort8v*)pb, b1 = *(const ushort8v*)(pb + 8);
        if (first) { a0 = relu8(a0); a1 = relu8(a1); }

        __syncthreads();
        *(ushort8v*)&As[sr][c0] = a0;  *(ushort8v*)&As[sr][c1] = a1;
        *(ushort8v*)&Bs[sr][c0] = b0;  *(ushort8v*)&Bs[sr][c1] = b1;
        __syncthreads();

        short8 fa[4], fb[4];
#pragma unroll
        for (int m = 0; m < 4; ++m) {
            const int ra = wm + m * 16 + l15;
            const int rb = wn + m * 16 + l15;
            fa[m] = *(const short8*)&As[ra][(q ^ (ra & 3)) * 8];
            fb[m] = *(const short8*)&Bs[rb][(q ^ (rb & 3)) * 8];
        }
#pragma unroll
        for (int m = 0; m < 4; ++m)
#pragma unroll
            for (int n = 0; n < 4; ++n)
                acc[m][n] = __builtin_amdgcn_mfma_f32_16x16x32_bf16(fa[m], fb[n], acc[m][n], 0, 0, 0);
    }

#pragma unroll
    for (int m = 0; m < 4; ++m)
#pragma unroll
        for (int n = 0; n < 4; ++n) {
            const int gj = col0 + wn + n * 16 + l15;
            if (gj < NCLS) {
#pragma unroll
                for (int r = 0; r < 4; ++r) {
                    const int gi = row0 + wm + m * 16 + q * 4 + r;
                    Cout[(size_t)gi * NCLS + gj] = acc[m][n][r];
                }
            }
        }
}

// ---------------------------------------------------------------------------
__global__ __launch_bounds__(256) void row_invnorm(
    const unsigned short* __restrict__ hi, const unsigned short* __restrict__ lo,
    float* __restrict__ invn)
{
    const int row = blockIdx.x;
    float s = 0.f;
    for (int j = threadIdx.x * 4; j < EXPN; j += 1024) {
        ushort4 h = *(const ushort4*)(hi + (size_t)row * EXPN + j);
        ushort4 l = *(const ushort4*)(lo + (size_t)row * EXPN + j);
        float x0 = bf2f(h.x) + bf2f(l.x), x1 = bf2f(h.y) + bf2f(l.y);
        float x2 = bf2f(h.z) + bf2f(l.z), x3 = bf2f(h.w) + bf2f(l.w);
        s += x0 * x0 + x1 * x1 + x2 * x2 + x3 * x3;
    }
#pragma unroll
    for (int off = 32; off > 0; off >>= 1) s += __shfl_down(s, off);
    __shared__ float wsum[4];
    if ((threadIdx.x & 63) == 0) wsum[threadIdx.x >> 6] = s;
    __syncthreads();
    if (threadIdx.x == 0)
        invn[row] = rsqrtf(wsum[0] + wsum[1] + wsum[2] + wsum[3]);
}

// ---------------------------------------------------------------------------
__global__ __launch_bounds__(256) void topk_thresh(const float* __restrict__ sim,
                                                   float* __restrict__ thr,
                                                   int N, const int* __restrict__ kp)
{
    const int row = blockIdx.x;
    const float* srow = sim + (size_t)row * N;
    __shared__ int hist[256];
    __shared__ unsigned s_prefix;
    __shared__ int s_rem;
    if (threadIdx.x == 0) { s_prefix = 0u; s_rem = *kp; }
    __syncthreads();

    for (int pass = 0; pass < 4; ++pass) {
        const int shift = 24 - 8 * pass;
        hist[threadIdx.x] = 0;
        __syncthreads();
        const unsigned prefix = s_prefix;
        const unsigned pmask = (pass == 0) ? 0u : (0xFFFFFFFFu << (shift + 8));
        for (int j = threadIdx.x; j < N; j += 256) {
            unsigned u = __float_as_uint(srow[j]);
            u = ((int)u < 0) ? ~u : (u | 0x80000000u);
            if ((u & pmask) == (prefix & pmask))
                atomicAdd(&hist[(u >> shift) & 255], 1);
        }
        __syncthreads();
        if (threadIdx.x == 0) {
            int rem = s_rem, accum = 0, b;
            for (b = 255; b > 0; --b) {
                if (accum + hist[b] >= rem) break;
                accum += hist[b];
            }
            s_rem = rem - accum;
            s_prefix = prefix | ((unsigned)b << shift);
        }
        __syncthreads();
    }

    if (threadIdx.x == 0) {
        const unsigned u = s_prefix;
        const unsigned orig = (u & 0x80000000u) ? (u & 0x7FFFFFFFu) : ~u;
        thr[row] = __uint_as_float(orig);
    }
}

// ---------------------------------------------------------------------------
__global__ __launch_bounds__(128) void bitpack(const float* __restrict__ Sm,
                                               const float* __restrict__ thr,
                                               unsigned* __restrict__ Abits)
{
    const int row = blockIdx.x;
    const int w = threadIdx.x;
    const float t = thr[row];
    const float* p = Sm + (size_t)row * MSAMP + w * 32;
    unsigned m = 0;
#pragma unroll
    for (int b = 0; b < 32; b += 4) {
        float4 v = *(const float4*)(p + b);
        m |= (v.x >= t ? 1u : 0u) << (b + 0);
        m |= (v.y >= t ? 1u : 0u) << (b + 1);
        m |= (v.z >= t ? 1u : 0u) << (b + 2);
        m |= (v.w >= t ? 1u : 0u) << (b + 3);
    }
    Abits[(size_t)row * (MSAMP / 32) + w] = m;
}

// ---------------------------------------------------------------------------
__global__ void transpose_bf16(const unsigned short* __restrict__ src,
                               unsigned short* __restrict__ dst)
{
    __shared__ unsigned short t[32][33];
    const int bx = blockIdx.x;
    const int by = blockIdx.y;
    const int tx = threadIdx.x, ty = threadIdx.y;
#pragma unroll
    for (int i = 0; i < 4; ++i)
        t[ty + 8 * i][tx] = src[(size_t)(by * 32 + ty + 8 * i) * EXPN + bx * 32 + tx];
    __syncthreads();
#pragma unroll
    for (int i = 0; i < 4; ++i)
        dst[(size_t)(bx * 32 + ty + 8 * i) * MSAMP + by * 32 + tx] = t[tx][ty + 8 * i];
}

// ---------------------------------------------------------------------------
extern "C" void kernel_launch(void* const* d_in, const int* in_sizes, int n_in,
                              void* d_out, int out_size, void* d_ws, size_t ws_size,
                              hipStream_t stream)
{
    const float* X  = (const float*)d_in[0];
    const float* Wb = (const float*)d_in[1];
    const float* Wm = (const float*)d_in[2];
    const float* Wc = (const float*)d_in[3];
    const int*   kp = (const int*)d_in[4];
    float* out = (float*)d_out;

    // Workspace (peak ~194 MiB, identical to known-good round 2/3):
    //  [0,64M)    XeHi bf16 [4096][8192]                           (live all phases)
    //  [64,128M)  XeLo -> XeT bf16 [8192][4096] -> WmT+WcT bf16 [1024][8192] x2
    //  [128,192M) Sm f32 [4096][4096] -> Tk bf16 [4096][8192]
    //  [192M..)   Abits u32 (2 MiB), invn, thr
    char* base = (char*)d_ws;
    const size_t SEG = (size_t)64 << 20;
    const size_t need = 3 * SEG + ((size_t)2 << 20) + 65536;
    if (ws_size < need) return;

    unsigned short* XeHi = (unsigned short*)base;
    unsigned short* XeLo = (unsigned short*)(base + SEG);
    unsigned short* XeT  = (unsigned short*)(base + SEG);        // overlay (after sim)
    unsigned short* WmT  = (unsigned short*)(base + SEG);        // overlay (after gemm_adj)
    unsigned short* WcT  = WmT + (size_t)NPAD * EXPN;            // +16 MiB
    float*          Sm   = (float*)(base + 2 * SEG);
    unsigned short* Tk   = (unsigned short*)(base + 2 * SEG);    // overlay (after bitpack)
    unsigned*       Abits= (unsigned*)(base + 3 * SEG);
    float*          invn = (float*)(base + 3 * SEG + ((size_t)2 << 20));
    float*          thr  = invn + MSAMP;

    const dim3 blk(256);

    // 1) Xe = X @ Wb  (f32 compute, bf16 hi/lo output)
    gemm_xe<<<dim3(EXPN / BN, MSAMP / BM), blk, 0, stream>>>(X, Wb, XeHi, XeLo);

    // 2) row inverse norms from hi+lo
    row_invnorm<<<dim3(MSAMP), blk, 0, stream>>>(XeHi, XeLo, invn);

    // 3) sim via split-bf16 MFMA (hh+hl+lh)
    gemm_sim<<<dim3(MSAMP / 128, MSAMP / 128), blk, 0, stream>>>(XeHi, XeLo, invn, Sm);

    // 4) per-row k-th largest threshold (exact f32 radix select)
    topk_thresh<<<dim3(MSAMP), blk, 0, stream>>>(Sm, thr, MSAMP, kp);

    // 5) adjacency bitmask
    bitpack<<<dim3(MSAMP), dim3(128), 0, stream>>>(Sm, thr, Abits);

    // 6) XeT = XeHi^T  (into dead XeLo region)
    transpose_bf16<<<dim3(EXPN / 32, MSAMP / 32), dim3(32, 8), 0, stream>>>(XeHi, XeT);

    // 7) Tk = tanh((1/k) Adj @ Xe) via MFMA — over dead Sm
    gemm_adj<<<dim3(EXPN / 128, MSAMP / 128), blk, 0, stream>>>(Abits, XeT, Tk, kp);

    // 8) W transposes (bf16, NT layout) into dead XeT region
    transpose_w<<<dim3(EXPN / 32, NPAD / 32), dim3(32, 8), 0, stream>>>(Wm, WmT);
    transpose_w<<<dim3(EXPN / 32, NPAD / 32), dim3(32, 8), 0, stream>>>(Wc, WcT);

    // 9) out = relu(Xe) @ Wm + Tk @ Wc  (fused K=16384 MFMA)
    gemm_out_mfma<<<dim3(NPAD / 128, MSAMP / 128), blk, 0, stream>>>(
        XeHi, Tk, WmT, WcT, out);
}

// Round 5
// 1947.089 us; speedup vs baseline: 5.6238x; 1.1221x over previous
//
#include <hip/hip_runtime.h>
#include <hip/hip_bf16.h>

#define MSAMP 4096
#define D0    512
#define EXPN  8192
#define NCLS  1000
#define NPAD  1024

typedef __attribute__((ext_vector_type(8))) short          short8;
typedef __attribute__((ext_vector_type(8))) unsigned short ushort8v;
typedef __attribute__((ext_vector_type(4))) float          f32x4;

__device__ __forceinline__ float bf2f(unsigned short u) {
    return __uint_as_float(((unsigned)u) << 16);
}
__device__ __forceinline__ unsigned short f2bf(float f) {   // RNE
    unsigned u = __float_as_uint(f);
    return (unsigned short)((u + 0x7FFFu + ((u >> 16) & 1u)) >> 16);
}
__device__ __forceinline__ ushort8v relu8(ushort8v v) {
#pragma unroll
    for (int j = 0; j < 8; ++j) v[j] = (v[j] & 0x8000u) ? (unsigned short)0 : v[j];
    return v;
}

// ---------------------------------------------------------------------------
// split f32 -> bf16 hi + residual lo  (elementwise, 8 per thread)
// ---------------------------------------------------------------------------
__global__ __launch_bounds__(256) void split_f32(const float* __restrict__ src,
                                                 unsigned short* __restrict__ hi,
                                                 unsigned short* __restrict__ lo)
{
    const size_t i = ((size_t)blockIdx.x * 256 + threadIdx.x) * 8;
    float4 v0 = *(const float4*)(src + i), v1 = *(const float4*)(src + i + 4);
    float vv[8] = {v0.x, v0.y, v0.z, v0.w, v1.x, v1.y, v1.z, v1.w};
    union { unsigned short u[8]; ushort8v v; } H, L;
#pragma unroll
    for (int j = 0; j < 8; ++j) {
        unsigned short h = f2bf(vv[j]);
        H.u[j] = h;
        L.u[j] = f2bf(vv[j] - bf2f(h));
    }
    *(ushort8v*)(hi + i) = H.v;
    *(ushort8v*)(lo + i) = L.v;
}

// ---------------------------------------------------------------------------
// Wb [512][8192] f32 -> WbT hi/lo bf16 [8192][512]
// ---------------------------------------------------------------------------
__global__ void transpose_split_wb(const float* __restrict__ src,
                                   unsigned short* __restrict__ dhi,
                                   unsigned short* __restrict__ dlo)
{
    __shared__ float t[32][33];
    const int n0 = blockIdx.x * 32, k0 = blockIdx.y * 32;
    const int tx = threadIdx.x, ty = threadIdx.y;
#pragma unroll
    for (int i = 0; i < 4; ++i)
        t[ty + 8 * i][tx] = src[(size_t)(k0 + ty + 8 * i) * EXPN + n0 + tx];
    __syncthreads();
#pragma unroll
    for (int i = 0; i < 4; ++i) {
        float v = t[tx][ty + 8 * i];
        unsigned short h = f2bf(v);
        dhi[(size_t)(n0 + ty + 8 * i) * D0 + k0 + tx] = h;
        dlo[(size_t)(n0 + ty + 8 * i) * D0 + k0 + tx] = f2bf(v - bf2f(h));
    }
}

// ---------------------------------------------------------------------------
// Xe = X @ Wb via split-bf16 MFMA (hh+hl+lh), NT, K=512.
// Epilogue: LDS-bounce coalesced XeHi/XeLo stores.
// Fragment-major LDS: frag arrays [8 mi][64 lane][8].
// ---------------------------------------------------------------------------
__global__ __launch_bounds__(256) void gemm_xe_mfma(
    const unsigned short* __restrict__ XHi, const unsigned short* __restrict__ XLo,
    const unsigned short* __restrict__ WHi, const unsigned short* __restrict__ WLo,
    unsigned short* __restrict__ XeHi, unsigned short* __restrict__ XeLo)
{
    __shared__ __align__(16) char smem[34816];
    unsigned short (*AhF)[64][8] = (unsigned short (*)[64][8])(smem);
    unsigned short (*AlF)[64][8] = (unsigned short (*)[64][8])(smem + 8192);
    unsigned short (*BhF)[64][8] = (unsigned short (*)[64][8])(smem + 16384);
    unsigned short (*BlF)[64][8] = (unsigned short (*)[64][8])(smem + 24576);

    const int tid = threadIdx.x;
    const int wid = tid >> 6, lane = tid & 63;
    const int l15 = lane & 15, q = lane >> 4;
    const int wm = (wid >> 1) * 64, wn = (wid & 1) * 64;
    const int row0 = blockIdx.y * 128, col0 = blockIdx.x * 128;

    const int sr = tid >> 1;               // 0..127
    const int scp = (tid & 1) * 2;         // chunk 0 or 2
    const int mi_w = sr >> 4, l_w = sr & 15;

    f32x4 acc[4][4];
#pragma unroll
    for (int m = 0; m < 4; ++m)
#pragma unroll
        for (int n = 0; n < 4; ++n) acc[m][n] = (f32x4){0.f, 0.f, 0.f, 0.f};

    for (int k0 = 0; k0 < D0; k0 += 32) {
        const unsigned short* pah = XHi + (size_t)(row0 + sr) * D0 + k0 + scp * 8;
        const unsigned short* pal = XLo + (size_t)(row0 + sr) * D0 + k0 + scp * 8;
        const unsigned short* pbh = WHi + (size_t)(col0 + sr) * D0 + k0 + scp * 8;
        const unsigned short* pbl = WLo + (size_t)(col0 + sr) * D0 + k0 + scp * 8;
        ushort8v ah0 = *(const ushort8v*)pah, ah1 = *(const ushort8v*)(pah + 8);
        ushort8v al0 = *(const ushort8v*)pal, al1 = *(const ushort8v*)(pal + 8);
        ushort8v bh0 = *(const ushort8v*)pbh, bh1 = *(const ushort8v*)(pbh + 8);
        ushort8v bl0 = *(const ushort8v*)pbl, bl1 = *(const ushort8v*)(pbl + 8);

        __syncthreads();
        *(ushort8v*)&AhF[mi_w][scp * 16 + l_w][0] = ah0;
        *(ushort8v*)&AhF[mi_w][(scp + 1) * 16 + l_w][0] = ah1;
        *(ushort8v*)&AlF[mi_w][scp * 16 + l_w][0] = al0;
        *(ushort8v*)&AlF[mi_w][(scp + 1) * 16 + l_w][0] = al1;
        *(ushort8v*)&BhF[mi_w][scp * 16 + l_w][0] = bh0;
        *(ushort8v*)&BhF[mi_w][(scp + 1) * 16 + l_w][0] = bh1;
        *(ushort8v*)&BlF[mi_w][scp * 16 + l_w][0] = bl0;
        *(ushort8v*)&BlF[mi_w][(scp + 1) * 16 + l_w][0] = bl1;
        __syncthreads();

        short8 fah[4], fal[4], fbh[4], fbl[4];
#pragma unroll
        for (int m = 0; m < 4; ++m) {
            fah[m] = *(const short8*)&AhF[(wm >> 4) + m][lane][0];
            fal[m] = *(const short8*)&AlF[(wm >> 4) + m][lane][0];
            fbh[m] = *(const short8*)&BhF[(wn >> 4) + m][lane][0];
            fbl[m] = *(const short8*)&BlF[(wn >> 4) + m][lane][0];
        }
#pragma unroll
        for (int m = 0; m < 4; ++m)
#pragma unroll
            for (int n = 0; n < 4; ++n) {
                acc[m][n] = __builtin_amdgcn_mfma_f32_16x16x32_bf16(fah[m], fbh[n], acc[m][n], 0, 0, 0);
                acc[m][n] = __builtin_amdgcn_mfma_f32_16x16x32_bf16(fah[m], fbl[n], acc[m][n], 0, 0, 0);
                acc[m][n] = __builtin_amdgcn_mfma_f32_16x16x32_bf16(fal[m], fbh[n], acc[m][n], 0, 0, 0);
            }
    }

    // ---- epilogue: LDS bounce, pass 1 = hi, pass 2 = lo ----
    unsigned short (*Cb)[136] = (unsigned short (*)[136])smem;
    const int rr = tid >> 1, hh = (tid & 1) * 64;

    __syncthreads();
#pragma unroll
    for (int m = 0; m < 4; ++m)
#pragma unroll
        for (int n = 0; n < 4; ++n)
#pragma unroll
            for (int r = 0; r < 4; ++r)
                Cb[wm + m * 16 + q * 4 + r][wn + n * 16 + l15] = f2bf(acc[m][n][r]);
    __syncthreads();
#pragma unroll
    for (int c = 0; c < 8; ++c)
        *(ushort8v*)&XeHi[(size_t)(row0 + rr) * EXPN + col0 + hh + c * 8] =
            *(const ushort8v*)&Cb[rr][hh + c * 8];

    __syncthreads();
#pragma unroll
    for (int m = 0; m < 4; ++m)
#pragma unroll
        for (int n = 0; n < 4; ++n)
#pragma unroll
            for (int r = 0; r < 4; ++r) {
                float v = acc[m][n][r];
                Cb[wm + m * 16 + q * 4 + r][wn + n * 16 + l15] = f2bf(v - bf2f(f2bf(v)));
            }
    __syncthreads();
#pragma unroll
    for (int c = 0; c < 8; ++c)
        *(ushort8v*)&XeLo[(size_t)(row0 + rr) * EXPN + col0 + hh + c * 8] =
            *(const ushort8v*)&Cb[rr][hh + c * 8];
}

// ---------------------------------------------------------------------------
// sim = (Xe @ Xe^T)*inv_i*inv_j, diag=-3e38. SYMMETRIC: 528 upper-tri blocks,
// mirror-writes. Split-bf16 MFMA (hh+hl+lh), fragment-major LDS.
// ---------------------------------------------------------------------------
__global__ __launch_bounds__(256) void gemm_sim(
    const unsigned short* __restrict__ XeHi, const unsigned short* __restrict__ XeLo,
    const float* __restrict__ invn, float* __restrict__ Sm)
{
    __shared__ unsigned short AhF[8][64][8], AlF[8][64][8];
    __shared__ unsigned short BhF[8][64][8], BlF[8][64][8];

    // triangular block decode: t -> (bi <= bj)
    const int t = blockIdx.x;
    int bj = (int)((sqrtf(8.0f * t + 1.0f) - 1.0f) * 0.5f);
    while ((bj + 1) * (bj + 2) / 2 <= t) ++bj;
    while (bj * (bj + 1) / 2 > t) --bj;
    const int bi = t - bj * (bj + 1) / 2;
    const int row0 = bi * 128, col0 = bj * 128;

    const int tid = threadIdx.x;
    const int wid = tid >> 6, lane = tid & 63;
    const int l15 = lane & 15, q = lane >> 4;
    const int wm = (wid >> 1) * 64, wn = (wid & 1) * 64;

    const int sr = tid >> 1;
    const int scp = (tid & 1) * 2;
    const int mi_w = sr >> 4, l_w = sr & 15;

    f32x4 acc[4][4];
#pragma unroll
    for (int m = 0; m < 4; ++m)
#pragma unroll
        for (int n = 0; n < 4; ++n) acc[m][n] = (f32x4){0.f, 0.f, 0.f, 0.f};

    for (int k0 = 0; k0 < EXPN; k0 += 32) {
        const unsigned short* pah = XeHi + (size_t)(row0 + sr) * EXPN + k0 + scp * 8;
        const unsigned short* pal = XeLo + (size_t)(row0 + sr) * EXPN + k0 + scp * 8;
        const unsigned short* pbh = XeHi + (size_t)(col0 + sr) * EXPN + k0 + scp * 8;
        const unsigned short* pbl = XeLo + (size_t)(col0 + sr) * EXPN + k0 + scp * 8;
        ushort8v ah0 = *(const ushort8v*)pah, ah1 = *(const ushort8v*)(pah + 8);
        ushort8v al0 = *(const ushort8v*)pal, al1 = *(const ushort8v*)(pal + 8);
        ushort8v bh0 = *(const ushort8v*)pbh, bh1 = *(const ushort8v*)(pbh + 8);
        ushort8v bl0 = *(const ushort8v*)pbl, bl1 = *(const ushort8v*)(pbl + 8);

        __syncthreads();
        *(ushort8v*)&AhF[mi_w][scp * 16 + l_w][0] = ah0;
        *(ushort8v*)&AhF[mi_w][(scp + 1) * 16 + l_w][0] = ah1;
        *(ushort8v*)&AlF[mi_w][scp * 16 + l_w][0] = al0;
        *(ushort8v*)&AlF[mi_w][(scp + 1) * 16 + l_w][0] = al1;
        *(ushort8v*)&BhF[mi_w][scp * 16 + l_w][0] = bh0;
        *(ushort8v*)&BhF[mi_w][(scp + 1) * 16 + l_w][0] = bh1;
        *(ushort8v*)&BlF[mi_w][scp * 16 + l_w][0] = bl0;
        *(ushort8v*)&BlF[mi_w][(scp + 1) * 16 + l_w][0] = bl1;
        __syncthreads();

        short8 fah[4], fal[4], fbh[4], fbl[4];
#pragma unroll
        for (int m = 0; m < 4; ++m) {
            fah[m] = *(const short8*)&AhF[(wm >> 4) + m][lane][0];
            fal[m] = *(const short8*)&AlF[(wm >> 4) + m][lane][0];
            fbh[m] = *(const short8*)&BhF[(wn >> 4) + m][lane][0];
            fbl[m] = *(const short8*)&BlF[(wn >> 4) + m][lane][0];
        }
#pragma unroll
        for (int m = 0; m < 4; ++m)
#pragma unroll
            for (int n = 0; n < 4; ++n) {
                acc[m][n] = __builtin_amdgcn_mfma_f32_16x16x32_bf16(fah[m], fbh[n], acc[m][n], 0, 0, 0);
                acc[m][n] = __builtin_amdgcn_mfma_f32_16x16x32_bf16(fah[m], fbl[n], acc[m][n], 0, 0, 0);
                acc[m][n] = __builtin_amdgcn_mfma_f32_16x16x32_bf16(fal[m], fbh[n], acc[m][n], 0, 0, 0);
            }
    }

    const bool mirror = (bi != bj);
#pragma unroll
    for (int m = 0; m < 4; ++m)
#pragma unroll
        for (int n = 0; n < 4; ++n) {
            const int gj = col0 + wn + n * 16 + l15;
            const float invj = invn[gj];
#pragma unroll
            for (int r = 0; r < 4; ++r) {
                const int gi = row0 + wm + m * 16 + q * 4 + r;
                float v = acc[m][n][r] * invn[gi] * invj;
                if (gi == gj) v = -3.0e38f;
                Sm[(size_t)gi * MSAMP + gj] = v;
                if (mirror) Sm[(size_t)gj * MSAMP + gi] = v;
            }
        }
}

// ---------------------------------------------------------------------------
// Tk(bf16) = tanh((1/k) * Adj @ Xe): A-frags from bitmask, B from XeT.
// ---------------------------------------------------------------------------
__global__ __launch_bounds__(256) void gemm_adj(
    const unsigned* __restrict__ Abits, const unsigned short* __restrict__ XeT,
    unsigned short* __restrict__ Tk, const int* __restrict__ kp)
{
    __shared__ unsigned short BhF[8][64][8];
    __shared__ unsigned aw[128];

    const int tid = threadIdx.x;
    const int wid = tid >> 6, lane = tid & 63;
    const int l15 = lane & 15, q = lane >> 4;
    const int wm = (wid >> 1) * 64, wn = (wid & 1) * 64;
    const int row0 = blockIdx.y * 128;
    const int col0 = blockIdx.x * 128;

    const int sr = tid >> 1;
    const int scp = (tid & 1) * 2;
    const int mi_w = sr >> 4, l_w = sr & 15;

    f32x4 acc[4][4];
#pragma unroll
    for (int m = 0; m < 4; ++m)
#pragma unroll
        for (int n = 0; n < 4; ++n) acc[m][n] = (f32x4){0.f, 0.f, 0.f, 0.f};

    for (int k0 = 0; k0 < MSAMP; k0 += 32) {
        const unsigned short* pb = XeT + (size_t)(col0 + sr) * MSAMP + k0 + scp * 8;
        ushort8v b0 = *(const ushort8v*)pb, b1 = *(const ushort8v*)(pb + 8);
        unsigned w = 0;
        if (tid < 128) w = Abits[(size_t)(row0 + tid) * (MSAMP / 32) + (k0 >> 5)];

        __syncthreads();
        *(ushort8v*)&BhF[mi_w][scp * 16 + l_w][0] = b0;
        *(ushort8v*)&BhF[mi_w][(scp + 1) * 16 + l_w][0] = b1;
        if (tid < 128) aw[tid] = w;
        __syncthreads();

        short8 fb[4];
#pragma unroll
        for (int n = 0; n < 4; ++n)
            fb[n] = *(const short8*)&BhF[(wn >> 4) + n][lane][0];
#pragma unroll
        for (int m = 0; m < 4; ++m) {
            const unsigned wrd = aw[wm + m * 16 + l15];
            const unsigned bits = (wrd >> (q * 8)) & 0xFFu;
            union { unsigned u[4]; short8 s; } fa;
#pragma unroll
            for (int p = 0; p < 4; ++p) {
                fa.u[p] = (((bits >> (2 * p)) & 1u) ? 0x3F80u : 0u) |
                          (((bits >> (2 * p + 1)) & 1u) ? 0x3F800000u : 0u);
            }
#pragma unroll
            for (int n = 0; n < 4; ++n)
                acc[m][n] = __builtin_amdgcn_mfma_f32_16x16x32_bf16(fa.s, fb[n], acc[m][n], 0, 0, 0);
        }
    }

    const float kv = 1.0f / (float)(*kp);
#pragma unroll
    for (int m = 0; m < 4; ++m)
#pragma unroll
        for (int n = 0; n < 4; ++n) {
            const int gj = col0 + wn + n * 16 + l15;
#pragma unroll
            for (int r = 0; r < 4; ++r) {
                const int gi = row0 + wm + m * 16 + q * 4 + r;
                Tk[(size_t)gi * EXPN + gj] = f2bf(tanhf(acc[m][n][r] * kv));
            }
        }
}

// ---------------------------------------------------------------------------
// Transpose+convert W: dst[n][k] = bf16(src[k][n]); zero-pad n to NPAD.
// ---------------------------------------------------------------------------
__global__ void transpose_w(const float* __restrict__ src,
                            unsigned short* __restrict__ dst)
{
    __shared__ float t[32][33];
    const int k0 = blockIdx.x * 32, n0 = blockIdx.y * 32;
    const int tx = threadIdx.x, ty = threadIdx.y;
#pragma unroll
    for (int i = 0; i < 4; ++i) {
        const int n = n0 + tx;
        t[ty + 8 * i][tx] = (n < NCLS) ? src[(size_t)(k0 + ty + 8 * i) * NCLS + n] : 0.f;
    }
    __syncthreads();
#pragma unroll
    for (int i = 0; i < 4; ++i)
        dst[(size_t)(n0 + ty + 8 * i) * EXPN + k0 + tx] = f2bf(t[tx][ty + 8 * i]);
}

// ---------------------------------------------------------------------------
// out = relu(XeHi) @ WmT^T + Tk @ WcT^T via MFMA, fused K=16384 loop.
// ---------------------------------------------------------------------------
__global__ __launch_bounds__(256) void gemm_out_mfma(
    const unsigned short* __restrict__ XeHi, const unsigned short* __restrict__ Tk,
    const unsigned short* __restrict__ WmT, const unsigned short* __restrict__ WcT,
    float* __restrict__ Cout)
{
    __shared__ unsigned short AsF[8][64][8], BsF[8][64][8];

    const int tid = threadIdx.x;
    const int wid = tid >> 6, lane = tid & 63;
    const int l15 = lane & 15, q = lane >> 4;
    const int wm = (wid >> 1) * 64, wn = (wid & 1) * 64;
    const int row0 = blockIdx.y * 128;
    const int col0 = blockIdx.x * 128;

    const int sr = tid >> 1;
    const int scp = (tid & 1) * 2;
    const int mi_w = sr >> 4, l_w = sr & 15;

    f32x4 acc[4][4];
#pragma unroll
    for (int m = 0; m < 4; ++m)
#pragma unroll
        for (int n = 0; n < 4; ++n) acc[m][n] = (f32x4){0.f, 0.f, 0.f, 0.f};

    for (int kt = 0; kt < 2 * EXPN; kt += 32) {
        const bool first = (kt < EXPN);
        const int k0 = first ? kt : kt - EXPN;
        const unsigned short* pa = (first ? XeHi : Tk) + (size_t)(row0 + sr) * EXPN + k0 + scp * 8;
        const unsigned short* pb = (first ? WmT : WcT) + (size_t)(col0 + sr) * EXPN + k0 + scp * 8;
        ushort8v a0 = *(const ushort8v*)pa, a1 = *(const ushort8v*)(pa + 8);
        ushort8v b0 = *(const ushort8v*)pb, b1 = *(const ushort8v*)(pb + 8);
        if (first) { a0 = relu8(a0); a1 = relu8(a1); }

        __syncthreads();
        *(ushort8v*)&AsF[mi_w][scp * 16 + l_w][0] = a0;
        *(ushort8v*)&AsF[mi_w][(scp + 1) * 16 + l_w][0] = a1;
        *(ushort8v*)&BsF[mi_w][scp * 16 + l_w][0] = b0;
        *(ushort8v*)&BsF[mi_w][(scp + 1) * 16 + l_w][0] = b1;
        __syncthreads();

        short8 fa[4], fb[4];
#pragma unroll
        for (int m = 0; m < 4; ++m) {
            fa[m] = *(const short8*)&AsF[(wm >> 4) + m][lane][0];
            fb[m] = *(const short8*)&BsF[(wn >> 4) + m][lane][0];
        }
#pragma unroll
        for (int m = 0; m < 4; ++m)
#pragma unroll
            for (int n = 0; n < 4; ++n)
                acc[m][n] = __builtin_amdgcn_mfma_f32_16x16x32_bf16(fa[m], fb[n], acc[m][n], 0, 0, 0);
    }

#pragma unroll
    for (int m = 0; m < 4; ++m)
#pragma unroll
        for (int n = 0; n < 4; ++n) {
            const int gj = col0 + wn + n * 16 + l15;
            if (gj < NCLS) {
#pragma unroll
                for (int r = 0; r < 4; ++r) {
                    const int gi = row0 + wm + m * 16 + q * 4 + r;
                    Cout[(size_t)gi * NCLS + gj] = acc[m][n][r];
                }
            }
        }
}

// ---------------------------------------------------------------------------
__global__ __launch_bounds__(256) void row_invnorm(
    const unsigned short* __restrict__ hi, const unsigned short* __restrict__ lo,
    float* __restrict__ invn)
{
    const int row = blockIdx.x;
    float s = 0.f;
    for (int j = threadIdx.x * 4; j < EXPN; j += 1024) {
        ushort4 h = *(const ushort4*)(hi + (size_t)row * EXPN + j);
        ushort4 l = *(const ushort4*)(lo + (size_t)row * EXPN + j);
        float x0 = bf2f(h.x) + bf2f(l.x), x1 = bf2f(h.y) + bf2f(l.y);
        float x2 = bf2f(h.z) + bf2f(l.z), x3 = bf2f(h.w) + bf2f(l.w);
        s += x0 * x0 + x1 * x1 + x2 * x2 + x3 * x3;
    }
#pragma unroll
    for (int off = 32; off > 0; off >>= 1) s += __shfl_down(s, off);
    __shared__ float wsum[4];
    if ((threadIdx.x & 63) == 0) wsum[threadIdx.x >> 6] = s;
    __syncthreads();
    if (threadIdx.x == 0)
        invn[row] = rsqrtf(wsum[0] + wsum[1] + wsum[2] + wsum[3]);
}

// ---------------------------------------------------------------------------
__global__ __launch_bounds__(256) void topk_thresh(const float* __restrict__ sim,
                                                   float* __restrict__ thr,
                                                   int N, const int* __restrict__ kp)
{
    const int row = blockIdx.x;
    const float* srow = sim + (size_t)row * N;
    __shared__ int hist[256];
    __shared__ unsigned s_prefix;
    __shared__ int s_rem;
    if (threadIdx.x == 0) { s_prefix = 0u; s_rem = *kp; }
    __syncthreads();

    for (int pass = 0; pass < 4; ++pass) {
        const int shift = 24 - 8 * pass;
        hist[threadIdx.x] = 0;
        __syncthreads();
        const unsigned prefix = s_prefix;
        const unsigned pmask = (pass == 0) ? 0u : (0xFFFFFFFFu << (shift + 8));
        for (int j = threadIdx.x; j < N; j += 256) {
            unsigned u = __float_as_uint(srow[j]);
            u = ((int)u < 0) ? ~u : (u | 0x80000000u);
            if ((u & pmask) == (prefix & pmask))
                atomicAdd(&hist[(u >> shift) & 255], 1);
        }
        __syncthreads();
        if (threadIdx.x == 0) {
            int rem = s_rem, accum = 0, b;
            for (b = 255; b > 0; --b) {
                if (accum + hist[b] >= rem) break;
                accum += hist[b];
            }
            s_rem = rem - accum;
            s_prefix = prefix | ((unsigned)b << shift);
        }
        __syncthreads();
    }

    if (threadIdx.x == 0) {
        const unsigned u = s_prefix;
        const unsigned orig = (u & 0x80000000u) ? (u & 0x7FFFFFFFu) : ~u;
        thr[row] = __uint_as_float(orig);
    }
}

// ---------------------------------------------------------------------------
__global__ __launch_bounds__(128) void bitpack(const float* __restrict__ Sm,
                                               const float* __restrict__ thr,
                                               unsigned* __restrict__ Abits)
{
    const int row = blockIdx.x;
    const int w = threadIdx.x;
    const float t = thr[row];
    const float* p = Sm + (size_t)row * MSAMP + w * 32;
    unsigned m = 0;
#pragma unroll
    for (int b = 0; b < 32; b += 4) {
        float4 v = *(const float4*)(p + b);
        m |= (v.x >= t ? 1u : 0u) << (b + 0);
        m |= (v.y >= t ? 1u : 0u) << (b + 1);
        m |= (v.z >= t ? 1u : 0u) << (b + 2);
        m |= (v.w >= t ? 1u : 0u) << (b + 3);
    }
    Abits[(size_t)row * (MSAMP / 32) + w] = m;
}

// ---------------------------------------------------------------------------
__global__ void transpose_bf16(const unsigned short* __restrict__ src,
                               unsigned short* __restrict__ dst)
{
    __shared__ unsigned short t[32][33];
    const int bx = blockIdx.x;
    const int by = blockIdx.y;
    const int tx = threadIdx.x, ty = threadIdx.y;
#pragma unroll
    for (int i = 0; i < 4; ++i)
        t[ty + 8 * i][tx] = src[(size_t)(by * 32 + ty + 8 * i) * EXPN + bx * 32 + tx];
    __syncthreads();
#pragma unroll
    for (int i = 0; i < 4; ++i)
        dst[(size_t)(bx * 32 + ty + 8 * i) * MSAMP + by * 32 + tx] = t[tx][ty + 8 * i];
}

// ---------------------------------------------------------------------------
extern "C" void kernel_launch(void* const* d_in, const int* in_sizes, int n_in,
                              void* d_out, int out_size, void* d_ws, size_t ws_size,
                              hipStream_t stream)
{
    const float* X  = (const float*)d_in[0];
    const float* Wb = (const float*)d_in[1];
    const float* Wm = (const float*)d_in[2];
    const float* Wc = (const float*)d_in[3];
    const int*   kp = (const int*)d_in[4];
    float* out = (float*)d_out;

    // Workspace (peak ~194 MiB, identical to known-good rounds 2-4):
    //  SEG0 [0,64M)    XeHi bf16 [4096][8192]
    //  SEG1 [64,128M)  XeLo -> XeT bf16 [8192][4096] -> WmT+WcT bf16
    //  SEG2 [128,192M) prep {WbTHi,WbTLo,XHi,XLo} -> Sm f32 -> Tk bf16
    //  [192M..)        Abits (2 MiB), invn, thr
    char* base = (char*)d_ws;
    const size_t SEG = (size_t)64 << 20;
    const size_t need = 3 * SEG + ((size_t)2 << 20) + 65536;
    if (ws_size < need) return;

    unsigned short* XeHi = (unsigned short*)base;
    unsigned short* XeLo = (unsigned short*)(base + SEG);
    unsigned short* XeT  = (unsigned short*)(base + SEG);        // overlay (after sim)
    unsigned short* WmT  = (unsigned short*)(base + SEG);        // overlay (after gemm_adj)
    unsigned short* WcT  = WmT + (size_t)NPAD * EXPN;
    // prep buffers in SEG2 (dead once gemm_xe_mfma completes; Sm overwrites)
    unsigned short* WbTHi = (unsigned short*)(base + 2 * SEG);               // 8 MB
    unsigned short* WbTLo = WbTHi + (size_t)EXPN * D0;                       // 8 MB
    unsigned short* XHi   = WbTLo + (size_t)EXPN * D0;                       // 4 MB
    unsigned short* XLo   = XHi + (size_t)MSAMP * D0;                        // 4 MB
    float*          Sm   = (float*)(base + 2 * SEG);
    unsigned short* Tk   = (unsigned short*)(base + 2 * SEG);    // overlay (after bitpack)
    unsigned*       Abits= (unsigned*)(base + 3 * SEG);
    float*          invn = (float*)(base + 3 * SEG + ((size_t)2 << 20));
    float*          thr  = invn + MSAMP;

    const dim3 blk(256);

    // 0) prep: split X, transpose+split Wb (into SEG2)
    split_f32<<<dim3((MSAMP * D0) / (256 * 8)), blk, 0, stream>>>(X, XHi, XLo);
    transpose_split_wb<<<dim3(EXPN / 32, D0 / 32), dim3(32, 8), 0, stream>>>(Wb, WbTHi, WbTLo);

    // 1) Xe = X @ Wb via split-bf16 MFMA -> XeHi/XeLo
    gemm_xe_mfma<<<dim3(EXPN / 128, MSAMP / 128), blk, 0, stream>>>(
        XHi, XLo, WbTHi, WbTLo, XeHi, XeLo);

    // 2) row inverse norms
    row_invnorm<<<dim3(MSAMP), blk, 0, stream>>>(XeHi, XeLo, invn);

    // 3) sim (symmetric: 528 upper-triangle blocks, mirrored writes)
    gemm_sim<<<dim3(528), blk, 0, stream>>>(XeHi, XeLo, invn, Sm);

    // 4) per-row k-th largest threshold (exact f32 radix select)
    topk_thresh<<<dim3(MSAMP), blk, 0, stream>>>(Sm, thr, MSAMP, kp);

    // 5) adjacency bitmask
    bitpack<<<dim3(MSAMP), dim3(128), 0, stream>>>(Sm, thr, Abits);

    // 6) XeT = XeHi^T (into dead XeLo region)
    transpose_bf16<<<dim3(EXPN / 32, MSAMP / 32), dim3(32, 8), 0, stream>>>(XeHi, XeT);

    // 7) Tk = tanh((1/k) Adj @ Xe) via MFMA — over dead Sm
    gemm_adj<<<dim3(EXPN / 128, MSAMP / 128), blk, 0, stream>>>(Abits, XeT, Tk, kp);

    // 8) W transposes (bf16 NT) into dead XeT region
    transpose_w<<<dim3(EXPN / 32, NPAD / 32), dim3(32, 8), 0, stream>>>(Wm, WmT);
    transpose_w<<<dim3(EXPN / 32, NPAD / 32), dim3(32, 8), 0, stream>>>(Wc, WcT);

    // 9) out = relu(Xe) @ Wm + Tk @ Wc (fused K=16384 MFMA)
    gemm_out_mfma<<<dim3(NPAD / 128, MSAMP / 128), blk, 0, stream>>>(
        XeHi, Tk, WmT, WcT, out);
}

// Round 6
// 1327.522 us; speedup vs baseline: 8.2484x; 1.4667x over previous
//
#include <hip/hip_runtime.h>
#include <hip/hip_bf16.h>

#define MSAMP 4096
#define D0    512
#define EXPN  8192
#define NCLS  1000
#define NPAD  1024

typedef __attribute__((ext_vector_type(8))) _Float16       half8;
typedef __attribute__((ext_vector_type(8))) unsigned short ushort8v;
typedef __attribute__((ext_vector_type(4))) float          f32x4;

__device__ __forceinline__ unsigned short f2h(float f) {
    union { _Float16 h; unsigned short u; } c; c.h = (_Float16)f; return c.u;
}
__device__ __forceinline__ float h2f(unsigned short u) {
    union { unsigned short u; _Float16 h; } c; c.u = u; return (float)c.h;
}
__device__ __forceinline__ ushort8v relu8h(ushort8v v) {   // f16 relu: sign bit
#pragma unroll
    for (int j = 0; j < 8; ++j) v[j] = (v[j] & 0x8000u) ? (unsigned short)0 : v[j];
    return v;
}
__device__ __forceinline__ half8 as_half8(const unsigned short* p) {
    return *(const half8*)p;
}

// ---------------------------------------------------------------------------
// X f32 [4096][512] -> f16
// ---------------------------------------------------------------------------
__global__ __launch_bounds__(256) void cvt_x(const float* __restrict__ src,
                                             unsigned short* __restrict__ dst)
{
    const size_t i = ((size_t)blockIdx.x * 256 + threadIdx.x) * 8;
    float4 v0 = *(const float4*)(src + i), v1 = *(const float4*)(src + i + 4);
    union { unsigned short u[8]; ushort8v v; } H;
    H.u[0] = f2h(v0.x); H.u[1] = f2h(v0.y); H.u[2] = f2h(v0.z); H.u[3] = f2h(v0.w);
    H.u[4] = f2h(v1.x); H.u[5] = f2h(v1.y); H.u[6] = f2h(v1.z); H.u[7] = f2h(v1.w);
    *(ushort8v*)(dst + i) = H.v;
}

// ---------------------------------------------------------------------------
// Wb [512][8192] f32 -> WbT f16 [8192][512]
// ---------------------------------------------------------------------------
__global__ void transpose_wb(const float* __restrict__ src,
                             unsigned short* __restrict__ dst)
{
    __shared__ float t[32][33];
    const int n0 = blockIdx.x * 32, k0 = blockIdx.y * 32;
    const int tx = threadIdx.x, ty = threadIdx.y;
#pragma unroll
    for (int i = 0; i < 4; ++i)
        t[ty + 8 * i][tx] = src[(size_t)(k0 + ty + 8 * i) * EXPN + n0 + tx];
    __syncthreads();
#pragma unroll
    for (int i = 0; i < 4; ++i)
        dst[(size_t)(n0 + ty + 8 * i) * D0 + k0 + tx] = f2h(t[tx][ty + 8 * i]);
}

// ---------------------------------------------------------------------------
// Xe(f16) = X @ Wb via f16 MFMA, NT, K=512. Fragment-major LDS.
// Epilogue: LDS-bounce coalesced f16 stores.
// ---------------------------------------------------------------------------
__global__ __launch_bounds__(256) void gemm_xe_mfma(
    const unsigned short* __restrict__ Xh, const unsigned short* __restrict__ WbT,
    unsigned short* __restrict__ Xe)
{
    __shared__ __align__(16) char smem[34816];
    unsigned short (*AsF)[64][8] = (unsigned short (*)[64][8])(smem);
    unsigned short (*BsF)[64][8] = (unsigned short (*)[64][8])(smem + 8192);

    const int tid = threadIdx.x;
    const int wid = tid >> 6, lane = tid & 63;
    const int l15 = lane & 15, q = lane >> 4;
    const int wm = (wid >> 1) * 64, wn = (wid & 1) * 64;
    const int row0 = blockIdx.y * 128, col0 = blockIdx.x * 128;

    const int sr = tid >> 1;
    const int scp = (tid & 1) * 2;
    const int mi_w = sr >> 4, l_w = sr & 15;

    f32x4 acc[4][4];
#pragma unroll
    for (int m = 0; m < 4; ++m)
#pragma unroll
        for (int n = 0; n < 4; ++n) acc[m][n] = (f32x4){0.f, 0.f, 0.f, 0.f};

    for (int k0 = 0; k0 < D0; k0 += 32) {
        const unsigned short* pa = Xh  + (size_t)(row0 + sr) * D0 + k0 + scp * 8;
        const unsigned short* pb = WbT + (size_t)(col0 + sr) * D0 + k0 + scp * 8;
        ushort8v a0 = *(const ushort8v*)pa, a1 = *(const ushort8v*)(pa + 8);
        ushort8v b0 = *(const ushort8v*)pb, b1 = *(const ushort8v*)(pb + 8);

        __syncthreads();
        *(ushort8v*)&AsF[mi_w][scp * 16 + l_w][0] = a0;
        *(ushort8v*)&AsF[mi_w][(scp + 1) * 16 + l_w][0] = a1;
        *(ushort8v*)&BsF[mi_w][scp * 16 + l_w][0] = b0;
        *(ushort8v*)&BsF[mi_w][(scp + 1) * 16 + l_w][0] = b1;
        __syncthreads();

        half8 fa[4], fb[4];
#pragma unroll
        for (int m = 0; m < 4; ++m) {
            fa[m] = as_half8(&AsF[(wm >> 4) + m][lane][0]);
            fb[m] = as_half8(&BsF[(wn >> 4) + m][lane][0]);
        }
#pragma unroll
        for (int m = 0; m < 4; ++m)
#pragma unroll
            for (int n = 0; n < 4; ++n)
                acc[m][n] = __builtin_amdgcn_mfma_f32_16x16x32_f16(fa[m], fb[n], acc[m][n], 0, 0, 0);
    }

    // epilogue: LDS bounce -> coalesced f16 stores
    unsigned short (*Cb)[136] = (unsigned short (*)[136])smem;
    const int rr = tid >> 1, hh = (tid & 1) * 64;
    __syncthreads();
#pragma unroll
    for (int m = 0; m < 4; ++m)
#pragma unroll
        for (int n = 0; n < 4; ++n)
#pragma unroll
            for (int r = 0; r < 4; ++r)
                Cb[wm + m * 16 + q * 4 + r][wn + n * 16 + l15] = f2h(acc[m][n][r]);
    __syncthreads();
#pragma unroll
    for (int c = 0; c < 8; ++c)
        *(ushort8v*)&Xe[(size_t)(row0 + rr) * EXPN + col0 + hh + c * 8] =
            *(const ushort8v*)&Cb[rr][hh + c * 8];
}

// ---------------------------------------------------------------------------
// sim = (Xe @ Xe^T)*inv_i*inv_j, diag=-3e38. 528 upper-tri blocks + mirror.
// Single f16 MFMA product, fragment-major LDS (16 KiB).
// ---------------------------------------------------------------------------
__global__ __launch_bounds__(256) void gemm_sim(
    const unsigned short* __restrict__ Xe,
    const float* __restrict__ invn, float* __restrict__ Sm)
{
    __shared__ unsigned short AsF[8][64][8], BsF[8][64][8];

    const int t = blockIdx.x;
    int bj = (int)((sqrtf(8.0f * t + 1.0f) - 1.0f) * 0.5f);
    while ((bj + 1) * (bj + 2) / 2 <= t) ++bj;
    while (bj * (bj + 1) / 2 > t) --bj;
    const int bi = t - bj * (bj + 1) / 2;
    const int row0 = bi * 128, col0 = bj * 128;

    const int tid = threadIdx.x;
    const int wid = tid >> 6, lane = tid & 63;
    const int l15 = lane & 15, q = lane >> 4;
    const int wm = (wid >> 1) * 64, wn = (wid & 1) * 64;

    const int sr = tid >> 1;
    const int scp = (tid & 1) * 2;
    const int mi_w = sr >> 4, l_w = sr & 15;

    f32x4 acc[4][4];
#pragma unroll
    for (int m = 0; m < 4; ++m)
#pragma unroll
        for (int n = 0; n < 4; ++n) acc[m][n] = (f32x4){0.f, 0.f, 0.f, 0.f};

    for (int k0 = 0; k0 < EXPN; k0 += 32) {
        const unsigned short* pa = Xe + (size_t)(row0 + sr) * EXPN + k0 + scp * 8;
        const unsigned short* pb = Xe + (size_t)(col0 + sr) * EXPN + k0 + scp * 8;
        ushort8v a0 = *(const ushort8v*)pa, a1 = *(const ushort8v*)(pa + 8);
        ushort8v b0 = *(const ushort8v*)pb, b1 = *(const ushort8v*)(pb + 8);

        __syncthreads();
        *(ushort8v*)&AsF[mi_w][scp * 16 + l_w][0] = a0;
        *(ushort8v*)&AsF[mi_w][(scp + 1) * 16 + l_w][0] = a1;
        *(ushort8v*)&BsF[mi_w][scp * 16 + l_w][0] = b0;
        *(ushort8v*)&BsF[mi_w][(scp + 1) * 16 + l_w][0] = b1;
        __syncthreads();

        half8 fa[4], fb[4];
#pragma unroll
        for (int m = 0; m < 4; ++m) {
            fa[m] = as_half8(&AsF[(wm >> 4) + m][lane][0]);
            fb[m] = as_half8(&BsF[(wn >> 4) + m][lane][0]);
        }
#pragma unroll
        for (int m = 0; m < 4; ++m)
#pragma unroll
            for (int n = 0; n < 4; ++n)
                acc[m][n] = __builtin_amdgcn_mfma_f32_16x16x32_f16(fa[m], fb[n], acc[m][n], 0, 0, 0);
    }

    const bool mirror = (bi != bj);
#pragma unroll
    for (int m = 0; m < 4; ++m)
#pragma unroll
        for (int n = 0; n < 4; ++n) {
            const int gj = col0 + wn + n * 16 + l15;
            const float invj = invn[gj];
#pragma unroll
            for (int r = 0; r < 4; ++r) {
                const int gi = row0 + wm + m * 16 + q * 4 + r;
                float v = acc[m][n][r] * invn[gi] * invj;
                if (gi == gj) v = -3.0e38f;
                Sm[(size_t)gi * MSAMP + gj] = v;
                if (mirror) Sm[(size_t)gj * MSAMP + gi] = v;
            }
        }
}

// ---------------------------------------------------------------------------
// Tk(f16) = tanh((1/k) * Adj @ Xe): A-frags from bitmask, B from XeT.
// Grid: x = m-tiles (32), y = n-tiles (64)  [consecutive blocks share B-tile].
// ---------------------------------------------------------------------------
__global__ __launch_bounds__(256) void gemm_adj(
    const unsigned* __restrict__ Abits, const unsigned short* __restrict__ XeT,
    unsigned short* __restrict__ Tk, const int* __restrict__ kp)
{
    __shared__ unsigned short BsF[8][64][8];
    __shared__ unsigned aw[128];

    const int tid = threadIdx.x;
    const int wid = tid >> 6, lane = tid & 63;
    const int l15 = lane & 15, q = lane >> 4;
    const int wm = (wid >> 1) * 64, wn = (wid & 1) * 64;
    const int row0 = blockIdx.x * 128;   // m over 4096
    const int col0 = blockIdx.y * 128;   // n over 8192

    const int sr = tid >> 1;
    const int scp = (tid & 1) * 2;
    const int mi_w = sr >> 4, l_w = sr & 15;

    f32x4 acc[4][4];
#pragma unroll
    for (int m = 0; m < 4; ++m)
#pragma unroll
        for (int n = 0; n < 4; ++n) acc[m][n] = (f32x4){0.f, 0.f, 0.f, 0.f};

    for (int k0 = 0; k0 < MSAMP; k0 += 32) {
        const unsigned short* pb = XeT + (size_t)(col0 + sr) * MSAMP + k0 + scp * 8;
        ushort8v b0 = *(const ushort8v*)pb, b1 = *(const ushort8v*)(pb + 8);
        unsigned w = 0;
        if (tid < 128) w = Abits[(size_t)(row0 + tid) * (MSAMP / 32) + (k0 >> 5)];

        __syncthreads();
        *(ushort8v*)&BsF[mi_w][scp * 16 + l_w][0] = b0;
        *(ushort8v*)&BsF[mi_w][(scp + 1) * 16 + l_w][0] = b1;
        if (tid < 128) aw[tid] = w;
        __syncthreads();

        half8 fb[4];
#pragma unroll
        for (int n = 0; n < 4; ++n)
            fb[n] = as_half8(&BsF[(wn >> 4) + n][lane][0]);
#pragma unroll
        for (int m = 0; m < 4; ++m) {
            const unsigned wrd = aw[wm + m * 16 + l15];
            const unsigned bits = (wrd >> (q * 8)) & 0xFFu;
            union { unsigned u[4]; half8 h; } fa;
#pragma unroll
            for (int p = 0; p < 4; ++p) {
                fa.u[p] = (((bits >> (2 * p)) & 1u) ? 0x3C00u : 0u) |
                          (((bits >> (2 * p + 1)) & 1u) ? 0x3C000000u : 0u);
            }
#pragma unroll
            for (int n = 0; n < 4; ++n)
                acc[m][n] = __builtin_amdgcn_mfma_f32_16x16x32_f16(fa.h, fb[n], acc[m][n], 0, 0, 0);
        }
    }

    const float kv = 1.0f / (float)(*kp);
#pragma unroll
    for (int m = 0; m < 4; ++m)
#pragma unroll
        for (int n = 0; n < 4; ++n) {
            const int gj = col0 + wn + n * 16 + l15;
#pragma unroll
            for (int r = 0; r < 4; ++r) {
                const int gi = row0 + wm + m * 16 + q * 4 + r;
                Tk[(size_t)gi * EXPN + gj] = f2h(tanhf(acc[m][n][r] * kv));
            }
        }
}

// ---------------------------------------------------------------------------
// W [8192][1000] f32 -> WT f16 [NPAD][8192], zero-padded rows.
// ---------------------------------------------------------------------------
__global__ void transpose_w(const float* __restrict__ src,
                            unsigned short* __restrict__ dst)
{
    __shared__ float t[32][33];
    const int k0 = blockIdx.x * 32, n0 = blockIdx.y * 32;
    const int tx = threadIdx.x, ty = threadIdx.y;
#pragma unroll
    for (int i = 0; i < 4; ++i) {
        const int n = n0 + tx;
        t[ty + 8 * i][tx] = (n < NCLS) ? src[(size_t)(k0 + ty + 8 * i) * NCLS + n] : 0.f;
    }
    __syncthreads();
#pragma unroll
    for (int i = 0; i < 4; ++i)
        dst[(size_t)(n0 + ty + 8 * i) * EXPN + k0 + tx] = f2h(t[tx][ty + 8 * i]);
}

// ---------------------------------------------------------------------------
// out = relu(Xe) @ WmT^T + Tk @ WcT^T via f16 MFMA, fused K=16384 loop.
// ---------------------------------------------------------------------------
__global__ __launch_bounds__(256) void gemm_out_mfma(
    const unsigned short* __restrict__ Xe, const unsigned short* __restrict__ Tk,
    const unsigned short* __restrict__ WmT, const unsigned short* __restrict__ WcT,
    float* __restrict__ Cout)
{
    __shared__ unsigned short AsF[8][64][8], BsF[8][64][8];

    const int tid = threadIdx.x;
    const int wid = tid >> 6, lane = tid & 63;
    const int l15 = lane & 15, q = lane >> 4;
    const int wm = (wid >> 1) * 64, wn = (wid & 1) * 64;
    const int row0 = blockIdx.y * 128;
    const int col0 = blockIdx.x * 128;

    const int sr = tid >> 1;
    const int scp = (tid & 1) * 2;
    const int mi_w = sr >> 4, l_w = sr & 15;

    f32x4 acc[4][4];
#pragma unroll
    for (int m = 0; m < 4; ++m)
#pragma unroll
        for (int n = 0; n < 4; ++n) acc[m][n] = (f32x4){0.f, 0.f, 0.f, 0.f};

    for (int kt = 0; kt < 2 * EXPN; kt += 32) {
        const bool first = (kt < EXPN);
        const int k0 = first ? kt : kt - EXPN;
        const unsigned short* pa = (first ? Xe : Tk) + (size_t)(row0 + sr) * EXPN + k0 + scp * 8;
        const unsigned short* pb = (first ? WmT : WcT) + (size_t)(col0 + sr) * EXPN + k0 + scp * 8;
        ushort8v a0 = *(const ushort8v*)pa, a1 = *(const ushort8v*)(pa + 8);
        ushort8v b0 = *(const ushort8v*)pb, b1 = *(const ushort8v*)(pb + 8);
        if (first) { a0 = relu8h(a0); a1 = relu8h(a1); }

        __syncthreads();
        *(ushort8v*)&AsF[mi_w][scp * 16 + l_w][0] = a0;
        *(ushort8v*)&AsF[mi_w][(scp + 1) * 16 + l_w][0] = a1;
        *(ushort8v*)&BsF[mi_w][scp * 16 + l_w][0] = b0;
        *(ushort8v*)&BsF[mi_w][(scp + 1) * 16 + l_w][0] = b1;
        __syncthreads();

        half8 fa[4], fb[4];
#pragma unroll
        for (int m = 0; m < 4; ++m) {
            fa[m] = as_half8(&AsF[(wm >> 4) + m][lane][0]);
            fb[m] = as_half8(&BsF[(wn >> 4) + m][lane][0]);
        }
#pragma unroll
        for (int m = 0; m < 4; ++m)
#pragma unroll
            for (int n = 0; n < 4; ++n)
                acc[m][n] = __builtin_amdgcn_mfma_f32_16x16x32_f16(fa[m], fb[n], acc[m][n], 0, 0, 0);
    }

#pragma unroll
    for (int m = 0; m < 4; ++m)
#pragma unroll
        for (int n = 0; n < 4; ++n) {
            const int gj = col0 + wn + n * 16 + l15;
            if (gj < NCLS) {
#pragma unroll
                for (int r = 0; r < 4; ++r) {
                    const int gi = row0 + wm + m * 16 + q * 4 + r;
                    Cout[(size_t)gi * NCLS + gj] = acc[m][n][r];
                }
            }
        }
}

// ---------------------------------------------------------------------------
__global__ __launch_bounds__(256) void row_invnorm(
    const unsigned short* __restrict__ Xe, float* __restrict__ invn)
{
    const int row = blockIdx.x;
    float s = 0.f;
    for (int j = threadIdx.x * 8; j < EXPN; j += 2048) {
        ushort8v h = *(const ushort8v*)(Xe + (size_t)row * EXPN + j);
#pragma unroll
        for (int c = 0; c < 8; ++c) { float x = h2f(h[c]); s += x * x; }
    }
#pragma unroll
    for (int off = 32; off > 0; off >>= 1) s += __shfl_down(s, off);
    __shared__ float wsum[4];
    if ((threadIdx.x & 63) == 0) wsum[threadIdx.x >> 6] = s;
    __syncthreads();
    if (threadIdx.x == 0)
        invn[row] = rsqrtf(wsum[0] + wsum[1] + wsum[2] + wsum[3]);
}

// ---------------------------------------------------------------------------
__global__ __launch_bounds__(256) void topk_thresh(const float* __restrict__ sim,
                                                   float* __restrict__ thr,
                                                   int N, const int* __restrict__ kp)
{
    const int row = blockIdx.x;
    const float* srow = sim + (size_t)row * N;
    __shared__ int hist[256];
    __shared__ unsigned s_prefix;
    __shared__ int s_rem;
    if (threadIdx.x == 0) { s_prefix = 0u; s_rem = *kp; }
    __syncthreads();

    for (int pass = 0; pass < 4; ++pass) {
        const int shift = 24 - 8 * pass;
        hist[threadIdx.x] = 0;
        __syncthreads();
        const unsigned prefix = s_prefix;
        const unsigned pmask = (pass == 0) ? 0u : (0xFFFFFFFFu << (shift + 8));
        for (int j = threadIdx.x; j < N; j += 256) {
            unsigned u = __float_as_uint(srow[j]);
            u = ((int)u < 0) ? ~u : (u | 0x80000000u);
            if ((u & pmask) == (prefix & pmask))
                atomicAdd(&hist[(u >> shift) & 255], 1);
        }
        __syncthreads();
        if (threadIdx.x == 0) {
            int rem = s_rem, accum = 0, b;
            for (b = 255; b > 0; --b) {
                if (accum + hist[b] >= rem) break;
                accum += hist[b];
            }
            s_rem = rem - accum;
            s_prefix = prefix | ((unsigned)b << shift);
        }
        __syncthreads();
    }

    if (threadIdx.x == 0) {
        const unsigned u = s_prefix;
        const unsigned orig = (u & 0x80000000u) ? (u & 0x7FFFFFFFu) : ~u;
        thr[row] = __uint_as_float(orig);
    }
}

// ---------------------------------------------------------------------------
__global__ __launch_bounds__(128) void bitpack(const float* __restrict__ Sm,
                                               const float* __restrict__ thr,
                                               unsigned* __restrict__ Abits)
{
    const int row = blockIdx.x;
    const int w = threadIdx.x;
    const float t = thr[row];
    const float* p = Sm + (size_t)row * MSAMP + w * 32;
    unsigned m = 0;
#pragma unroll
    for (int b = 0; b < 32; b += 4) {
        float4 v = *(const float4*)(p + b);
        m |= (v.x >= t ? 1u : 0u) << (b + 0);
        m |= (v.y >= t ? 1u : 0u) << (b + 1);
        m |= (v.z >= t ? 1u : 0u) << (b + 2);
        m |= (v.w >= t ? 1u : 0u) << (b + 3);
    }
    Abits[(size_t)row * (MSAMP / 32) + w] = m;
}

// ---------------------------------------------------------------------------
// XeT[n][m] = Xe[m][n]  (ushort/f16 transpose, 32x32 tiles)
// ---------------------------------------------------------------------------
__global__ void transpose_xe(const unsigned short* __restrict__ src,
                             unsigned short* __restrict__ dst)
{
    __shared__ unsigned short t[32][33];
    const int bx = blockIdx.x;
    const int by = blockIdx.y;
    const int tx = threadIdx.x, ty = threadIdx.y;
#pragma unroll
    for (int i = 0; i < 4; ++i)
        t[ty + 8 * i][tx] = src[(size_t)(by * 32 + ty + 8 * i) * EXPN + bx * 32 + tx];
    __syncthreads();
#pragma unroll
    for (int i = 0; i < 4; ++i)
        dst[(size_t)(bx * 32 + ty + 8 * i) * MSAMP + by * 32 + tx] = t[tx][ty + 8 * i];
}

// ---------------------------------------------------------------------------
extern "C" void kernel_launch(void* const* d_in, const int* in_sizes, int n_in,
                              void* d_out, int out_size, void* d_ws, size_t ws_size,
                              hipStream_t stream)
{
    const float* X  = (const float*)d_in[0];
    const float* Wb = (const float*)d_in[1];
    const float* Wm = (const float*)d_in[2];
    const float* Wc = (const float*)d_in[3];
    const int*   kp = (const int*)d_in[4];
    float* out = (float*)d_out;

    // Workspace (peak ~194 MiB, same envelope as rounds 2-5):
    //  SEG0 [0,64M)    Xe f16 [4096][8192]
    //  SEG1 [64,128M)  XeT f16 [8192][4096] -> WmT+WcT f16 [1024][8192] x2
    //  SEG2 [128,192M) prep {Xh 4M, WbT 8M} -> Sm f32 -> Tk f16
    //  [192M..)        Abits (2 MiB), invn, thr
    char* base = (char*)d_ws;
    const size_t SEG = (size_t)64 << 20;
    const size_t need = 3 * SEG + ((size_t)2 << 20) + 65536;
    if (ws_size < need) return;

    unsigned short* Xe   = (unsigned short*)base;
    unsigned short* XeT  = (unsigned short*)(base + SEG);
    unsigned short* WmT  = (unsigned short*)(base + SEG);        // overlay (after gemm_adj)
    unsigned short* WcT  = WmT + (size_t)NPAD * EXPN;
    unsigned short* Xh   = (unsigned short*)(base + 2 * SEG);               // 4 MB
    unsigned short* WbT  = Xh + (size_t)MSAMP * D0;                         // 8 MB
    float*          Sm   = (float*)(base + 2 * SEG);             // overlay (after gemm_xe)
    unsigned short* Tk   = (unsigned short*)(base + 2 * SEG);    // overlay (after bitpack)
    unsigned*       Abits= (unsigned*)(base + 3 * SEG);
    float*          invn = (float*)(base + 3 * SEG + ((size_t)2 << 20));
    float*          thr  = invn + MSAMP;

    const dim3 blk(256);

    // 0) prep: X -> f16, Wb -> WbT f16
    cvt_x<<<dim3((MSAMP * D0) / (256 * 8)), blk, 0, stream>>>(X, Xh);
    transpose_wb<<<dim3(EXPN / 32, D0 / 32), dim3(32, 8), 0, stream>>>(Wb, WbT);

    // 1) Xe = X @ Wb (f16 MFMA)
    gemm_xe_mfma<<<dim3(EXPN / 128, MSAMP / 128), blk, 0, stream>>>(Xh, WbT, Xe);

    // 2) row inverse norms
    row_invnorm<<<dim3(MSAMP), blk, 0, stream>>>(Xe, invn);

    // 3) sim (symmetric: 528 upper-tri blocks, mirrored writes)
    gemm_sim<<<dim3(528), blk, 0, stream>>>(Xe, invn, Sm);

    // 4) per-row k-th largest threshold (exact f32 radix select)
    topk_thresh<<<dim3(MSAMP), blk, 0, stream>>>(Sm, thr, MSAMP, kp);

    // 5) adjacency bitmask
    bitpack<<<dim3(MSAMP), dim3(128), 0, stream>>>(Sm, thr, Abits);

    // 6) XeT = Xe^T (into SEG1)
    transpose_xe<<<dim3(EXPN / 32, MSAMP / 32), dim3(32, 8), 0, stream>>>(Xe, XeT);

    // 7) Tk = tanh((1/k) Adj @ Xe) via f16 MFMA — over dead Sm
    gemm_adj<<<dim3(MSAMP / 128, EXPN / 128), blk, 0, stream>>>(Abits, XeT, Tk, kp);

    // 8) W transposes (f16 NT) into dead XeT region
    transpose_w<<<dim3(EXPN / 32, NPAD / 32), dim3(32, 8), 0, stream>>>(Wm, WmT);
    transpose_w<<<dim3(EXPN / 32, NPAD / 32), dim3(32, 8), 0, stream>>>(Wc, WcT);

    // 9) out = relu(Xe) @ Wm + Tk @ Wc (fused K=16384 f16 MFMA)
    gemm_out_mfma<<<dim3(NPAD / 128, MSAMP / 128), blk, 0, stream>>>(
        Xe, Tk, WmT, WcT, out);
}

// Round 8
// 1220.358 us; speedup vs baseline: 8.9727x; 1.0878x over previous
//
#include <hip/hip_runtime.h>
#include <hip/hip_bf16.h>

#define MSAMP 4096
#define D0    512
#define EXPN  8192
#define NCLS  1000
#define NPAD  1024

typedef __attribute__((ext_vector_type(8))) _Float16       half8;
typedef __attribute__((ext_vector_type(8))) unsigned short ushort8v;
typedef __attribute__((ext_vector_type(4))) float          f32x4;

__device__ __forceinline__ unsigned short f2h(float f) {
    union { _Float16 h; unsigned short u; } c; c.h = (_Float16)f; return c.u;
}
__device__ __forceinline__ float h2f(unsigned short u) {
    union { unsigned short u; _Float16 h; } c; c.u = u; return (float)c.h;
}
__device__ __forceinline__ ushort8v relu8h(ushort8v v) {   // f16 relu: sign bit
#pragma unroll
    for (int j = 0; j < 8; ++j) v[j] = (v[j] & 0x8000u) ? (unsigned short)0 : v[j];
    return v;
}
__device__ __forceinline__ half8 as_half8(const unsigned short* p) {
    return *(const half8*)p;
}

// ---------------------------------------------------------------------------
// X f32 [4096][512] -> f16
// ---------------------------------------------------------------------------
__global__ __launch_bounds__(256) void cvt_x(const float* __restrict__ src,
                                             unsigned short* __restrict__ dst)
{
    const size_t i = ((size_t)blockIdx.x * 256 + threadIdx.x) * 8;
    float4 v0 = *(const float4*)(src + i), v1 = *(const float4*)(src + i + 4);
    union { unsigned short u[8]; ushort8v v; } H;
    H.u[0] = f2h(v0.x); H.u[1] = f2h(v0.y); H.u[2] = f2h(v0.z); H.u[3] = f2h(v0.w);
    H.u[4] = f2h(v1.x); H.u[5] = f2h(v1.y); H.u[6] = f2h(v1.z); H.u[7] = f2h(v1.w);
    *(ushort8v*)(dst + i) = H.v;
}

// ---------------------------------------------------------------------------
// Wb [512][8192] f32 -> WbT f16 [8192][512]
// ---------------------------------------------------------------------------
__global__ void transpose_wb(const float* __restrict__ src,
                             unsigned short* __restrict__ dst)
{
    __shared__ float t[32][33];
    const int n0 = blockIdx.x * 32, k0 = blockIdx.y * 32;
    const int tx = threadIdx.x, ty = threadIdx.y;
#pragma unroll
    for (int i = 0; i < 4; ++i)
        t[ty + 8 * i][tx] = src[(size_t)(k0 + ty + 8 * i) * EXPN + n0 + tx];
    __syncthreads();
#pragma unroll
    for (int i = 0; i < 4; ++i)
        dst[(size_t)(n0 + ty + 8 * i) * D0 + k0 + tx] = f2h(t[tx][ty + 8 * i]);
}

// ---------------------------------------------------------------------------
// Xe(f16) = X @ Wb via f16 MFMA, NT, K=512. Fragment-major LDS.
// ---------------------------------------------------------------------------
__global__ __launch_bounds__(256) void gemm_xe_mfma(
    const unsigned short* __restrict__ Xh, const unsigned short* __restrict__ WbT,
    unsigned short* __restrict__ Xe)
{
    __shared__ __align__(16) char smem[34816];
    unsigned short (*AsF)[64][8] = (unsigned short (*)[64][8])(smem);
    unsigned short (*BsF)[64][8] = (unsigned short (*)[64][8])(smem + 8192);

    const int tid = threadIdx.x;
    const int wid = tid >> 6, lane = tid & 63;
    const int l15 = lane & 15, q = lane >> 4;
    const int wm = (wid >> 1) * 64, wn = (wid & 1) * 64;
    const int row0 = blockIdx.y * 128, col0 = blockIdx.x * 128;

    const int sr = tid >> 1;
    const int scp = (tid & 1) * 2;
    const int mi_w = sr >> 4, l_w = sr & 15;

    f32x4 acc[4][4];
#pragma unroll
    for (int m = 0; m < 4; ++m)
#pragma unroll
        for (int n = 0; n < 4; ++n) acc[m][n] = (f32x4){0.f, 0.f, 0.f, 0.f};

    for (int k0 = 0; k0 < D0; k0 += 32) {
        const unsigned short* pa = Xh  + (size_t)(row0 + sr) * D0 + k0 + scp * 8;
        const unsigned short* pb = WbT + (size_t)(col0 + sr) * D0 + k0 + scp * 8;
        ushort8v a0 = *(const ushort8v*)pa, a1 = *(const ushort8v*)(pa + 8);
        ushort8v b0 = *(const ushort8v*)pb, b1 = *(const ushort8v*)(pb + 8);

        __syncthreads();
        *(ushort8v*)&AsF[mi_w][scp * 16 + l_w][0] = a0;
        *(ushort8v*)&AsF[mi_w][(scp + 1) * 16 + l_w][0] = a1;
        *(ushort8v*)&BsF[mi_w][scp * 16 + l_w][0] = b0;
        *(ushort8v*)&BsF[mi_w][(scp + 1) * 16 + l_w][0] = b1;
        __syncthreads();

        half8 fa[4], fb[4];
#pragma unroll
        for (int m = 0; m < 4; ++m) {
            fa[m] = as_half8(&AsF[(wm >> 4) + m][lane][0]);
            fb[m] = as_half8(&BsF[(wn >> 4) + m][lane][0]);
        }
#pragma unroll
        for (int m = 0; m < 4; ++m)
#pragma unroll
            for (int n = 0; n < 4; ++n)
                acc[m][n] = __builtin_amdgcn_mfma_f32_16x16x32_f16(fa[m], fb[n], acc[m][n], 0, 0, 0);
    }

    unsigned short (*Cb)[136] = (unsigned short (*)[136])smem;
    const int rr = tid >> 1, hh = (tid & 1) * 64;
    __syncthreads();
#pragma unroll
    for (int m = 0; m < 4; ++m)
#pragma unroll
        for (int n = 0; n < 4; ++n)
#pragma unroll
            for (int r = 0; r < 4; ++r)
                Cb[wm + m * 16 + q * 4 + r][wn + n * 16 + l15] = f2h(acc[m][n][r]);
    __syncthreads();
#pragma unroll
    for (int c = 0; c < 8; ++c)
        *(ushort8v*)&Xe[(size_t)(row0 + rr) * EXPN + col0 + hh + c * 8] =
            *(const ushort8v*)&Cb[rr][hh + c * 8];
}

// ---------------------------------------------------------------------------
// sim = (Xe @ Xe^T)*inv_i*inv_j, diag=-3e38. 528 upper-tri blocks + mirror.
// ---------------------------------------------------------------------------
__global__ __launch_bounds__(256) void gemm_sim(
    const unsigned short* __restrict__ Xe,
    const float* __restrict__ invn, float* __restrict__ Sm)
{
    __shared__ unsigned short AsF[8][64][8], BsF[8][64][8];

    const int t = blockIdx.x;
    int bj = (int)((sqrtf(8.0f * t + 1.0f) - 1.0f) * 0.5f);
    while ((bj + 1) * (bj + 2) / 2 <= t) ++bj;
    while (bj * (bj + 1) / 2 > t) --bj;
    const int bi = t - bj * (bj + 1) / 2;
    const int row0 = bi * 128, col0 = bj * 128;

    const int tid = threadIdx.x;
    const int wid = tid >> 6, lane = tid & 63;
    const int l15 = lane & 15, q = lane >> 4;
    const int wm = (wid >> 1) * 64, wn = (wid & 1) * 64;

    const int sr = tid >> 1;
    const int scp = (tid & 1) * 2;
    const int mi_w = sr >> 4, l_w = sr & 15;

    f32x4 acc[4][4];
#pragma unroll
    for (int m = 0; m < 4; ++m)
#pragma unroll
        for (int n = 0; n < 4; ++n) acc[m][n] = (f32x4){0.f, 0.f, 0.f, 0.f};

    for (int k0 = 0; k0 < EXPN; k0 += 32) {
        const unsigned short* pa = Xe + (size_t)(row0 + sr) * EXPN + k0 + scp * 8;
        const unsigned short* pb = Xe + (size_t)(col0 + sr) * EXPN + k0 + scp * 8;
        ushort8v a0 = *(const ushort8v*)pa, a1 = *(const ushort8v*)(pa + 8);
        ushort8v b0 = *(const ushort8v*)pb, b1 = *(const ushort8v*)(pb + 8);

        __syncthreads();
        *(ushort8v*)&AsF[mi_w][scp * 16 + l_w][0] = a0;
        *(ushort8v*)&AsF[mi_w][(scp + 1) * 16 + l_w][0] = a1;
        *(ushort8v*)&BsF[mi_w][scp * 16 + l_w][0] = b0;
        *(ushort8v*)&BsF[mi_w][(scp + 1) * 16 + l_w][0] = b1;
        __syncthreads();

        half8 fa[4], fb[4];
#pragma unroll
        for (int m = 0; m < 4; ++m) {
            fa[m] = as_half8(&AsF[(wm >> 4) + m][lane][0]);
            fb[m] = as_half8(&BsF[(wn >> 4) + m][lane][0]);
        }
#pragma unroll
        for (int m = 0; m < 4; ++m)
#pragma unroll
            for (int n = 0; n < 4; ++n)
                acc[m][n] = __builtin_amdgcn_mfma_f32_16x16x32_f16(fa[m], fb[n], acc[m][n], 0, 0, 0);
    }

    const bool mirror = (bi != bj);
#pragma unroll
    for (int m = 0; m < 4; ++m)
#pragma unroll
        for (int n = 0; n < 4; ++n) {
            const int gj = col0 + wn + n * 16 + l15;
            const float invj = invn[gj];
#pragma unroll
            for (int r = 0; r < 4; ++r) {
                const int gi = row0 + wm + m * 16 + q * 4 + r;
                float v = acc[m][n][r] * invn[gi] * invj;
                if (gi == gj) v = -3.0e38f;
                Sm[(size_t)gi * MSAMP + gj] = v;
                if (mirror) Sm[(size_t)gj * MSAMP + gi] = v;
            }
        }
}

// ---------------------------------------------------------------------------
// Tk(f16) = tanh((1/k) * Adj @ Xe): A-frags from bitmask, B from XeT.
// ---------------------------------------------------------------------------
__global__ __launch_bounds__(256) void gemm_adj(
    const unsigned* __restrict__ Abits, const unsigned short* __restrict__ XeT,
    unsigned short* __restrict__ Tk, const int* __restrict__ kp)
{
    __shared__ unsigned short BsF[8][64][8];
    __shared__ unsigned aw[128];

    const int tid = threadIdx.x;
    const int wid = tid >> 6, lane = tid & 63;
    const int l15 = lane & 15, q = lane >> 4;
    const int wm = (wid >> 1) * 64, wn = (wid & 1) * 64;
    const int row0 = blockIdx.x * 128;   // m over 4096
    const int col0 = blockIdx.y * 128;   // n over 8192

    const int sr = tid >> 1;
    const int scp = (tid & 1) * 2;
    const int mi_w = sr >> 4, l_w = sr & 15;

    f32x4 acc[4][4];
#pragma unroll
    for (int m = 0; m < 4; ++m)
#pragma unroll
        for (int n = 0; n < 4; ++n) acc[m][n] = (f32x4){0.f, 0.f, 0.f, 0.f};

    for (int k0 = 0; k0 < MSAMP; k0 += 32) {
        const unsigned short* pb = XeT + (size_t)(col0 + sr) * MSAMP + k0 + scp * 8;
        ushort8v b0 = *(const ushort8v*)pb, b1 = *(const ushort8v*)(pb + 8);
        unsigned w = 0;
        if (tid < 128) w = Abits[(size_t)(row0 + tid) * (MSAMP / 32) + (k0 >> 5)];

        __syncthreads();
        *(ushort8v*)&BsF[mi_w][scp * 16 + l_w][0] = b0;
        *(ushort8v*)&BsF[mi_w][(scp + 1) * 16 + l_w][0] = b1;
        if (tid < 128) aw[tid] = w;
        __syncthreads();

        half8 fb[4];
#pragma unroll
        for (int n = 0; n < 4; ++n)
            fb[n] = as_half8(&BsF[(wn >> 4) + n][lane][0]);
#pragma unroll
        for (int m = 0; m < 4; ++m) {
            const unsigned wrd = aw[wm + m * 16 + l15];
            const unsigned bits = (wrd >> (q * 8)) & 0xFFu;
            union { unsigned u[4]; half8 h; } fa;
#pragma unroll
            for (int p = 0; p < 4; ++p) {
                fa.u[p] = (((bits >> (2 * p)) & 1u) ? 0x3C00u : 0u) |
                          (((bits >> (2 * p + 1)) & 1u) ? 0x3C000000u : 0u);
            }
#pragma unroll
            for (int n = 0; n < 4; ++n)
                acc[m][n] = __builtin_amdgcn_mfma_f32_16x16x32_f16(fa.h, fb[n], acc[m][n], 0, 0, 0);
        }
    }

    const float kv = 1.0f / (float)(*kp);
#pragma unroll
    for (int m = 0; m < 4; ++m)
#pragma unroll
        for (int n = 0; n < 4; ++n) {
            const int gj = col0 + wn + n * 16 + l15;
#pragma unroll
            for (int r = 0; r < 4; ++r) {
                const int gi = row0 + wm + m * 16 + q * 4 + r;
                Tk[(size_t)gi * EXPN + gj] = f2h(tanhf(acc[m][n][r] * kv));
            }
        }
}

// ---------------------------------------------------------------------------
// W [8192][1000] f32 -> WT f16 [NPAD][8192], zero-padded rows.
// ---------------------------------------------------------------------------
__global__ void transpose_w(const float* __restrict__ src,
                            unsigned short* __restrict__ dst)
{
    __shared__ float t[32][33];
    const int k0 = blockIdx.x * 32, n0 = blockIdx.y * 32;
    const int tx = threadIdx.x, ty = threadIdx.y;
#pragma unroll
    for (int i = 0; i < 4; ++i) {
        const int n = n0 + tx;
        t[ty + 8 * i][tx] = (n < NCLS) ? src[(size_t)(k0 + ty + 8 * i) * NCLS + n] : 0.f;
    }
    __syncthreads();
#pragma unroll
    for (int i = 0; i < 4; ++i)
        dst[(size_t)(n0 + ty + 8 * i) * EXPN + k0 + tx] = f2h(t[tx][ty + 8 * i]);
}

// ---------------------------------------------------------------------------
// Split-K=2, NO atomics: z=0 computes k in [0,8192) (relu(Xe)@WmT) -> Cout,
// z=1 computes k in [8192,16384) (Tk@WcT) -> Ppart. Plain stores, disjoint
// buffers; add_partials sums after the kernel boundary (XCD-safe).
// ---------------------------------------------------------------------------
__global__ __launch_bounds__(256) void gemm_out_split(
    const unsigned short* __restrict__ Xe, const unsigned short* __restrict__ Tk,
    const unsigned short* __restrict__ WmT, const unsigned short* __restrict__ WcT,
    float* __restrict__ Cout, float* __restrict__ Ppart)
{
    __shared__ unsigned short AsF[8][64][8], BsF[8][64][8];

    const int tid = threadIdx.x;
    const int wid = tid >> 6, lane = tid & 63;
    const int l15 = lane & 15, q = lane >> 4;
    const int wm = (wid >> 1) * 64, wn = (wid & 1) * 64;
    const int row0 = blockIdx.y * 128;
    const int col0 = blockIdx.x * 128;
    const bool first = (blockIdx.z == 0);

    const unsigned short* Abase = first ? Xe : Tk;
    const unsigned short* Bbase = first ? WmT : WcT;
    float* dst = first ? Cout : Ppart;

    const int sr = tid >> 1;
    const int scp = (tid & 1) * 2;
    const int mi_w = sr >> 4, l_w = sr & 15;

    f32x4 acc[4][4];
#pragma unroll
    for (int m = 0; m < 4; ++m)
#pragma unroll
        for (int n = 0; n < 4; ++n) acc[m][n] = (f32x4){0.f, 0.f, 0.f, 0.f};

    for (int k0 = 0; k0 < EXPN; k0 += 32) {
        const unsigned short* pa = Abase + (size_t)(row0 + sr) * EXPN + k0 + scp * 8;
        const unsigned short* pb = Bbase + (size_t)(col0 + sr) * EXPN + k0 + scp * 8;
        ushort8v a0 = *(const ushort8v*)pa, a1 = *(const ushort8v*)(pa + 8);
        ushort8v b0 = *(const ushort8v*)pb, b1 = *(const ushort8v*)(pb + 8);
        if (first) { a0 = relu8h(a0); a1 = relu8h(a1); }

        __syncthreads();
        *(ushort8v*)&AsF[mi_w][scp * 16 + l_w][0] = a0;
        *(ushort8v*)&AsF[mi_w][(scp + 1) * 16 + l_w][0] = a1;
        *(ushort8v*)&BsF[mi_w][scp * 16 + l_w][0] = b0;
        *(ushort8v*)&BsF[mi_w][(scp + 1) * 16 + l_w][0] = b1;
        __syncthreads();

        half8 fa[4], fb[4];
#pragma unroll
        for (int m = 0; m < 4; ++m) {
            fa[m] = as_half8(&AsF[(wm >> 4) + m][lane][0]);
            fb[m] = as_half8(&BsF[(wn >> 4) + m][lane][0]);
        }
#pragma unroll
        for (int m = 0; m < 4; ++m)
#pragma unroll
            for (int n = 0; n < 4; ++n)
                acc[m][n] = __builtin_amdgcn_mfma_f32_16x16x32_f16(fa[m], fb[n], acc[m][n], 0, 0, 0);
    }

#pragma unroll
    for (int m = 0; m < 4; ++m)
#pragma unroll
        for (int n = 0; n < 4; ++n) {
            const int gj = col0 + wn + n * 16 + l15;
            if (gj < NCLS) {
#pragma unroll
                for (int r = 0; r < 4; ++r) {
                    const int gi = row0 + wm + m * 16 + q * 4 + r;
                    dst[(size_t)gi * NCLS + gj] = acc[m][n][r];
                }
            }
        }
}

// ---------------------------------------------------------------------------
// out[i] += P[i]  (float4-vectorized; MSAMP*NCLS is divisible by 4)
// ---------------------------------------------------------------------------
__global__ __launch_bounds__(256) void add_partials(float* __restrict__ out,
                                                    const float* __restrict__ P,
                                                    int n4)
{
    const int i = blockIdx.x * 256 + threadIdx.x;
    if (i < n4) {
        float4 a = ((const float4*)out)[i];
        float4 b = ((const float4*)P)[i];
        a.x += b.x; a.y += b.y; a.z += b.z; a.w += b.w;
        ((float4*)out)[i] = a;
    }
}

// ---------------------------------------------------------------------------
__global__ __launch_bounds__(256) void row_invnorm(
    const unsigned short* __restrict__ Xe, float* __restrict__ invn)
{
    const int row = blockIdx.x;
    float s = 0.f;
    for (int j = threadIdx.x * 8; j < EXPN; j += 2048) {
        ushort8v h = *(const ushort8v*)(Xe + (size_t)row * EXPN + j);
#pragma unroll
        for (int c = 0; c < 8; ++c) { float x = h2f(h[c]); s += x * x; }
    }
#pragma unroll
    for (int off = 32; off > 0; off >>= 1) s += __shfl_down(s, off);
    __shared__ float wsum[4];
    if ((threadIdx.x & 63) == 0) wsum[threadIdx.x >> 6] = s;
    __syncthreads();
    if (threadIdx.x == 0)
        invn[row] = rsqrtf(wsum[0] + wsum[1] + wsum[2] + wsum[3]);
}

// ---------------------------------------------------------------------------
__global__ __launch_bounds__(256) void topk_thresh(const float* __restrict__ sim,
                                                   float* __restrict__ thr,
                                                   int N, const int* __restrict__ kp)
{
    const int row = blockIdx.x;
    const float* srow = sim + (size_t)row * N;
    __shared__ int hist[256];
    __shared__ unsigned s_prefix;
    __shared__ int s_rem;
    if (threadIdx.x == 0) { s_prefix = 0u; s_rem = *kp; }
    __syncthreads();

    for (int pass = 0; pass < 4; ++pass) {
        const int shift = 24 - 8 * pass;
        hist[threadIdx.x] = 0;
        __syncthreads();
        const unsigned prefix = s_prefix;
        const unsigned pmask = (pass == 0) ? 0u : (0xFFFFFFFFu << (shift + 8));
        for (int j = threadIdx.x; j < N; j += 256) {
            unsigned u = __float_as_uint(srow[j]);
            u = ((int)u < 0) ? ~u : (u | 0x80000000u);
            if ((u & pmask) == (prefix & pmask))
                atomicAdd(&hist[(u >> shift) & 255], 1);
        }
        __syncthreads();
        if (threadIdx.x == 0) {
            int rem = s_rem, accum = 0, b;
            for (b = 255; b > 0; --b) {
                if (accum + hist[b] >= rem) break;
                accum += hist[b];
            }
            s_rem = rem - accum;
            s_prefix = prefix | ((unsigned)b << shift);
        }
        __syncthreads();
    }

    if (threadIdx.x == 0) {
        const unsigned u = s_prefix;
        const unsigned orig = (u & 0x80000000u) ? (u & 0x7FFFFFFFu) : ~u;
        thr[row] = __uint_as_float(orig);
    }
}

// ---------------------------------------------------------------------------
__global__ __launch_bounds__(128) void bitpack(const float* __restrict__ Sm,
                                               const float* __restrict__ thr,
                                               unsigned* __restrict__ Abits)
{
    const int row = blockIdx.x;
    const int w = threadIdx.x;
    const float t = thr[row];
    const float* p = Sm + (size_t)row * MSAMP + w * 32;
    unsigned m = 0;
#pragma unroll
    for (int b = 0; b < 32; b += 4) {
        float4 v = *(const float4*)(p + b);
        m |= (v.x >= t ? 1u : 0u) << (b + 0);
        m |= (v.y >= t ? 1u : 0u) << (b + 1);
        m |= (v.z >= t ? 1u : 0u) << (b + 2);
        m |= (v.w >= t ? 1u : 0u) << (b + 3);
    }
    Abits[(size_t)row * (MSAMP / 32) + w] = m;
}

// ---------------------------------------------------------------------------
__global__ void transpose_xe(const unsigned short* __restrict__ src,
                             unsigned short* __restrict__ dst)
{
    __shared__ unsigned short t[32][33];
    const int bx = blockIdx.x;
    const int by = blockIdx.y;
    const int tx = threadIdx.x, ty = threadIdx.y;
#pragma unroll
    for (int i = 0; i < 4; ++i)
        t[ty + 8 * i][tx] = src[(size_t)(by * 32 + ty + 8 * i) * EXPN + bx * 32 + tx];
    __syncthreads();
#pragma unroll
    for (int i = 0; i < 4; ++i)
        dst[(size_t)(bx * 32 + ty + 8 * i) * MSAMP + by * 32 + tx] = t[tx][ty + 8 * i];
}

// ---------------------------------------------------------------------------
extern "C" void kernel_launch(void* const* d_in, const int* in_sizes, int n_in,
                              void* d_out, int out_size, void* d_ws, size_t ws_size,
                              hipStream_t stream)
{
    const float* X  = (const float*)d_in[0];
    const float* Wb = (const float*)d_in[1];
    const float* Wm = (const float*)d_in[2];
    const float* Wc = (const float*)d_in[3];
    const int*   kp = (const int*)d_in[4];
    float* out = (float*)d_out;

    // Workspace (peak ~194 MiB, same envelope as rounds 2-6):
    //  SEG0 [0,64M)    Xe f16 [4096][8192]
    //  SEG1 [64,128M)  XeT f16 [8192][4096] -> [WmT+WcT f16 32M | Ppart f32 16.4M]
    //  SEG2 [128,192M) prep {Xh 4M, WbT 8M} -> Sm f32 -> Tk f16
    //  [192M..)        Abits (2 MiB), invn, thr
    char* base = (char*)d_ws;
    const size_t SEG = (size_t)64 << 20;
    const size_t need = 3 * SEG + ((size_t)2 << 20) + 65536;
    if (ws_size < need) return;

    unsigned short* Xe   = (unsigned short*)base;
    unsigned short* XeT  = (unsigned short*)(base + SEG);
    unsigned short* WmT  = (unsigned short*)(base + SEG);        // overlay (after gemm_adj)
    unsigned short* WcT  = WmT + (size_t)NPAD * EXPN;            // +16 MiB
    float*          Ppart= (float*)(base + SEG + ((size_t)32 << 20)); // dead XeT tail, 16.4 MiB
    unsigned short* Xh   = (unsigned short*)(base + 2 * SEG);               // 4 MB
    unsigned short* WbT  = Xh + (size_t)MSAMP * D0;                         // 8 MB
    float*          Sm   = (float*)(base + 2 * SEG);             // overlay (after gemm_xe)
    unsigned short* Tk   = (unsigned short*)(base + 2 * SEG);    // overlay (after bitpack)
    unsigned*       Abits= (unsigned*)(base + 3 * SEG);
    float*          invn = (float*)(base + 3 * SEG + ((size_t)2 << 20));
    float*          thr  = invn + MSAMP;

    const dim3 blk(256);

    // 0) prep: X -> f16, Wb -> WbT f16
    cvt_x<<<dim3((MSAMP * D0) / (256 * 8)), blk, 0, stream>>>(X, Xh);
    transpose_wb<<<dim3(EXPN / 32, D0 / 32), dim3(32, 8), 0, stream>>>(Wb, WbT);

    // 1) Xe = X @ Wb (f16 MFMA)
    gemm_xe_mfma<<<dim3(EXPN / 128, MSAMP / 128), blk, 0, stream>>>(Xh, WbT, Xe);

    // 2) row inverse norms
    row_invnorm<<<dim3(MSAMP), blk, 0, stream>>>(Xe, invn);

    // 3) sim (symmetric: 528 upper-tri blocks, mirrored writes)
    gemm_sim<<<dim3(528), blk, 0, stream>>>(Xe, invn, Sm);

    // 4) per-row k-th largest threshold (exact f32 radix select)
    topk_thresh<<<dim3(MSAMP), blk, 0, stream>>>(Sm, thr, MSAMP, kp);

    // 5) adjacency bitmask
    bitpack<<<dim3(MSAMP), dim3(128), 0, stream>>>(Sm, thr, Abits);

    // 6) XeT = Xe^T (into SEG1)
    transpose_xe<<<dim3(EXPN / 32, MSAMP / 32), dim3(32, 8), 0, stream>>>(Xe, XeT);

    // 7) Tk = tanh((1/k) Adj @ Xe) via f16 MFMA — over dead Sm
    gemm_adj<<<dim3(MSAMP / 128, EXPN / 128), blk, 0, stream>>>(Abits, XeT, Tk, kp);

    // 8) W transposes (f16 NT) into dead XeT region
    transpose_w<<<dim3(EXPN / 32, NPAD / 32), dim3(32, 8), 0, stream>>>(Wm, WmT);
    transpose_w<<<dim3(EXPN / 32, NPAD / 32), dim3(32, 8), 0, stream>>>(Wc, WcT);

    // 9) split-K=2 output GEMM: z=0 -> out, z=1 -> Ppart (no atomics)
    gemm_out_split<<<dim3(NPAD / 128, MSAMP / 128, 2), blk, 0, stream>>>(
        Xe, Tk, WmT, WcT, out, Ppart);

    // 10) out += Ppart (kernel-boundary-ordered, XCD-safe)
    add_partials<<<dim3((MSAMP * NCLS / 4 + 255) / 256), blk, 0, stream>>>(
        out, Ppart, MSAMP * NCLS / 4);
}

// Round 9
// 1048.356 us; speedup vs baseline: 10.4449x; 1.1641x over previous
//
#include <hip/hip_runtime.h>
#include <hip/hip_bf16.h>

#define MSAMP 4096
#define D0    512
#define EXPN  8192
#define NCLS  1000
#define NPAD  1024
#define QSCALE     (6.0f / 127.0f)
#define QSCALE_INV (127.0f / 6.0f)

typedef __attribute__((ext_vector_type(8))) _Float16       half8;
typedef __attribute__((ext_vector_type(8))) unsigned short ushort8v;
typedef __attribute__((ext_vector_type(4))) float          f32x4;
typedef __attribute__((ext_vector_type(4))) int            i32x4v;

__device__ __forceinline__ unsigned short f2h(float f) {
    union { _Float16 h; unsigned short u; } c; c.h = (_Float16)f; return c.u;
}
__device__ __forceinline__ float h2f(unsigned short u) {
    union { unsigned short u; _Float16 h; } c; c.u = u; return (float)c.h;
}
__device__ __forceinline__ ushort8v relu8h(ushort8v v) {   // f16 relu: sign bit
#pragma unroll
    for (int j = 0; j < 8; ++j) v[j] = (v[j] & 0x8000u) ? (unsigned short)0 : v[j];
    return v;
}
__device__ __forceinline__ half8 as_half8(const unsigned short* p) {
    return *(const half8*)p;
}
__device__ __forceinline__ float tanh_fast(float x) {
    // |x| <= ~0.3 in this workload; formula robust for all x anyway.
    float e = __expf(2.0f * x);
    return 1.0f - 2.0f * __builtin_amdgcn_rcpf(e + 1.0f);
}

// ---------------------------------------------------------------------------
// X f32 [4096][512] -> f16
// ---------------------------------------------------------------------------
__global__ __launch_bounds__(256) void cvt_x(const float* __restrict__ src,
                                             unsigned short* __restrict__ dst)
{
    const size_t i = ((size_t)blockIdx.x * 256 + threadIdx.x) * 8;
    float4 v0 = *(const float4*)(src + i), v1 = *(const float4*)(src + i + 4);
    union { unsigned short u[8]; ushort8v v; } H;
    H.u[0] = f2h(v0.x); H.u[1] = f2h(v0.y); H.u[2] = f2h(v0.z); H.u[3] = f2h(v0.w);
    H.u[4] = f2h(v1.x); H.u[5] = f2h(v1.y); H.u[6] = f2h(v1.z); H.u[7] = f2h(v1.w);
    *(ushort8v*)(dst + i) = H.v;
}

// ---------------------------------------------------------------------------
// Wb [512][8192] f32 -> WbT f16 [8192][512]
// ---------------------------------------------------------------------------
__global__ void transpose_wb(const float* __restrict__ src,
                             unsigned short* __restrict__ dst)
{
    __shared__ float t[32][33];
    const int n0 = blockIdx.x * 32, k0 = blockIdx.y * 32;
    const int tx = threadIdx.x, ty = threadIdx.y;
#pragma unroll
    for (int i = 0; i < 4; ++i)
        t[ty + 8 * i][tx] = src[(size_t)(k0 + ty + 8 * i) * EXPN + n0 + tx];
    __syncthreads();
#pragma unroll
    for (int i = 0; i < 4; ++i)
        dst[(size_t)(n0 + ty + 8 * i) * D0 + k0 + tx] = f2h(t[tx][ty + 8 * i]);
}

// ---------------------------------------------------------------------------
// Xe(f16) = X @ Wb via f16 MFMA, NT, K=512. Fragment-major LDS.
// ---------------------------------------------------------------------------
__global__ __launch_bounds__(256) void gemm_xe_mfma(
    const unsigned short* __restrict__ Xh, const unsigned short* __restrict__ WbT,
    unsigned short* __restrict__ Xe)
{
    __shared__ __align__(16) char smem[34816];
    unsigned short (*AsF)[64][8] = (unsigned short (*)[64][8])(smem);
    unsigned short (*BsF)[64][8] = (unsigned short (*)[64][8])(smem + 8192);

    const int tid = threadIdx.x;
    const int wid = tid >> 6, lane = tid & 63;
    const int l15 = lane & 15, q = lane >> 4;
    const int wm = (wid >> 1) * 64, wn = (wid & 1) * 64;
    const int row0 = blockIdx.y * 128, col0 = blockIdx.x * 128;

    const int sr = tid >> 1;
    const int scp = (tid & 1) * 2;
    const int mi_w = sr >> 4, l_w = sr & 15;

    f32x4 acc[4][4];
#pragma unroll
    for (int m = 0; m < 4; ++m)
#pragma unroll
        for (int n = 0; n < 4; ++n) acc[m][n] = (f32x4){0.f, 0.f, 0.f, 0.f};

    for (int k0 = 0; k0 < D0; k0 += 32) {
        const unsigned short* pa = Xh  + (size_t)(row0 + sr) * D0 + k0 + scp * 8;
        const unsigned short* pb = WbT + (size_t)(col0 + sr) * D0 + k0 + scp * 8;
        ushort8v a0 = *(const ushort8v*)pa, a1 = *(const ushort8v*)(pa + 8);
        ushort8v b0 = *(const ushort8v*)pb, b1 = *(const ushort8v*)(pb + 8);

        __syncthreads();
        *(ushort8v*)&AsF[mi_w][scp * 16 + l_w][0] = a0;
        *(ushort8v*)&AsF[mi_w][(scp + 1) * 16 + l_w][0] = a1;
        *(ushort8v*)&BsF[mi_w][scp * 16 + l_w][0] = b0;
        *(ushort8v*)&BsF[mi_w][(scp + 1) * 16 + l_w][0] = b1;
        __syncthreads();

        half8 fa[4], fb[4];
#pragma unroll
        for (int m = 0; m < 4; ++m) {
            fa[m] = as_half8(&AsF[(wm >> 4) + m][lane][0]);
            fb[m] = as_half8(&BsF[(wn >> 4) + m][lane][0]);
        }
#pragma unroll
        for (int m = 0; m < 4; ++m)
#pragma unroll
            for (int n = 0; n < 4; ++n)
                acc[m][n] = __builtin_amdgcn_mfma_f32_16x16x32_f16(fa[m], fb[n], acc[m][n], 0, 0, 0);
    }

    unsigned short (*Cb)[136] = (unsigned short (*)[136])smem;
    const int rr = tid >> 1, hh = (tid & 1) * 64;
    __syncthreads();
#pragma unroll
    for (int m = 0; m < 4; ++m)
#pragma unroll
        for (int n = 0; n < 4; ++n)
#pragma unroll
            for (int r = 0; r < 4; ++r)
                Cb[wm + m * 16 + q * 4 + r][wn + n * 16 + l15] = f2h(acc[m][n][r]);
    __syncthreads();
#pragma unroll
    for (int c = 0; c < 8; ++c)
        *(ushort8v*)&Xe[(size_t)(row0 + rr) * EXPN + col0 + hh + c * 8] =
            *(const ushort8v*)&Cb[rr][hh + c * 8];
}

// ---------------------------------------------------------------------------
// sim = (Xe @ Xe^T)*inv_i*inv_j, diag=-3e38. 528 upper-tri blocks + mirror.
// ---------------------------------------------------------------------------
__global__ __launch_bounds__(256) void gemm_sim(
    const unsigned short* __restrict__ Xe,
    const float* __restrict__ invn, float* __restrict__ Sm)
{
    __shared__ unsigned short AsF[8][64][8], BsF[8][64][8];

    const int t = blockIdx.x;
    int bj = (int)((sqrtf(8.0f * t + 1.0f) - 1.0f) * 0.5f);
    while ((bj + 1) * (bj + 2) / 2 <= t) ++bj;
    while (bj * (bj + 1) / 2 > t) --bj;
    const int bi = t - bj * (bj + 1) / 2;
    const int row0 = bi * 128, col0 = bj * 128;

    const int tid = threadIdx.x;
    const int wid = tid >> 6, lane = tid & 63;
    const int l15 = lane & 15, q = lane >> 4;
    const int wm = (wid >> 1) * 64, wn = (wid & 1) * 64;

    const int sr = tid >> 1;
    const int scp = (tid & 1) * 2;
    const int mi_w = sr >> 4, l_w = sr & 15;

    f32x4 acc[4][4];
#pragma unroll
    for (int m = 0; m < 4; ++m)
#pragma unroll
        for (int n = 0; n < 4; ++n) acc[m][n] = (f32x4){0.f, 0.f, 0.f, 0.f};

    for (int k0 = 0; k0 < EXPN; k0 += 32) {
        const unsigned short* pa = Xe + (size_t)(row0 + sr) * EXPN + k0 + scp * 8;
        const unsigned short* pb = Xe + (size_t)(col0 + sr) * EXPN + k0 + scp * 8;
        ushort8v a0 = *(const ushort8v*)pa, a1 = *(const ushort8v*)(pa + 8);
        ushort8v b0 = *(const ushort8v*)pb, b1 = *(const ushort8v*)(pb + 8);

        __syncthreads();
        *(ushort8v*)&AsF[mi_w][scp * 16 + l_w][0] = a0;
        *(ushort8v*)&AsF[mi_w][(scp + 1) * 16 + l_w][0] = a1;
        *(ushort8v*)&BsF[mi_w][scp * 16 + l_w][0] = b0;
        *(ushort8v*)&BsF[mi_w][(scp + 1) * 16 + l_w][0] = b1;
        __syncthreads();

        half8 fa[4], fb[4];
#pragma unroll
        for (int m = 0; m < 4; ++m) {
            fa[m] = as_half8(&AsF[(wm >> 4) + m][lane][0]);
            fb[m] = as_half8(&BsF[(wn >> 4) + m][lane][0]);
        }
#pragma unroll
        for (int m = 0; m < 4; ++m)
#pragma unroll
            for (int n = 0; n < 4; ++n)
                acc[m][n] = __builtin_amdgcn_mfma_f32_16x16x32_f16(fa[m], fb[n], acc[m][n], 0, 0, 0);
    }

    const bool mirror = (bi != bj);
#pragma unroll
    for (int m = 0; m < 4; ++m)
#pragma unroll
        for (int n = 0; n < 4; ++n) {
            const int gj = col0 + wn + n * 16 + l15;
            const float invj = invn[gj];
#pragma unroll
            for (int r = 0; r < 4; ++r) {
                const int gi = row0 + wm + m * 16 + q * 4 + r;
                float v = acc[m][n][r] * invn[gi] * invj;
                if (gi == gj) v = -3.0e38f;
                Sm[(size_t)gi * MSAMP + gj] = v;
                if (mirror) Sm[(size_t)gj * MSAMP + gi] = v;
            }
        }
}

// ---------------------------------------------------------------------------
// Tk(f16) = tanh((1/k) * Adj @ Xe) via i8 MFMA (K=64/instr).
// A (0/1) decoded from bitmask via nibble-spread; B = XeT quantized i8.
// ---------------------------------------------------------------------------
__global__ __launch_bounds__(256) void gemm_adj_i8(
    const unsigned* __restrict__ Abits, const signed char* __restrict__ XeT,
    unsigned short* __restrict__ Tk, const int* __restrict__ kp)
{
    __shared__ signed char BsF[8][64][16];   // 8 KB: frag-major i8 B tile
    __shared__ uint2 aw2[128];               // 64-bit adjacency window per row

    const int tid = threadIdx.x;
    const int wid = tid >> 6, lane = tid & 63;
    const int l15 = lane & 15, q = lane >> 4;
    const int wm = (wid >> 1) * 64, wn = (wid & 1) * 64;
    const int row0 = blockIdx.x * 128;   // m over 4096
    const int col0 = blockIdx.y * 128;   // n over 8192

    const int sr = tid >> 1;             // 0..127: B staging row
    const int half = tid & 1;            // k-half of the 64-wide window

    i32x4v acc[4][4];
#pragma unroll
    for (int m = 0; m < 4; ++m)
#pragma unroll
        for (int n = 0; n < 4; ++n) acc[m][n] = (i32x4v){0, 0, 0, 0};

    for (int k0 = 0; k0 < MSAMP; k0 += 64) {
        const signed char* pb = XeT + (size_t)(col0 + sr) * MSAMP + k0 + half * 32;
        i32x4v b0 = *(const i32x4v*)pb;
        i32x4v b1 = *(const i32x4v*)(pb + 16);
        uint2 wv = make_uint2(0u, 0u);
        if (tid < 128)
            wv = *(const uint2*)(Abits + (size_t)(row0 + tid) * (MSAMP / 32) + (k0 >> 5));

        __syncthreads();
        *(i32x4v*)&BsF[sr >> 4][(half * 2 + 0) * 16 + (sr & 15)][0] = b0;
        *(i32x4v*)&BsF[sr >> 4][(half * 2 + 1) * 16 + (sr & 15)][0] = b1;
        if (tid < 128) aw2[tid] = wv;
        __syncthreads();

        i32x4v fb[4];
#pragma unroll
        for (int n = 0; n < 4; ++n)
            fb[n] = *(const i32x4v*)&BsF[(wn >> 4) + n][lane][0];

#pragma unroll
        for (int m = 0; m < 4; ++m) {
            const uint2 ww = aw2[wm + m * 16 + l15];
            const unsigned w = (q >= 2) ? ww.y : ww.x;
            const unsigned hw = (q & 1) ? (w >> 16) : w;   // 16 adjacency bits for this lane's k
            i32x4v fa;
#pragma unroll
            for (int p = 0; p < 4; ++p)
                fa[p] = (int)((((hw >> (4 * p)) & 0xFu) * 0x00204081u) & 0x01010101u);
#pragma unroll
            for (int n = 0; n < 4; ++n)
                acc[m][n] = __builtin_amdgcn_mfma_i32_16x16x64_i8(fa, fb[n], acc[m][n], 0, 0, 0);
        }
    }

    const float kv = QSCALE / (float)(*kp);
#pragma unroll
    for (int m = 0; m < 4; ++m)
#pragma unroll
        for (int n = 0; n < 4; ++n) {
            const int gj = col0 + wn + n * 16 + l15;
#pragma unroll
            for (int r = 0; r < 4; ++r) {
                const int gi = row0 + wm + m * 16 + q * 4 + r;
                Tk[(size_t)gi * EXPN + gj] = f2h(tanh_fast((float)acc[m][n][r] * kv));
            }
        }
}

// ---------------------------------------------------------------------------
// W [8192][1000] f32 -> WT f16 [NPAD][8192], zero-padded rows.
// ---------------------------------------------------------------------------
__global__ void transpose_w(const float* __restrict__ src,
                            unsigned short* __restrict__ dst)
{
    __shared__ float t[32][33];
    const int k0 = blockIdx.x * 32, n0 = blockIdx.y * 32;
    const int tx = threadIdx.x, ty = threadIdx.y;
#pragma unroll
    for (int i = 0; i < 4; ++i) {
        const int n = n0 + tx;
        t[ty + 8 * i][tx] = (n < NCLS) ? src[(size_t)(k0 + ty + 8 * i) * NCLS + n] : 0.f;
    }
    __syncthreads();
#pragma unroll
    for (int i = 0; i < 4; ++i)
        dst[(size_t)(n0 + ty + 8 * i) * EXPN + k0 + tx] = f2h(t[tx][ty + 8 * i]);
}

// ---------------------------------------------------------------------------
// Split-K=2, NO atomics: z=0 -> Cout (relu(Xe)@WmT), z=1 -> Ppart (Tk@WcT).
// ---------------------------------------------------------------------------
__global__ __launch_bounds__(256) void gemm_out_split(
    const unsigned short* __restrict__ Xe, const unsigned short* __restrict__ Tk,
    const unsigned short* __restrict__ WmT, const unsigned short* __restrict__ WcT,
    float* __restrict__ Cout, float* __restrict__ Ppart)
{
    __shared__ unsigned short AsF[8][64][8], BsF[8][64][8];

    const int tid = threadIdx.x;
    const int wid = tid >> 6, lane = tid & 63;
    const int l15 = lane & 15, q = lane >> 4;
    const int wm = (wid >> 1) * 64, wn = (wid & 1) * 64;
    const int row0 = blockIdx.y * 128;
    const int col0 = blockIdx.x * 128;
    const bool first = (blockIdx.z == 0);

    const unsigned short* Abase = first ? Xe : Tk;
    const unsigned short* Bbase = first ? WmT : WcT;
    float* dst = first ? Cout : Ppart;

    const int sr = tid >> 1;
    const int scp = (tid & 1) * 2;
    const int mi_w = sr >> 4, l_w = sr & 15;

    f32x4 acc[4][4];
#pragma unroll
    for (int m = 0; m < 4; ++m)
#pragma unroll
        for (int n = 0; n < 4; ++n) acc[m][n] = (f32x4){0.f, 0.f, 0.f, 0.f};

    for (int k0 = 0; k0 < EXPN; k0 += 32) {
        const unsigned short* pa = Abase + (size_t)(row0 + sr) * EXPN + k0 + scp * 8;
        const unsigned short* pb = Bbase + (size_t)(col0 + sr) * EXPN + k0 + scp * 8;
        ushort8v a0 = *(const ushort8v*)pa, a1 = *(const ushort8v*)(pa + 8);
        ushort8v b0 = *(const ushort8v*)pb, b1 = *(const ushort8v*)(pb + 8);
        if (first) { a0 = relu8h(a0); a1 = relu8h(a1); }

        __syncthreads();
        *(ushort8v*)&AsF[mi_w][scp * 16 + l_w][0] = a0;
        *(ushort8v*)&AsF[mi_w][(scp + 1) * 16 + l_w][0] = a1;
        *(ushort8v*)&BsF[mi_w][scp * 16 + l_w][0] = b0;
        *(ushort8v*)&BsF[mi_w][(scp + 1) * 16 + l_w][0] = b1;
        __syncthreads();

        half8 fa[4], fb[4];
#pragma unroll
        for (int m = 0; m < 4; ++m) {
            fa[m] = as_half8(&AsF[(wm >> 4) + m][lane][0]);
            fb[m] = as_half8(&BsF[(wn >> 4) + m][lane][0]);
        }
#pragma unroll
        for (int m = 0; m < 4; ++m)
#pragma unroll
            for (int n = 0; n < 4; ++n)
                acc[m][n] = __builtin_amdgcn_mfma_f32_16x16x32_f16(fa[m], fb[n], acc[m][n], 0, 0, 0);
    }

#pragma unroll
    for (int m = 0; m < 4; ++m)
#pragma unroll
        for (int n = 0; n < 4; ++n) {
            const int gj = col0 + wn + n * 16 + l15;
            if (gj < NCLS) {
#pragma unroll
                for (int r = 0; r < 4; ++r) {
                    const int gi = row0 + wm + m * 16 + q * 4 + r;
                    dst[(size_t)gi * NCLS + gj] = acc[m][n][r];
                }
            }
        }
}

// ---------------------------------------------------------------------------
// out[i] += P[i]
// ---------------------------------------------------------------------------
__global__ __launch_bounds__(256) void add_partials(float* __restrict__ out,
                                                    const float* __restrict__ P,
                                                    int n4)
{
    const int i = blockIdx.x * 256 + threadIdx.x;
    if (i < n4) {
        float4 a = ((const float4*)out)[i];
        float4 b = ((const float4*)P)[i];
        a.x += b.x; a.y += b.y; a.z += b.z; a.w += b.w;
        ((float4*)out)[i] = a;
    }
}

// ---------------------------------------------------------------------------
__global__ __launch_bounds__(256) void row_invnorm(
    const unsigned short* __restrict__ Xe, float* __restrict__ invn)
{
    const int row = blockIdx.x;
    float s = 0.f;
    for (int j = threadIdx.x * 8; j < EXPN; j += 2048) {
        ushort8v h = *(const ushort8v*)(Xe + (size_t)row * EXPN + j);
#pragma unroll
        for (int c = 0; c < 8; ++c) { float x = h2f(h[c]); s += x * x; }
    }
#pragma unroll
    for (int off = 32; off > 0; off >>= 1) s += __shfl_down(s, off);
    __shared__ float wsum[4];
    if ((threadIdx.x & 63) == 0) wsum[threadIdx.x >> 6] = s;
    __syncthreads();
    if (threadIdx.x == 0)
        invn[row] = rsqrtf(wsum[0] + wsum[1] + wsum[2] + wsum[3]);
}

// ---------------------------------------------------------------------------
__global__ __launch_bounds__(256) void topk_thresh(const float* __restrict__ sim,
                                                   float* __restrict__ thr,
                                                   int N, const int* __restrict__ kp)
{
    const int row = blockIdx.x;
    const float* srow = sim + (size_t)row * N;
    __shared__ int hist[256];
    __shared__ unsigned s_prefix;
    __shared__ int s_rem;
    if (threadIdx.x == 0) { s_prefix = 0u; s_rem = *kp; }
    __syncthreads();

    for (int pass = 0; pass < 4; ++pass) {
        const int shift = 24 - 8 * pass;
        hist[threadIdx.x] = 0;
        __syncthreads();
        const unsigned prefix = s_prefix;
        const unsigned pmask = (pass == 0) ? 0u : (0xFFFFFFFFu << (shift + 8));
        for (int j = threadIdx.x; j < N; j += 256) {
            unsigned u = __float_as_uint(srow[j]);
            u = ((int)u < 0) ? ~u : (u | 0x80000000u);
            if ((u & pmask) == (prefix & pmask))
                atomicAdd(&hist[(u >> shift) & 255], 1);
        }
        __syncthreads();
        if (threadIdx.x == 0) {
            int rem = s_rem, accum = 0, b;
            for (b = 255; b > 0; --b) {
                if (accum + hist[b] >= rem) break;
                accum += hist[b];
            }
            s_rem = rem - accum;
            s_prefix = prefix | ((unsigned)b << shift);
        }
        __syncthreads();
    }

    if (threadIdx.x == 0) {
        const unsigned u = s_prefix;
        const unsigned orig = (u & 0x80000000u) ? (u & 0x7FFFFFFFu) : ~u;
        thr[row] = __uint_as_float(orig);
    }
}

// ---------------------------------------------------------------------------
__global__ __launch_bounds__(128) void bitpack(const float* __restrict__ Sm,
                                               const float* __restrict__ thr,
                                               unsigned* __restrict__ Abits)
{
    const int row = blockIdx.x;
    const int w = threadIdx.x;
    const float t = thr[row];
    const float* p = Sm + (size_t)row * MSAMP + w * 32;
    unsigned m = 0;
#pragma unroll
    for (int b = 0; b < 32; b += 4) {
        float4 v = *(const float4*)(p + b);
        m |= (v.x >= t ? 1u : 0u) << (b + 0);
        m |= (v.y >= t ? 1u : 0u) << (b + 1);
        m |= (v.z >= t ? 1u : 0u) << (b + 2);
        m |= (v.w >= t ? 1u : 0u) << (b + 3);
    }
    Abits[(size_t)row * (MSAMP / 32) + w] = m;
}

// ---------------------------------------------------------------------------
// XeT_i8[n][m] = clamp(round(Xe[m][n] * 127/6)) — transpose + quantize.
// ---------------------------------------------------------------------------
__global__ void transpose_xe_q(const unsigned short* __restrict__ src,
                               signed char* __restrict__ dst)
{
    __shared__ signed char t[32][36];
    const int bx = blockIdx.x;   // n tiles (8192/32)
    const int by = blockIdx.y;   // m tiles (4096/32)
    const int tx = threadIdx.x, ty = threadIdx.y;
#pragma unroll
    for (int i = 0; i < 4; ++i) {
        float v = h2f(src[(size_t)(by * 32 + ty + 8 * i) * EXPN + bx * 32 + tx]);
        int qv = (int)rintf(v * QSCALE_INV);
        qv = max(-127, min(127, qv));
        t[tx][ty + 8 * i] = (signed char)qv;
    }
    __syncthreads();
    const int tid = ty * 32 + tx;
    const int nl = tid >> 3, mg = (tid & 7) * 4;
    char4 o;
    o.x = t[nl][mg + 0]; o.y = t[nl][mg + 1];
    o.z = t[nl][mg + 2]; o.w = t[nl][mg + 3];
    *(char4*)&dst[(size_t)(bx * 32 + nl) * MSAMP + by * 32 + mg] = o;
}

// ---------------------------------------------------------------------------
extern "C" void kernel_launch(void* const* d_in, const int* in_sizes, int n_in,
                              void* d_out, int out_size, void* d_ws, size_t ws_size,
                              hipStream_t stream)
{
    const float* X  = (const float*)d_in[0];
    const float* Wb = (const float*)d_in[1];
    const float* Wm = (const float*)d_in[2];
    const float* Wc = (const float*)d_in[3];
    const int*   kp = (const int*)d_in[4];
    float* out = (float*)d_out;

    // Workspace (peak ~194 MiB, same envelope as rounds 2-8):
    //  SEG0 [0,64M)    Xe f16 [4096][8192]
    //  SEG1 [64,128M)  XeT_i8 [8192][4096] (32M) -> WmT+WcT f16 (32M) | Ppart f32 @+32M
    //  SEG2 [128,192M) prep {Xh 4M, WbT 8M} -> Sm f32 -> Tk f16
    //  [192M..)        Abits (2 MiB), invn, thr
    char* base = (char*)d_ws;
    const size_t SEG = (size_t)64 << 20;
    const size_t need = 3 * SEG + ((size_t)2 << 20) + 65536;
    if (ws_size < need) return;

    unsigned short* Xe   = (unsigned short*)base;
    signed char*    XeTq = (signed char*)(base + SEG);
    unsigned short* WmT  = (unsigned short*)(base + SEG);        // overlay (after gemm_adj)
    unsigned short* WcT  = WmT + (size_t)NPAD * EXPN;            // +16 MiB
    float*          Ppart= (float*)(base + SEG + ((size_t)32 << 20)); // 16.4 MiB
    unsigned short* Xh   = (unsigned short*)(base + 2 * SEG);               // 4 MB
    unsigned short* WbT  = Xh + (size_t)MSAMP * D0;                         // 8 MB
    float*          Sm   = (float*)(base + 2 * SEG);             // overlay (after gemm_xe)
    unsigned short* Tk   = (unsigned short*)(base + 2 * SEG);    // overlay (after bitpack)
    unsigned*       Abits= (unsigned*)(base + 3 * SEG);
    float*          invn = (float*)(base + 3 * SEG + ((size_t)2 << 20));
    float*          thr  = invn + MSAMP;

    const dim3 blk(256);

    // 0) prep: X -> f16, Wb -> WbT f16
    cvt_x<<<dim3((MSAMP * D0) / (256 * 8)), blk, 0, stream>>>(X, Xh);
    transpose_wb<<<dim3(EXPN / 32, D0 / 32), dim3(32, 8), 0, stream>>>(Wb, WbT);

    // 1) Xe = X @ Wb (f16 MFMA)
    gemm_xe_mfma<<<dim3(EXPN / 128, MSAMP / 128), blk, 0, stream>>>(Xh, WbT, Xe);

    // 2) row inverse norms
    row_invnorm<<<dim3(MSAMP), blk, 0, stream>>>(Xe, invn);

    // 3) sim (symmetric: 528 upper-tri blocks, mirrored writes)
    gemm_sim<<<dim3(528), blk, 0, stream>>>(Xe, invn, Sm);

    // 4) per-row k-th largest threshold (exact f32 radix select)
    topk_thresh<<<dim3(MSAMP), blk, 0, stream>>>(Sm, thr, MSAMP, kp);

    // 5) adjacency bitmask
    bitpack<<<dim3(MSAMP), dim3(128), 0, stream>>>(Sm, thr, Abits);

    // 6) XeT_i8 = quantized Xe^T (into SEG1)
    transpose_xe_q<<<dim3(EXPN / 32, MSAMP / 32), dim3(32, 8), 0, stream>>>(Xe, XeTq);

    // 7) Tk = tanh((1/k) Adj @ Xe) via i8 MFMA — over dead Sm
    gemm_adj_i8<<<dim3(MSAMP / 128, EXPN / 128), blk, 0, stream>>>(Abits, XeTq, Tk, kp);

    // 8) W transposes (f16 NT) into dead XeT region
    transpose_w<<<dim3(EXPN / 32, NPAD / 32), dim3(32, 8), 0, stream>>>(Wm, WmT);
    transpose_w<<<dim3(EXPN / 32, NPAD / 32), dim3(32, 8), 0, stream>>>(Wc, WcT);

    // 9) split-K=2 output GEMM: z=0 -> out, z=1 -> Ppart (no atomics)
    gemm_out_split<<<dim3(NPAD / 128, MSAMP / 128, 2), blk, 0, stream>>>(
        Xe, Tk, WmT, WcT, out, Ppart);

    // 10) out += Ppart (kernel-boundary-ordered, XCD-safe)
    add_partials<<<dim3((MSAMP * NCLS / 4 + 255) / 256), blk, 0, stream>>>(
        out, Ppart, MSAMP * NCLS / 4);
}

// Round 10
// 1025.278 us; speedup vs baseline: 10.6800x; 1.0225x over previous
//
#include <hip/hip_runtime.h>
#include <hip/hip_bf16.h>

#define MSAMP 4096
#define D0    512
#define EXPN  8192
#define NCLS  1000
#define NPAD  1024
#define QSCALE     (6.0f / 127.0f)
#define QSCALE_INV (127.0f / 6.0f)

typedef __attribute__((ext_vector_type(8))) _Float16       half8;
typedef __attribute__((ext_vector_type(8))) unsigned short ushort8v;
typedef __attribute__((ext_vector_type(4))) float          f32x4;
typedef __attribute__((ext_vector_type(4))) int            i32x4v;

__device__ __forceinline__ unsigned short f2h(float f) {
    union { _Float16 h; unsigned short u; } c; c.h = (_Float16)f; return c.u;
}
__device__ __forceinline__ float h2f(unsigned short u) {
    union { unsigned short u; _Float16 h; } c; c.u = u; return (float)c.h;
}
__device__ __forceinline__ ushort8v relu8h(ushort8v v) {   // f16 relu: sign bit
#pragma unroll
    for (int j = 0; j < 8; ++j) v[j] = (v[j] & 0x8000u) ? (unsigned short)0 : v[j];
    return v;
}
__device__ __forceinline__ half8 as_half8(const unsigned short* p) {
    return *(const half8*)p;
}
__device__ __forceinline__ float tanh_fast(float x) {
    float e = __expf(2.0f * x);
    return 1.0f - 2.0f * __builtin_amdgcn_rcpf(e + 1.0f);
}

// ---------------------------------------------------------------------------
// X f32 [4096][512] -> f16
// ---------------------------------------------------------------------------
__global__ __launch_bounds__(256) void cvt_x(const float* __restrict__ src,
                                             unsigned short* __restrict__ dst)
{
    const size_t i = ((size_t)blockIdx.x * 256 + threadIdx.x) * 8;
    float4 v0 = *(const float4*)(src + i), v1 = *(const float4*)(src + i + 4);
    union { unsigned short u[8]; ushort8v v; } H;
    H.u[0] = f2h(v0.x); H.u[1] = f2h(v0.y); H.u[2] = f2h(v0.z); H.u[3] = f2h(v0.w);
    H.u[4] = f2h(v1.x); H.u[5] = f2h(v1.y); H.u[6] = f2h(v1.z); H.u[7] = f2h(v1.w);
    *(ushort8v*)(dst + i) = H.v;
}

// ---------------------------------------------------------------------------
// Wb [512][8192] f32 -> WbT f16 [8192][512]
// ---------------------------------------------------------------------------
__global__ void transpose_wb(const float* __restrict__ src,
                             unsigned short* __restrict__ dst)
{
    __shared__ float t[32][33];
    const int n0 = blockIdx.x * 32, k0 = blockIdx.y * 32;
    const int tx = threadIdx.x, ty = threadIdx.y;
#pragma unroll
    for (int i = 0; i < 4; ++i)
        t[ty + 8 * i][tx] = src[(size_t)(k0 + ty + 8 * i) * EXPN + n0 + tx];
    __syncthreads();
#pragma unroll
    for (int i = 0; i < 4; ++i)
        dst[(size_t)(n0 + ty + 8 * i) * D0 + k0 + tx] = f2h(t[tx][ty + 8 * i]);
}

// ---------------------------------------------------------------------------
// Xe(f16) = X @ Wb via f16 MFMA, NT, K=512. Fragment-major LDS.
// ---------------------------------------------------------------------------
__global__ __launch_bounds__(256) void gemm_xe_mfma(
    const unsigned short* __restrict__ Xh, const unsigned short* __restrict__ WbT,
    unsigned short* __restrict__ Xe)
{
    __shared__ __align__(16) char smem[34816];
    unsigned short (*AsF)[64][8] = (unsigned short (*)[64][8])(smem);
    unsigned short (*BsF)[64][8] = (unsigned short (*)[64][8])(smem + 8192);

    const int tid = threadIdx.x;
    const int wid = tid >> 6, lane = tid & 63;
    const int l15 = lane & 15, q = lane >> 4;
    const int wm = (wid >> 1) * 64, wn = (wid & 1) * 64;
    const int row0 = blockIdx.y * 128, col0 = blockIdx.x * 128;

    const int sr = tid >> 1;
    const int scp = (tid & 1) * 2;
    const int mi_w = sr >> 4, l_w = sr & 15;

    f32x4 acc[4][4];
#pragma unroll
    for (int m = 0; m < 4; ++m)
#pragma unroll
        for (int n = 0; n < 4; ++n) acc[m][n] = (f32x4){0.f, 0.f, 0.f, 0.f};

    for (int k0 = 0; k0 < D0; k0 += 32) {
        const unsigned short* pa = Xh  + (size_t)(row0 + sr) * D0 + k0 + scp * 8;
        const unsigned short* pb = WbT + (size_t)(col0 + sr) * D0 + k0 + scp * 8;
        ushort8v a0 = *(const ushort8v*)pa, a1 = *(const ushort8v*)(pa + 8);
        ushort8v b0 = *(const ushort8v*)pb, b1 = *(const ushort8v*)(pb + 8);

        __syncthreads();
        *(ushort8v*)&AsF[mi_w][scp * 16 + l_w][0] = a0;
        *(ushort8v*)&AsF[mi_w][(scp + 1) * 16 + l_w][0] = a1;
        *(ushort8v*)&BsF[mi_w][scp * 16 + l_w][0] = b0;
        *(ushort8v*)&BsF[mi_w][(scp + 1) * 16 + l_w][0] = b1;
        __syncthreads();

        half8 fa[4], fb[4];
#pragma unroll
        for (int m = 0; m < 4; ++m) {
            fa[m] = as_half8(&AsF[(wm >> 4) + m][lane][0]);
            fb[m] = as_half8(&BsF[(wn >> 4) + m][lane][0]);
        }
#pragma unroll
        for (int m = 0; m < 4; ++m)
#pragma unroll
            for (int n = 0; n < 4; ++n)
                acc[m][n] = __builtin_amdgcn_mfma_f32_16x16x32_f16(fa[m], fb[n], acc[m][n], 0, 0, 0);
    }

    unsigned short (*Cb)[136] = (unsigned short (*)[136])smem;
    const int rr = tid >> 1, hh = (tid & 1) * 64;
    __syncthreads();
#pragma unroll
    for (int m = 0; m < 4; ++m)
#pragma unroll
        for (int n = 0; n < 4; ++n)
#pragma unroll
            for (int r = 0; r < 4; ++r)
                Cb[wm + m * 16 + q * 4 + r][wn + n * 16 + l15] = f2h(acc[m][n][r]);
    __syncthreads();
#pragma unroll
    for (int c = 0; c < 8; ++c)
        *(ushort8v*)&Xe[(size_t)(row0 + rr) * EXPN + col0 + hh + c * 8] =
            *(const ushort8v*)&Cb[rr][hh + c * 8];
}

// ---------------------------------------------------------------------------
// sim = (Xe @ Xe^T)*inv_i*inv_j, diag=-3e38. 528 upper-tri blocks + mirror.
// ---------------------------------------------------------------------------
__global__ __launch_bounds__(256) void gemm_sim(
    const unsigned short* __restrict__ Xe,
    const float* __restrict__ invn, float* __restrict__ Sm)
{
    __shared__ unsigned short AsF[8][64][8], BsF[8][64][8];

    const int t = blockIdx.x;
    int bj = (int)((sqrtf(8.0f * t + 1.0f) - 1.0f) * 0.5f);
    while ((bj + 1) * (bj + 2) / 2 <= t) ++bj;
    while (bj * (bj + 1) / 2 > t) --bj;
    const int bi = t - bj * (bj + 1) / 2;
    const int row0 = bi * 128, col0 = bj * 128;

    const int tid = threadIdx.x;
    const int wid = tid >> 6, lane = tid & 63;
    const int l15 = lane & 15, q = lane >> 4;
    const int wm = (wid >> 1) * 64, wn = (wid & 1) * 64;

    const int sr = tid >> 1;
    const int scp = (tid & 1) * 2;
    const int mi_w = sr >> 4, l_w = sr & 15;

    f32x4 acc[4][4];
#pragma unroll
    for (int m = 0; m < 4; ++m)
#pragma unroll
        for (int n = 0; n < 4; ++n) acc[m][n] = (f32x4){0.f, 0.f, 0.f, 0.f};

    for (int k0 = 0; k0 < EXPN; k0 += 32) {
        const unsigned short* pa = Xe + (size_t)(row0 + sr) * EXPN + k0 + scp * 8;
        const unsigned short* pb = Xe + (size_t)(col0 + sr) * EXPN + k0 + scp * 8;
        ushort8v a0 = *(const ushort8v*)pa, a1 = *(const ushort8v*)(pa + 8);
        ushort8v b0 = *(const ushort8v*)pb, b1 = *(const ushort8v*)(pb + 8);

        __syncthreads();
        *(ushort8v*)&AsF[mi_w][scp * 16 + l_w][0] = a0;
        *(ushort8v*)&AsF[mi_w][(scp + 1) * 16 + l_w][0] = a1;
        *(ushort8v*)&BsF[mi_w][scp * 16 + l_w][0] = b0;
        *(ushort8v*)&BsF[mi_w][(scp + 1) * 16 + l_w][0] = b1;
        __syncthreads();

        half8 fa[4], fb[4];
#pragma unroll
        for (int m = 0; m < 4; ++m) {
            fa[m] = as_half8(&AsF[(wm >> 4) + m][lane][0]);
            fb[m] = as_half8(&BsF[(wn >> 4) + m][lane][0]);
        }
#pragma unroll
        for (int m = 0; m < 4; ++m)
#pragma unroll
            for (int n = 0; n < 4; ++n)
                acc[m][n] = __builtin_amdgcn_mfma_f32_16x16x32_f16(fa[m], fb[n], acc[m][n], 0, 0, 0);
    }

    const bool mirror = (bi != bj);
#pragma unroll
    for (int m = 0; m < 4; ++m)
#pragma unroll
        for (int n = 0; n < 4; ++n) {
            const int gj = col0 + wn + n * 16 + l15;
            const float invj = invn[gj];
#pragma unroll
            for (int r = 0; r < 4; ++r) {
                const int gi = row0 + wm + m * 16 + q * 4 + r;
                float v = acc[m][n][r] * invn[gi] * invj;
                if (gi == gj) v = -3.0e38f;
                Sm[(size_t)gi * MSAMP + gj] = v;
                if (mirror) Sm[(size_t)gj * MSAMP + gi] = v;
            }
        }
}

// ---------------------------------------------------------------------------
// Tk(f16) = tanh((1/k) * Adj @ Xe) via i8 MFMA (K=64/instr).
// ---------------------------------------------------------------------------
__global__ __launch_bounds__(256) void gemm_adj_i8(
    const unsigned* __restrict__ Abits, const signed char* __restrict__ XeT,
    unsigned short* __restrict__ Tk, const int* __restrict__ kp)
{
    __shared__ signed char BsF[8][64][16];
    __shared__ uint2 aw2[128];

    const int tid = threadIdx.x;
    const int wid = tid >> 6, lane = tid & 63;
    const int l15 = lane & 15, q = lane >> 4;
    const int wm = (wid >> 1) * 64, wn = (wid & 1) * 64;
    const int row0 = blockIdx.x * 128;
    const int col0 = blockIdx.y * 128;

    const int sr = tid >> 1;
    const int half = tid & 1;

    i32x4v acc[4][4];
#pragma unroll
    for (int m = 0; m < 4; ++m)
#pragma unroll
        for (int n = 0; n < 4; ++n) acc[m][n] = (i32x4v){0, 0, 0, 0};

    for (int k0 = 0; k0 < MSAMP; k0 += 64) {
        const signed char* pb = XeT + (size_t)(col0 + sr) * MSAMP + k0 + half * 32;
        i32x4v b0 = *(const i32x4v*)pb;
        i32x4v b1 = *(const i32x4v*)(pb + 16);
        uint2 wv = make_uint2(0u, 0u);
        if (tid < 128)
            wv = *(const uint2*)(Abits + (size_t)(row0 + tid) * (MSAMP / 32) + (k0 >> 5));

        __syncthreads();
        *(i32x4v*)&BsF[sr >> 4][(half * 2 + 0) * 16 + (sr & 15)][0] = b0;
        *(i32x4v*)&BsF[sr >> 4][(half * 2 + 1) * 16 + (sr & 15)][0] = b1;
        if (tid < 128) aw2[tid] = wv;
        __syncthreads();

        i32x4v fb[4];
#pragma unroll
        for (int n = 0; n < 4; ++n)
            fb[n] = *(const i32x4v*)&BsF[(wn >> 4) + n][lane][0];

#pragma unroll
        for (int m = 0; m < 4; ++m) {
            const uint2 ww = aw2[wm + m * 16 + l15];
            const unsigned w = (q >= 2) ? ww.y : ww.x;
            const unsigned hw = (q & 1) ? (w >> 16) : w;
            i32x4v fa;
#pragma unroll
            for (int p = 0; p < 4; ++p)
                fa[p] = (int)((((hw >> (4 * p)) & 0xFu) * 0x00204081u) & 0x01010101u);
#pragma unroll
            for (int n = 0; n < 4; ++n)
                acc[m][n] = __builtin_amdgcn_mfma_i32_16x16x64_i8(fa, fb[n], acc[m][n], 0, 0, 0);
        }
    }

    const float kv = QSCALE / (float)(*kp);
#pragma unroll
    for (int m = 0; m < 4; ++m)
#pragma unroll
        for (int n = 0; n < 4; ++n) {
            const int gj = col0 + wn + n * 16 + l15;
#pragma unroll
            for (int r = 0; r < 4; ++r) {
                const int gi = row0 + wm + m * 16 + q * 4 + r;
                Tk[(size_t)gi * EXPN + gj] = f2h(tanh_fast((float)acc[m][n][r] * kv));
            }
        }
}

// ---------------------------------------------------------------------------
// W [8192][1000] f32 -> WT f16 [NPAD][8192], zero-padded rows.
// ---------------------------------------------------------------------------
__global__ void transpose_w(const float* __restrict__ src,
                            unsigned short* __restrict__ dst)
{
    __shared__ float t[32][33];
    const int k0 = blockIdx.x * 32, n0 = blockIdx.y * 32;
    const int tx = threadIdx.x, ty = threadIdx.y;
#pragma unroll
    for (int i = 0; i < 4; ++i) {
        const int n = n0 + tx;
        t[ty + 8 * i][tx] = (n < NCLS) ? src[(size_t)(k0 + ty + 8 * i) * NCLS + n] : 0.f;
    }
    __syncthreads();
#pragma unroll
    for (int i = 0; i < 4; ++i)
        dst[(size_t)(n0 + ty + 8 * i) * EXPN + k0 + tx] = f2h(t[tx][ty + 8 * i]);
}

// ---------------------------------------------------------------------------
// Split-K=4, NO atomics:
//   z=0: relu(Xe) k[0,4096)  @ WmT -> f32 out
//   z=1: relu(Xe) k[4096,8K) @ WmT -> f16 P[0]
//   z=2: Tk       k[0,4096)  @ WcT -> f16 P[1]
//   z=3: Tk       k[4096,8K) @ WcT -> f16 P[2]
// Disjoint plain-store buffers; add_partials sums after kernel boundary.
// ---------------------------------------------------------------------------
__global__ __launch_bounds__(256) void gemm_out_split(
    const unsigned short* __restrict__ Xe, const unsigned short* __restrict__ Tk,
    const unsigned short* __restrict__ WmT, const unsigned short* __restrict__ WcT,
    float* __restrict__ Cout, unsigned short* __restrict__ Pf)
{
    __shared__ unsigned short AsF[8][64][8], BsF[8][64][8];

    const int tid = threadIdx.x;
    const int wid = tid >> 6, lane = tid & 63;
    const int l15 = lane & 15, q = lane >> 4;
    const int wm = (wid >> 1) * 64, wn = (wid & 1) * 64;
    const int row0 = blockIdx.y * 128;
    const int col0 = blockIdx.x * 128;
    const int zz = blockIdx.z;
    const bool xe_side = (zz < 2);
    const int kbase = (zz & 1) * (EXPN / 2);

    const unsigned short* Abase = xe_side ? Xe : Tk;
    const unsigned short* Bbase = xe_side ? WmT : WcT;

    const int sr = tid >> 1;
    const int scp = (tid & 1) * 2;
    const int mi_w = sr >> 4, l_w = sr & 15;

    f32x4 acc[4][4];
#pragma unroll
    for (int m = 0; m < 4; ++m)
#pragma unroll
        for (int n = 0; n < 4; ++n) acc[m][n] = (f32x4){0.f, 0.f, 0.f, 0.f};

    for (int kk = 0; kk < EXPN / 2; kk += 32) {
        const int k0 = kbase + kk;
        const unsigned short* pa = Abase + (size_t)(row0 + sr) * EXPN + k0 + scp * 8;
        const unsigned short* pb = Bbase + (size_t)(col0 + sr) * EXPN + k0 + scp * 8;
        ushort8v a0 = *(const ushort8v*)pa, a1 = *(const ushort8v*)(pa + 8);
        ushort8v b0 = *(const ushort8v*)pb, b1 = *(const ushort8v*)(pb + 8);
        if (xe_side) { a0 = relu8h(a0); a1 = relu8h(a1); }

        __syncthreads();
        *(ushort8v*)&AsF[mi_w][scp * 16 + l_w][0] = a0;
        *(ushort8v*)&AsF[mi_w][(scp + 1) * 16 + l_w][0] = a1;
        *(ushort8v*)&BsF[mi_w][scp * 16 + l_w][0] = b0;
        *(ushort8v*)&BsF[mi_w][(scp + 1) * 16 + l_w][0] = b1;
        __syncthreads();

        half8 fa[4], fb[4];
#pragma unroll
        for (int m = 0; m < 4; ++m) {
            fa[m] = as_half8(&AsF[(wm >> 4) + m][lane][0]);
            fb[m] = as_half8(&BsF[(wn >> 4) + m][lane][0]);
        }
#pragma unroll
        for (int m = 0; m < 4; ++m)
#pragma unroll
            for (int n = 0; n < 4; ++n)
                acc[m][n] = __builtin_amdgcn_mfma_f32_16x16x32_f16(fa[m], fb[n], acc[m][n], 0, 0, 0);
    }

    if (zz == 0) {
#pragma unroll
        for (int m = 0; m < 4; ++m)
#pragma unroll
            for (int n = 0; n < 4; ++n) {
                const int gj = col0 + wn + n * 16 + l15;
                if (gj < NCLS) {
#pragma unroll
                    for (int r = 0; r < 4; ++r) {
                        const int gi = row0 + wm + m * 16 + q * 4 + r;
                        Cout[(size_t)gi * NCLS + gj] = acc[m][n][r];
                    }
                }
            }
    } else {
        unsigned short* dp = Pf + (size_t)(zz - 1) * MSAMP * NCLS;
#pragma unroll
        for (int m = 0; m < 4; ++m)
#pragma unroll
            for (int n = 0; n < 4; ++n) {
                const int gj = col0 + wn + n * 16 + l15;
                if (gj < NCLS) {
#pragma unroll
                    for (int r = 0; r < 4; ++r) {
                        const int gi = row0 + wm + m * 16 + q * 4 + r;
                        dp[(size_t)gi * NCLS + gj] = f2h(acc[m][n][r]);
                    }
                }
            }
    }
}

// ---------------------------------------------------------------------------
// out[i] += P0[i] + P1[i] + P2[i]   (f16 partials -> f32 accumulate)
// ---------------------------------------------------------------------------
__global__ __launch_bounds__(256) void add_partials(float* __restrict__ out,
                                                    const unsigned short* __restrict__ P,
                                                    int n4)
{
    const int i = blockIdx.x * 256 + threadIdx.x;
    if (i < n4) {
        float4 a = ((const float4*)out)[i];
        const ushort4 p0 = *(const ushort4*)(P + (size_t)i * 4);
        const ushort4 p1 = *(const ushort4*)(P + (size_t)MSAMP * NCLS + (size_t)i * 4);
        const ushort4 p2 = *(const ushort4*)(P + (size_t)2 * MSAMP * NCLS + (size_t)i * 4);
        a.x += h2f(p0.x) + h2f(p1.x) + h2f(p2.x);
        a.y += h2f(p0.y) + h2f(p1.y) + h2f(p2.y);
        a.z += h2f(p0.z) + h2f(p1.z) + h2f(p2.z);
        a.w += h2f(p0.w) + h2f(p1.w) + h2f(p2.w);
        ((float4*)out)[i] = a;
    }
}

// ---------------------------------------------------------------------------
__global__ __launch_bounds__(256) void row_invnorm(
    const unsigned short* __restrict__ Xe, float* __restrict__ invn)
{
    const int row = blockIdx.x;
    float s = 0.f;
    for (int j = threadIdx.x * 8; j < EXPN; j += 2048) {
        ushort8v h = *(const ushort8v*)(Xe + (size_t)row * EXPN + j);
#pragma unroll
        for (int c = 0; c < 8; ++c) { float x = h2f(h[c]); s += x * x; }
    }
#pragma unroll
    for (int off = 32; off > 0; off >>= 1) s += __shfl_down(s, off);
    __shared__ float wsum[4];
    if ((threadIdx.x & 63) == 0) wsum[threadIdx.x >> 6] = s;
    __syncthreads();
    if (threadIdx.x == 0)
        invn[row] = rsqrtf(wsum[0] + wsum[1] + wsum[2] + wsum[3]);
}

// ---------------------------------------------------------------------------
__global__ __launch_bounds__(256) void topk_thresh(const float* __restrict__ sim,
                                                   float* __restrict__ thr,
                                                   int N, const int* __restrict__ kp)
{
    const int row = blockIdx.x;
    const float* srow = sim + (size_t)row * N;
    __shared__ int hist[256];
    __shared__ unsigned s_prefix;
    __shared__ int s_rem;
    if (threadIdx.x == 0) { s_prefix = 0u; s_rem = *kp; }
    __syncthreads();

    for (int pass = 0; pass < 4; ++pass) {
        const int shift = 24 - 8 * pass;
        hist[threadIdx.x] = 0;
        __syncthreads();
        const unsigned prefix = s_prefix;
        const unsigned pmask = (pass == 0) ? 0u : (0xFFFFFFFFu << (shift + 8));
        for (int j = threadIdx.x; j < N; j += 256) {
            unsigned u = __float_as_uint(srow[j]);
            u = ((int)u < 0) ? ~u : (u | 0x80000000u);
            if ((u & pmask) == (prefix & pmask))
                atomicAdd(&hist[(u >> shift) & 255], 1);
        }
        __syncthreads();
        if (threadIdx.x == 0) {
            int rem = s_rem, accum = 0, b;
            for (b = 255; b > 0; --b) {
                if (accum + hist[b] >= rem) break;
                accum += hist[b];
            }
            s_rem = rem - accum;
            s_prefix = prefix | ((unsigned)b << shift);
        }
        __syncthreads();
    }

    if (threadIdx.x == 0) {
        const unsigned u = s_prefix;
        const unsigned orig = (u & 0x80000000u) ? (u & 0x7FFFFFFFu) : ~u;
        thr[row] = __uint_as_float(orig);
    }
}

// ---------------------------------------------------------------------------
__global__ __launch_bounds__(128) void bitpack(const float* __restrict__ Sm,
                                               const float* __restrict__ thr,
                                               unsigned* __restrict__ Abits)
{
    const int row = blockIdx.x;
    const int w = threadIdx.x;
    const float t = thr[row];
    const float* p = Sm + (size_t)row * MSAMP + w * 32;
    unsigned m = 0;
#pragma unroll
    for (int b = 0; b < 32; b += 4) {
        float4 v = *(const float4*)(p + b);
        m |= (v.x >= t ? 1u : 0u) << (b + 0);
        m |= (v.y >= t ? 1u : 0u) << (b + 1);
        m |= (v.z >= t ? 1u : 0u) << (b + 2);
        m |= (v.w >= t ? 1u : 0u) << (b + 3);
    }
    Abits[(size_t)row * (MSAMP / 32) + w] = m;
}

// ---------------------------------------------------------------------------
// XeT_i8[n][m] = clamp(round(Xe[m][n] * 127/6)) — transpose + quantize.
// ---------------------------------------------------------------------------
__global__ void transpose_xe_q(const unsigned short* __restrict__ src,
                               signed char* __restrict__ dst)
{
    __shared__ signed char t[32][36];
    const int bx = blockIdx.x;
    const int by = blockIdx.y;
    const int tx = threadIdx.x, ty = threadIdx.y;
#pragma unroll
    for (int i = 0; i < 4; ++i) {
        float v = h2f(src[(size_t)(by * 32 + ty + 8 * i) * EXPN + bx * 32 + tx]);
        int qv = (int)rintf(v * QSCALE_INV);
        qv = max(-127, min(127, qv));
        t[tx][ty + 8 * i] = (signed char)qv;
    }
    __syncthreads();
    const int tid = ty * 32 + tx;
    const int nl = tid >> 3, mg = (tid & 7) * 4;
    char4 o;
    o.x = t[nl][mg + 0]; o.y = t[nl][mg + 1];
    o.z = t[nl][mg + 2]; o.w = t[nl][mg + 3];
    *(char4*)&dst[(size_t)(bx * 32 + nl) * MSAMP + by * 32 + mg] = o;
}

// ---------------------------------------------------------------------------
extern "C" void kernel_launch(void* const* d_in, const int* in_sizes, int n_in,
                              void* d_out, int out_size, void* d_ws, size_t ws_size,
                              hipStream_t stream)
{
    const float* X  = (const float*)d_in[0];
    const float* Wb = (const float*)d_in[1];
    const float* Wm = (const float*)d_in[2];
    const float* Wc = (const float*)d_in[3];
    const int*   kp = (const int*)d_in[4];
    float* out = (float*)d_out;

    // Workspace (peak ~194 MiB, same envelope as rounds 2-9):
    //  SEG0 [0,64M)    Xe f16 [4096][8192]
    //  SEG1 [64,128M)  XeT_i8 (32M) -> WmT+WcT f16 (32M) | Pf f16 x3 @+32M (23.4M)
    //  SEG2 [128,192M) prep {Xh 4M, WbT 8M} -> Sm f32 -> Tk f16
    //  [192M..)        Abits (2 MiB), invn, thr
    char* base = (char*)d_ws;
    const size_t SEG = (size_t)64 << 20;
    const size_t need = 3 * SEG + ((size_t)2 << 20) + 65536;
    if (ws_size < need) return;

    unsigned short* Xe   = (unsigned short*)base;
    signed char*    XeTq = (signed char*)(base + SEG);
    unsigned short* WmT  = (unsigned short*)(base + SEG);        // overlay (after gemm_adj)
    unsigned short* WcT  = WmT + (size_t)NPAD * EXPN;            // +16 MiB
    unsigned short* Pf   = (unsigned short*)(base + SEG + ((size_t)32 << 20)); // 3 x 7.8 MiB
    unsigned short* Xh   = (unsigned short*)(base + 2 * SEG);               // 4 MB
    unsigned short* WbT  = Xh + (size_t)MSAMP * D0;                         // 8 MB
    float*          Sm   = (float*)(base + 2 * SEG);             // overlay (after gemm_xe)
    unsigned short* Tk   = (unsigned short*)(base + 2 * SEG);    // overlay (after bitpack)
    unsigned*       Abits= (unsigned*)(base + 3 * SEG);
    float*          invn = (float*)(base + 3 * SEG + ((size_t)2 << 20));
    float*          thr  = invn + MSAMP;

    const dim3 blk(256);

    // 0) prep: X -> f16, Wb -> WbT f16
    cvt_x<<<dim3((MSAMP * D0) / (256 * 8)), blk, 0, stream>>>(X, Xh);
    transpose_wb<<<dim3(EXPN / 32, D0 / 32), dim3(32, 8), 0, stream>>>(Wb, WbT);

    // 1) Xe = X @ Wb (f16 MFMA)
    gemm_xe_mfma<<<dim3(EXPN / 128, MSAMP / 128), blk, 0, stream>>>(Xh, WbT, Xe);

    // 2) row inverse norms
    row_invnorm<<<dim3(MSAMP), blk, 0, stream>>>(Xe, invn);

    // 3) sim (symmetric: 528 upper-tri blocks, mirrored writes)
    gemm_sim<<<dim3(528), blk, 0, stream>>>(Xe, invn, Sm);

    // 4) per-row k-th largest threshold (exact f32 radix select)
    topk_thresh<<<dim3(MSAMP), blk, 0, stream>>>(Sm, thr, MSAMP, kp);

    // 5) adjacency bitmask
    bitpack<<<dim3(MSAMP), dim3(128), 0, stream>>>(Sm, thr, Abits);

    // 6) XeT_i8 = quantized Xe^T (into SEG1)
    transpose_xe_q<<<dim3(EXPN / 32, MSAMP / 32), dim3(32, 8), 0, stream>>>(Xe, XeTq);

    // 7) Tk = tanh((1/k) Adj @ Xe) via i8 MFMA — over dead Sm
    gemm_adj_i8<<<dim3(MSAMP / 128, EXPN / 128), blk, 0, stream>>>(Abits, XeTq, Tk, kp);

    // 8) W transposes (f16 NT) into dead XeT region
    transpose_w<<<dim3(EXPN / 32, NPAD / 32), dim3(32, 8), 0, stream>>>(Wm, WmT);
    transpose_w<<<dim3(EXPN / 32, NPAD / 32), dim3(32, 8), 0, stream>>>(Wc, WcT);

    // 9) split-K=4 output GEMM: z=0 -> f32 out, z=1..3 -> f16 partials
    gemm_out_split<<<dim3(NPAD / 128, MSAMP / 128, 4), blk, 0, stream>>>(
        Xe, Tk, WmT, WcT, out, Pf);

    // 10) out += P0+P1+P2 (kernel-boundary-ordered, XCD-safe)
    add_partials<<<dim3((MSAMP * NCLS / 4 + 255) / 256), blk, 0, stream>>>(
        out, Pf, MSAMP * NCLS / 4);
}